// Round 4
// baseline (787.806 us; speedup 1.0000x reference)
//
#include <hip/hip_runtime.h>
#include <math.h>

constexpr int NN  = 50000;   // nodes
constexpr int NE  = 150000;  // edges
constexpr int NIN = 16;      // node features in
constexpr int EIN = 19;      // edge features in
constexpr int HD  = 32;      // hidden H
constexpr int NTILES = NE / 16;  // 9375 exactly

#define LEAK  0.1f
#define BNEPS 1e-5f

typedef __attribute__((ext_vector_type(8))) short bfrag;    // 8 bf16 = 4 VGPR
typedef __attribute__((ext_vector_type(4))) float f32x4;
typedef __attribute__((ext_vector_type(4))) int   i32x4;

__device__ __forceinline__ float lky(float v){ return fmaxf(v, LEAK*v); }
__device__ __forceinline__ unsigned short f2bf(float f){
  unsigned u = __float_as_uint(f);
  return (unsigned short)((u + 0x7FFFu + ((u >> 16) & 1u)) >> 16);   // RNE
}

// ---------------------------------------------------------------- zero
__global__ void zero_kernel(float* __restrict__ p, int n){
  int stride = gridDim.x * blockDim.x;
  for(int i = blockIdx.x*blockDim.x + threadIdx.x; i < n; i += stride) p[i] = 0.f;
}

// ---------------------------------------------------------------- BN stats
template<int C>
__global__ void stats_kernel(const float* __restrict__ data, int rows, float* __restrict__ sums){
  __shared__ float ls[2*C];
  for(int i = threadIdx.x; i < 2*C; i += blockDim.x) ls[i] = 0.f;
  __syncthreads();
  float s[C], q[C];
  #pragma unroll
  for(int c = 0; c < C; c++){ s[c] = 0.f; q[c] = 0.f; }
  int stride = gridDim.x * blockDim.x;
  for(int r = blockIdx.x*blockDim.x + threadIdx.x; r < rows; r += stride){
    const float* rp = data + (size_t)r * C;
    #pragma unroll
    for(int c = 0; c < C; c++){ float v = rp[c]; s[c] += v; q[c] += v*v; }
  }
  #pragma unroll
  for(int c = 0; c < C; c++){ atomicAdd(&ls[c], s[c]); atomicAdd(&ls[C+c], q[c]); }
  __syncthreads();
  for(int i = threadIdx.x; i < 2*C; i += blockDim.x) atomicAdd(&sums[i], ls[i]);
}

// ss layout: scale_e[19], shift_e[19], scale_x[16], shift_x[16]
__global__ void finalize_stats(const float* __restrict__ sums_e, const float* __restrict__ sums_x,
                               const float* __restrict__ ge, const float* __restrict__ be,
                               const float* __restrict__ gx, const float* __restrict__ bx,
                               float* __restrict__ ss){
  int t = threadIdx.x;
  if(t < EIN){
    float m = sums_e[t] / (float)NE;
    float v = sums_e[EIN+t] / (float)NE - m*m;
    float sc = ge[t] * rsqrtf(v + BNEPS);
    ss[t] = sc; ss[EIN+t] = be[t] - m*sc;
  } else if(t < EIN + NIN){
    int c = t - EIN;
    float m = sums_x[c] / (float)NN;
    float v = sums_x[NIN+c] / (float)NN - m*m;
    float sc = gx[c] * rsqrtf(v + BNEPS);
    ss[2*EIN + c] = sc; ss[2*EIN + NIN + c] = bx[c] - m*sc;
  }
}

// ---------------------------------------------------------------- fold BN(e) into W1/b1 + predictor
__global__ void fold_kernel(const float* __restrict__ ss,
                            const float* __restrict__ l0W1, const float* __restrict__ l0b1,
                            const float* __restrict__ l1W1, const float* __restrict__ l1b1,
                            const float* __restrict__ l2W1, const float* __restrict__ l2b1,
                            const float* __restrict__ emW1, const float* __restrict__ emb1,
                            float* __restrict__ W1f, float* __restrict__ b1f,
                            float* __restrict__ emW1f, float* __restrict__ emb1f){
  int t = threadIdx.x;
  int seg = t >> 5, j = t & 31;
  if(seg == 0){
    if(j < NIN){
      float acc = l0b1[j];
      for(int k = 0; k < EIN; k++){
        W1f[0*640 + k*NIN + j] = ss[k] * l0W1[k*NIN + j];
        acc += ss[EIN+k] * l0W1[k*NIN + j];
      }
      b1f[0*32 + j] = acc;
    }
  } else if(seg == 1){
    float acc = l1b1[j];
    for(int k = 0; k < EIN; k++){
      W1f[1*640 + k*HD + j] = ss[k] * l1W1[k*HD + j];
      acc += ss[EIN+k] * l1W1[k*HD + j];
    }
    b1f[1*32 + j] = acc;
  } else if(seg == 2){
    float acc = l2b1[j];
    for(int k = 0; k < EIN; k++){
      W1f[2*640 + k*HD + j] = ss[k] * l2W1[k*HD + j];
      acc += ss[EIN+k] * l2W1[k*HD + j];
    }
    b1f[2*32 + j] = acc;
  } else if(seg == 3){
    float acc = emb1[j];
    for(int k = 0; k < EIN; k++){
      emW1f[k*HD + j] = ss[k] * emW1[(2*HD+k)*HD + j];
      acc += ss[EIN+k] * emW1[(2*HD+k)*HD + j];
    }
    emb1f[j] = acc;
  }
}

template<int C>
__global__ void normalize_kernel(const float* __restrict__ in, float* __restrict__ outp,
                                 const float* __restrict__ ss, int rows){
  int n = rows * C;
  int stride = gridDim.x * blockDim.x;
  for(int i = blockIdx.x*blockDim.x + threadIdx.x; i < n; i += stride){
    int c = i % C;
    outp[i] = in[i] * ss[c] + ss[C + c];
  }
}

// ---------------------------------------------------------------- pack W2 into B-fragment layout (bf16)
template<int DIN, int NCH>
__global__ void w2pack_kernel(const float* __restrict__ W2, short* __restrict__ outp){
  int idx = blockIdx.x*blockDim.x + threadIdx.x;
  if(idx >= NCH*512) return;
  int c = idx >> 9, l = (idx >> 3) & 63, j = idx & 7;
  int k = 8*(l>>4) + j;
  int n = c*16 + (l & 15);
  float v = (k < DIN) ? W2[(size_t)k*(DIN*HD) + n] : 0.f;
  outp[idx] = (short)f2bf(v);
}

// ---------------------------------------------------------------- T1 = leaky(e_raw @ W1f + b1f) -> bf16 [E,32]
template<int DIN>
__global__ __launch_bounds__(256) void t1_kernel(const float* __restrict__ eraw,
                                                 const float* __restrict__ W1f,
                                                 const float* __restrict__ b1f,
                                                 short* __restrict__ T1){
  int idx = blockIdx.x*blockDim.x + threadIdx.x;
  if(idx >= NE*16) return;
  int e = idx >> 4, j0 = idx & 15;
  const float* ep = eraw + (size_t)e*EIN;
  float eb[EIN];
  #pragma unroll
  for(int k = 0; k < EIN; k++) eb[k] = ep[k];

  float a = b1f[j0];
  #pragma unroll
  for(int k = 0; k < EIN; k++) a = fmaf(eb[k], W1f[k*DIN + j0], a);
  short r0 = (short)f2bf(lky(a));
  short r1 = 0;
  if(DIN == 32){
    float b = b1f[j0 + 16];
    #pragma unroll
    for(int k = 0; k < EIN; k++) b = fmaf(eb[k], W1f[k*DIN + j0 + 16], b);
    r1 = (short)f2bf(lky(b));
  }
  T1[(size_t)e*32 + j0]      = r0;
  T1[(size_t)e*32 + j0 + 16] = r1;
}

// ---------------------------------------------------------------- x_next = x @ root + bias
template<int DIN>
__global__ __launch_bounds__(256) void root_kernel(const float* __restrict__ xin,
                                                   const float* __restrict__ root,
                                                   const float* __restrict__ bias,
                                                   float* __restrict__ xout){
  int idx = blockIdx.x*blockDim.x + threadIdx.x;
  if(idx >= NN * HD) return;
  int node = idx / HD, o = idx % HD;
  const float* xr = xin + (size_t)node * DIN;
  float acc = bias[o];
  #pragma unroll
  for(int k = 0; k < DIN; k++) acc += xr[k] * root[k*HD + o];
  xout[idx] = acc;
}

// ---------------------------------------------------------------- MFMA msg (unchanged from R2)
template<int DIN, int NCH>
__global__ __launch_bounds__(256) void msg3_kernel(const short* __restrict__ T1,
                                                   const int* __restrict__ rowp,
                                                   const int* __restrict__ colp,
                                                   const float* __restrict__ xin,
                                                   const short* __restrict__ w2p,
                                                   const float* __restrict__ b2,
                                                   float* __restrict__ xout){
  constexpr int XGP = DIN + 4;
  __shared__ short w2s[NCH*512];
  __shared__ float b2s[NCH*16];
  __shared__ float xgs[4][16][XGP];

  const int tid  = threadIdx.x;
  const int l    = tid & 63;
  const int wid  = tid >> 6;
  const int grp  = l >> 4, lo16 = l & 15;

  for(int t = tid; t < NCH*64; t += 256)
    ((i32x4*)w2s)[t] = ((const i32x4*)w2p)[t];
  for(int t = tid; t < NCH*16; t += 256) b2s[t] = b2[t];
  __syncthreads();

  int tile = blockIdx.x*4 + wid;
  if(tile >= NTILES) return;
  int e0 = tile * 16;

  {
    int r = rowp[e0 + lo16];
    if(DIN == 32){
      const f32x4* xp = (const f32x4*)(xin + (size_t)r*32 + grp*8);
      *(f32x4*)&xgs[wid][lo16][grp*8]     = xp[0];
      *(f32x4*)&xgs[wid][lo16][grp*8 + 4] = xp[1];
    } else {
      const f32x4* xp = (const f32x4*)(xin + (size_t)r*16 + grp*4);
      *(f32x4*)&xgs[wid][lo16][grp*4] = xp[0];
    }
  }

  bfrag af = *(const bfrag*)(T1 + (size_t)(e0 + lo16)*32 + grp*8);

  f32x4 m0; m0[0]=0.f; m0[1]=0.f; m0[2]=0.f; m0[3]=0.f;
  f32x4 m1 = m0;
  const f32x4 z = m0;

  #pragma unroll 4
  for(int i = 0; i < NCH/2; i++){
    bfrag b0 = *(const bfrag*)&w2s[((2*i  )*64 + l)*8];
    bfrag b1 = *(const bfrag*)&w2s[((2*i+1)*64 + l)*8];
    f32x4 u0 = __builtin_amdgcn_mfma_f32_16x16x32_bf16(af, b0, z, 0, 0, 0);
    f32x4 u1 = __builtin_amdgcn_mfma_f32_16x16x32_bf16(af, b1, z, 0, 0, 0);
    float bv0 = b2s[(2*i)*16 + lo16];
    float bv1 = b2s[(2*i+1)*16 + lo16];
    #pragma unroll
    for(int reg = 0; reg < 4; reg++){
      float xv = xgs[wid][grp*4 + reg][i];
      float a0 = u0[reg] + bv0; a0 = fmaxf(a0, LEAK*a0);
      float a1 = u1[reg] + bv1; a1 = fmaxf(a1, LEAK*a1);
      m0[reg] = fmaf(xv, a0, m0[reg]);
      m1[reg] = fmaf(xv, a1, m1[reg]);
    }
  }

  #pragma unroll
  for(int reg = 0; reg < 4; reg++){
    int ce = colp[e0 + grp*4 + reg];
    atomicAdd(&xout[(size_t)ce*HD + lo16],      m0[reg]);
    atomicAdd(&xout[(size_t)ce*HD + 16 + lo16], m1[reg]);
  }
}

// ---------------------------------------------------------------- predictor v2: 2 threads/edge (o-halves), shfl exchange
__global__ __launch_bounds__(256) void pred_edge2_kernel(const float* __restrict__ x,
                                                         const float* __restrict__ eraw,
                                                         const int* __restrict__ row,
                                                         const int* __restrict__ col,
                                                         const float* __restrict__ emW1,
                                                         const float* __restrict__ emW1f,
                                                         const float* __restrict__ emb1f,
                                                         const float* __restrict__ emW2,
                                                         const float* __restrict__ emb2,
                                                         const float* __restrict__ nm1W1,
                                                         const float* __restrict__ nm1b1,
                                                         const float* __restrict__ nm1W2,
                                                         const float* __restrict__ nm1b2,
                                                         float* __restrict__ agg,
                                                         float* __restrict__ cnt){
  int gid = blockIdx.x*blockDim.x + threadIdx.x;
  int e = gid >> 1;
  if(e >= NE) return;
  const int h  = gid & 1;        // o-half owned by this lane
  const int ob = h * 16;
  int r = row[e], c = col[e];

  f32x4 xr4[8], xc4[8];
  const f32x4* xrp = (const f32x4*)(x + (size_t)r*HD);
  const f32x4* xcp = (const f32x4*)(x + (size_t)c*HD);
  #pragma unroll
  for(int k = 0; k < 8; k++) xr4[k] = xrp[k];
  #pragma unroll
  for(int k = 0; k < 8; k++) xc4[k] = xcp[k];
  float eb[EIN];
  #pragma unroll
  for(int k = 0; k < EIN; k++) eb[k] = eraw[(size_t)e*EIN + k];

  // ---- u half: leaky([xr,xc,e_raw] @ emW1(+fold) + b)[ob..ob+16)
  float u[16];
  {
    const f32x4* bp = (const f32x4*)(emb1f + ob);
    #pragma unroll
    for(int g = 0; g < 4; g++) *(f32x4*)&u[g*4] = bp[g];
  }
  #pragma unroll
  for(int k = 0; k < HD; k++){
    float v = xr4[k>>2][k&3];
    const f32x4* wp = (const f32x4*)(emW1 + k*HD + ob);
    #pragma unroll
    for(int g = 0; g < 4; g++){ f32x4 w = wp[g];
      #pragma unroll
      for(int j = 0; j < 4; j++) u[g*4+j] = fmaf(v, w[j], u[g*4+j]); }
  }
  #pragma unroll
  for(int k = 0; k < HD; k++){
    float v = xc4[k>>2][k&3];
    const f32x4* wp = (const f32x4*)(emW1 + (HD+k)*HD + ob);
    #pragma unroll
    for(int g = 0; g < 4; g++){ f32x4 w = wp[g];
      #pragma unroll
      for(int j = 0; j < 4; j++) u[g*4+j] = fmaf(v, w[j], u[g*4+j]); }
  }
  #pragma unroll
  for(int k = 0; k < EIN; k++){
    float v = eb[k];
    const f32x4* wp = (const f32x4*)(emW1f + k*HD + ob);
    #pragma unroll
    for(int g = 0; g < 4; g++){ f32x4 w = wp[g];
      #pragma unroll
      for(int j = 0; j < 4; j++) u[g*4+j] = fmaf(v, w[j], u[g*4+j]); }
  }
  #pragma unroll
  for(int j = 0; j < 16; j++) u[j] = lky(u[j]);

  // ---- exchange -> full u (low = k 0..15, high = k 16..31)
  float ulo[16], uhi[16];
  #pragma unroll
  for(int j = 0; j < 16; j++){
    float o = __shfl_xor(u[j], 1);
    ulo[j] = h ? o : u[j];
    uhi[j] = h ? u[j] : o;
  }

  // ---- e2 half
  float e2[16];
  {
    const f32x4* bp = (const f32x4*)(emb2 + ob);
    #pragma unroll
    for(int g = 0; g < 4; g++) *(f32x4*)&e2[g*4] = bp[g];
  }
  #pragma unroll
  for(int k = 0; k < 16; k++){
    float v = ulo[k];
    const f32x4* wp = (const f32x4*)(emW2 + k*HD + ob);
    #pragma unroll
    for(int g = 0; g < 4; g++){ f32x4 w = wp[g];
      #pragma unroll
      for(int j = 0; j < 4; j++) e2[g*4+j] = fmaf(v, w[j], e2[g*4+j]); }
  }
  #pragma unroll
  for(int k = 0; k < 16; k++){
    float v = uhi[k];
    const f32x4* wp = (const f32x4*)(emW2 + (16+k)*HD + ob);
    #pragma unroll
    for(int g = 0; g < 4; g++){ f32x4 w = wp[g];
      #pragma unroll
      for(int j = 0; j < 4; j++) e2[g*4+j] = fmaf(v, w[j], e2[g*4+j]); }
  }

  // ---- exchange -> full e2
  float e2lo[16], e2hi[16];
  #pragma unroll
  for(int j = 0; j < 16; j++){
    float o = __shfl_xor(e2[j], 1);
    e2lo[j] = h ? o : e2[j];
    e2hi[j] = h ? e2[j] : o;
  }

  // ---- vv half = leaky([xr, e2] @ nm1W1 + b)
  float vv[16];
  {
    const f32x4* bp = (const f32x4*)(nm1b1 + ob);
    #pragma unroll
    for(int g = 0; g < 4; g++) *(f32x4*)&vv[g*4] = bp[g];
  }
  #pragma unroll
  for(int k = 0; k < HD; k++){
    float v = xr4[k>>2][k&3];
    const f32x4* wp = (const f32x4*)(nm1W1 + k*HD + ob);
    #pragma unroll
    for(int g = 0; g < 4; g++){ f32x4 w = wp[g];
      #pragma unroll
      for(int j = 0; j < 4; j++) vv[g*4+j] = fmaf(v, w[j], vv[g*4+j]); }
  }
  #pragma unroll
  for(int k = 0; k < 16; k++){
    float v = e2lo[k];
    const f32x4* wp = (const f32x4*)(nm1W1 + (HD+k)*HD + ob);
    #pragma unroll
    for(int g = 0; g < 4; g++){ f32x4 w = wp[g];
      #pragma unroll
      for(int j = 0; j < 4; j++) vv[g*4+j] = fmaf(v, w[j], vv[g*4+j]); }
  }
  #pragma unroll
  for(int k = 0; k < 16; k++){
    float v = e2hi[k];
    const f32x4* wp = (const f32x4*)(nm1W1 + (HD+16+k)*HD + ob);
    #pragma unroll
    for(int g = 0; g < 4; g++){ f32x4 w = wp[g];
      #pragma unroll
      for(int j = 0; j < 4; j++) vv[g*4+j] = fmaf(v, w[j], vv[g*4+j]); }
  }
  #pragma unroll
  for(int j = 0; j < 16; j++) vv[j] = lky(vv[j]);

  // ---- exchange -> full vv
  float vlo[16], vhi[16];
  #pragma unroll
  for(int j = 0; j < 16; j++){
    float o = __shfl_xor(vv[j], 1);
    vlo[j] = h ? o : vv[j];
    vhi[j] = h ? vv[j] : o;
  }

  // ---- h half = vv @ nm1W2 + b ; scatter
  float hh[16];
  {
    const f32x4* bp = (const f32x4*)(nm1b2 + ob);
    #pragma unroll
    for(int g = 0; g < 4; g++) *(f32x4*)&hh[g*4] = bp[g];
  }
  #pragma unroll
  for(int k = 0; k < 16; k++){
    float v = vlo[k];
    const f32x4* wp = (const f32x4*)(nm1W2 + k*HD + ob);
    #pragma unroll
    for(int g = 0; g < 4; g++){ f32x4 w = wp[g];
      #pragma unroll
      for(int j = 0; j < 4; j++) hh[g*4+j] = fmaf(v, w[j], hh[g*4+j]); }
  }
  #pragma unroll
  for(int k = 0; k < 16; k++){
    float v = vhi[k];
    const f32x4* wp = (const f32x4*)(nm1W2 + (16+k)*HD + ob);
    #pragma unroll
    for(int g = 0; g < 4; g++){ f32x4 w = wp[g];
      #pragma unroll
      for(int j = 0; j < 4; j++) hh[g*4+j] = fmaf(v, w[j], hh[g*4+j]); }
  }

  float* aggp = agg + (size_t)c * HD + ob;
  #pragma unroll
  for(int j = 0; j < 16; j++) atomicAdd(&aggp[j], hh[j]);
  if(h == 0) atomicAdd(&cnt[c], 1.f);
}

// ---------------------------------------------------------------- final node model + log_softmax
__global__ __launch_bounds__(256) void final_kernel(const float* __restrict__ x,
                                                    const float* __restrict__ agg,
                                                    const float* __restrict__ cnt,
                                                    const float* __restrict__ W1,
                                                    const float* __restrict__ b1,
                                                    const float* __restrict__ W2,
                                                    const float* __restrict__ b2,
                                                    float* __restrict__ out){
  int n = blockIdx.x*blockDim.x + threadIdx.x;
  if(n >= NN) return;
  float inv = 1.f / fmaxf(cnt[n], 1.f);
  const float* xp = x + (size_t)n * HD;
  const float* ap = agg + (size_t)n * HD;

  float t[HD];
  #pragma unroll
  for(int o = 0; o < HD; o++) t[o] = b1[o];
  #pragma unroll
  for(int k = 0; k < HD; k++){ float v = xp[k]; const float* wp = W1 + k*HD;
    #pragma unroll
    for(int o = 0; o < HD; o++) t[o] += v * wp[o]; }
  #pragma unroll
  for(int k = 0; k < HD; k++){ float v = ap[k] * inv; const float* wp = W1 + (HD+k)*HD;
    #pragma unroll
    for(int o = 0; o < HD; o++) t[o] += v * wp[o]; }

  float a0 = b2[0], a1 = b2[1];
  #pragma unroll
  for(int k = 0; k < HD; k++){ float v = lky(t[k]); a0 += v * W2[k*2]; a1 += v * W2[k*2+1]; }

  float m  = fmaxf(a0, a1);
  float ls = m + logf(expf(a0 - m) + expf(a1 - m));
  out[(size_t)n*2]   = a0 - ls;
  out[(size_t)n*2+1] = a1 - ls;
}

// ---------------------------------------------------------------- launch
extern "C" void kernel_launch(void* const* d_in, const int* in_sizes, int n_in,
                              void* d_out, int out_size, void* d_ws, size_t ws_size,
                              hipStream_t stream){
  const float* x  = (const float*)d_in[0];
  const int*   ei = (const int*)  d_in[1];
  const float* e  = (const float*)d_in[2];
  const float* bn_node_g = (const float*)d_in[4];
  const float* bn_node_b = (const float*)d_in[5];
  const float* bn_edge_g = (const float*)d_in[6];
  const float* bn_edge_b = (const float*)d_in[7];
  const float* lW1[3], *lb1[3], *lW2[3], *lb2[3], *lroot[3], *lbias[3];
  for(int l = 0; l < 3; l++){
    lW1[l]   = (const float*)d_in[8 + 6*l + 0];
    lb1[l]   = (const float*)d_in[8 + 6*l + 1];
    lW2[l]   = (const float*)d_in[8 + 6*l + 2];
    lb2[l]   = (const float*)d_in[8 + 6*l + 3];
    lroot[l] = (const float*)d_in[8 + 6*l + 4];
    lbias[l] = (const float*)d_in[8 + 6*l + 5];
  }
  const float* emW1  = (const float*)d_in[26];
  const float* emb1  = (const float*)d_in[27];
  const float* emW2  = (const float*)d_in[28];
  const float* emb2  = (const float*)d_in[29];
  const float* nm1W1 = (const float*)d_in[30];
  const float* nm1b1 = (const float*)d_in[31];
  const float* nm1W2 = (const float*)d_in[32];
  const float* nm1b2 = (const float*)d_in[33];
  const float* nm2W1 = (const float*)d_in[34];
  const float* nm2b1 = (const float*)d_in[35];
  const float* nm2W2 = (const float*)d_in[36];
  const float* nm2b2 = (const float*)d_in[37];

  const int* rowp = ei;
  const int* colp = ei + NE;

  // workspace layout (float units)
  float* ws   = (float*)d_ws;
  float* x_bn = ws;                                 // 800000
  float* x_a  = x_bn + (size_t)NN*NIN;              // 1600000
  float* x_b  = x_a  + (size_t)NN*HD;               // 1600000
  float* scr  = x_b  + (size_t)NN*HD;               // 4096
  float* sums_e = scr;          // 38
  float* sums_x = scr + 64;     // 32
  float* ss     = scr + 128;    // 70
  float* W1f    = scr + 256;    // 3*640
  float* b1f    = scr + 2304;   // 3*32
  float* emW1f  = scr + 2432;   // 608
  float* emb1f  = scr + 3072;   // 32
  short* w2pk   = (short*)(scr + 4096);             // 3 * 32768 shorts
  short* T1     = w2pk + 3*32768;                   // NE*32 bf16
  float* agg    = (float*)T1;                       // alias (T1 dead after layer-2 msg)
  float* cnt    = agg + (size_t)NN*HD;

  zero_kernel<<<1, 256, 0, stream>>>(scr, 256);
  stats_kernel<EIN><<<256, 256, 0, stream>>>(e, NE, sums_e);
  stats_kernel<NIN><<<256, 256, 0, stream>>>(x, NN, sums_x);
  finalize_stats<<<1, 64, 0, stream>>>(sums_e, sums_x, bn_edge_g, bn_edge_b,
                                       bn_node_g, bn_node_b, ss);
  fold_kernel<<<1, 128, 0, stream>>>(ss, lW1[0], lb1[0], lW1[1], lb1[1], lW1[2], lb1[2],
                                     emW1, emb1, W1f, b1f, emW1f, emb1f);
  normalize_kernel<NIN><<<1024, 256, 0, stream>>>(x, x_bn, ss + 2*EIN, NN);

  w2pack_kernel<NIN, 32><<<(32*512 + 255)/256, 256, 0, stream>>>(lW2[0], w2pk + 0*32768);
  w2pack_kernel<HD,  64><<<(64*512 + 255)/256, 256, 0, stream>>>(lW2[1], w2pk + 1*32768);
  w2pack_kernel<HD,  64><<<(64*512 + 255)/256, 256, 0, stream>>>(lW2[2], w2pk + 2*32768);

  const int t1blocks = (NE*16 + 255)/256;
  const int nblocks  = (NN*HD + 255)/256;
  const int mblocks  = (NTILES + 3)/4;

  // layer 0 (din=16): x_bn -> x_a
  root_kernel<NIN><<<nblocks, 256, 0, stream>>>(x_bn, lroot[0], lbias[0], x_a);
  t1_kernel<NIN><<<t1blocks, 256, 0, stream>>>(e, W1f + 0*640, b1f + 0*32, T1);
  msg3_kernel<NIN, 32><<<mblocks, 256, 0, stream>>>(T1, rowp, colp, x_bn,
                                                    w2pk + 0*32768, lb2[0], x_a);
  // layer 1 (din=32): x_a -> x_b
  root_kernel<HD><<<nblocks, 256, 0, stream>>>(x_a, lroot[1], lbias[1], x_b);
  t1_kernel<HD><<<t1blocks, 256, 0, stream>>>(e, W1f + 1*640, b1f + 1*32, T1);
  msg3_kernel<HD, 64><<<mblocks, 256, 0, stream>>>(T1, rowp, colp, x_a,
                                                   w2pk + 1*32768, lb2[1], x_b);
  // layer 2 (din=32): x_b -> x_a
  root_kernel<HD><<<nblocks, 256, 0, stream>>>(x_b, lroot[2], lbias[2], x_a);
  t1_kernel<HD><<<t1blocks, 256, 0, stream>>>(e, W1f + 2*640, b1f + 2*32, T1);
  msg3_kernel<HD, 64><<<mblocks, 256, 0, stream>>>(T1, rowp, colp, x_b,
                                                   w2pk + 2*32768, lb2[2], x_a);

  // predictor (agg/cnt alias T1 region — zero first)
  zero_kernel<<<2048, 256, 0, stream>>>(agg, NN*HD + NN);
  pred_edge2_kernel<<<(NE*2 + 255)/256, 256, 0, stream>>>(x_a, e, rowp, colp,
                                                          emW1, emW1f, emb1f, emW2, emb2,
                                                          nm1W1, nm1b1, nm1W2, nm1b2,
                                                          agg, cnt);
  final_kernel<<<(NN + 255)/256, 256, 0, stream>>>(x_a, agg, cnt,
                                                   nm2W1, nm2b1, nm2W2, nm2b2,
                                                   (float*)d_out);
}

// Round 5
// 459.528 us; speedup vs baseline: 1.7144x; 1.7144x over previous
//
#include <hip/hip_runtime.h>
#include <math.h>

constexpr int NN  = 50000;   // nodes
constexpr int NE  = 150000;  // edges
constexpr int NIN = 16;      // node features in
constexpr int EIN = 19;      // edge features in
constexpr int HD  = 32;      // hidden H
constexpr int NTILES = NE / 16;  // 9375 exactly

#define LEAK  0.1f
#define BNEPS 1e-5f

typedef __attribute__((ext_vector_type(8))) short bfrag;    // 8 bf16 = 4 VGPR
typedef __attribute__((ext_vector_type(4))) float f32x4;
typedef __attribute__((ext_vector_type(4))) int   i32x4;

__device__ __forceinline__ float lky(float v){ return fmaxf(v, LEAK*v); }
__device__ __forceinline__ unsigned f2bf(float f){
  unsigned u = __float_as_uint(f);
  return ((u + 0x7FFFu + ((u >> 16) & 1u)) >> 16);   // RNE
}
// split v into hi(bf16) + lo(bf16 of residual); pack 8 of each into i32x4
__device__ __forceinline__ void split8(const float* v, i32x4& h4, i32x4& l4){
  unsigned hs[8], ls[8];
  #pragma unroll
  for(int j = 0; j < 8; j++){
    unsigned hh = f2bf(v[j]);
    float hf = __uint_as_float(hh << 16);
    hs[j] = hh; ls[j] = f2bf(v[j] - hf);
  }
  h4[0] = (int)(hs[0] | (hs[1]<<16)); h4[1] = (int)(hs[2] | (hs[3]<<16));
  h4[2] = (int)(hs[4] | (hs[5]<<16)); h4[3] = (int)(hs[6] | (hs[7]<<16));
  l4[0] = (int)(ls[0] | (ls[1]<<16)); l4[1] = (int)(ls[2] | (ls[3]<<16));
  l4[2] = (int)(ls[4] | (ls[5]<<16)); l4[3] = (int)(ls[6] | (ls[7]<<16));
}

// ---------------------------------------------------------------- zero
__global__ void zero_kernel(float* __restrict__ p, int n){
  int stride = gridDim.x * blockDim.x;
  for(int i = blockIdx.x*blockDim.x + threadIdx.x; i < n; i += stride) p[i] = 0.f;
}

// ---------------------------------------------------------------- BN stats
template<int C>
__global__ void stats_kernel(const float* __restrict__ data, int rows, float* __restrict__ sums){
  __shared__ float ls[2*C];
  for(int i = threadIdx.x; i < 2*C; i += blockDim.x) ls[i] = 0.f;
  __syncthreads();
  float s[C], q[C];
  #pragma unroll
  for(int c = 0; c < C; c++){ s[c] = 0.f; q[c] = 0.f; }
  int stride = gridDim.x * blockDim.x;
  for(int r = blockIdx.x*blockDim.x + threadIdx.x; r < rows; r += stride){
    const float* rp = data + (size_t)r * C;
    #pragma unroll
    for(int c = 0; c < C; c++){ float v = rp[c]; s[c] += v; q[c] += v*v; }
  }
  #pragma unroll
  for(int c = 0; c < C; c++){ atomicAdd(&ls[c], s[c]); atomicAdd(&ls[C+c], q[c]); }
  __syncthreads();
  for(int i = threadIdx.x; i < 2*C; i += blockDim.x) atomicAdd(&sums[i], ls[i]);
}

// ss layout: scale_e[19], shift_e[19], scale_x[16], shift_x[16]
__global__ void finalize_stats(const float* __restrict__ sums_e, const float* __restrict__ sums_x,
                               const float* __restrict__ ge, const float* __restrict__ be,
                               const float* __restrict__ gx, const float* __restrict__ bx,
                               float* __restrict__ ss){
  int t = threadIdx.x;
  if(t < EIN){
    float m = sums_e[t] / (float)NE;
    float v = sums_e[EIN+t] / (float)NE - m*m;
    float sc = ge[t] * rsqrtf(v + BNEPS);
    ss[t] = sc; ss[EIN+t] = be[t] - m*sc;
  } else if(t < EIN + NIN){
    int c = t - EIN;
    float m = sums_x[c] / (float)NN;
    float v = sums_x[NIN+c] / (float)NN - m*m;
    float sc = gx[c] * rsqrtf(v + BNEPS);
    ss[2*EIN + c] = sc; ss[2*EIN + NIN + c] = bx[c] - m*sc;
  }
}

// ---------------------------------------------------------------- fold BN(e) into W1/b1 + predictor
__global__ void fold_kernel(const float* __restrict__ ss,
                            const float* __restrict__ l0W1, const float* __restrict__ l0b1,
                            const float* __restrict__ l1W1, const float* __restrict__ l1b1,
                            const float* __restrict__ l2W1, const float* __restrict__ l2b1,
                            const float* __restrict__ emW1, const float* __restrict__ emb1,
                            float* __restrict__ W1f, float* __restrict__ b1f,
                            float* __restrict__ emW1f, float* __restrict__ emb1f){
  int t = threadIdx.x;
  int seg = t >> 5, j = t & 31;
  if(seg == 0){
    if(j < NIN){
      float acc = l0b1[j];
      for(int k = 0; k < EIN; k++){
        W1f[0*640 + k*NIN + j] = ss[k] * l0W1[k*NIN + j];
        acc += ss[EIN+k] * l0W1[k*NIN + j];
      }
      b1f[0*32 + j] = acc;
    }
  } else if(seg == 1){
    float acc = l1b1[j];
    for(int k = 0; k < EIN; k++){
      W1f[1*640 + k*HD + j] = ss[k] * l1W1[k*HD + j];
      acc += ss[EIN+k] * l1W1[k*HD + j];
    }
    b1f[1*32 + j] = acc;
  } else if(seg == 2){
    float acc = l2b1[j];
    for(int k = 0; k < EIN; k++){
      W1f[2*640 + k*HD + j] = ss[k] * l2W1[k*HD + j];
      acc += ss[EIN+k] * l2W1[k*HD + j];
    }
    b1f[2*32 + j] = acc;
  } else if(seg == 3){
    float acc = emb1[j];
    for(int k = 0; k < EIN; k++){
      emW1f[k*HD + j] = ss[k] * emW1[(2*HD+k)*HD + j];
      acc += ss[EIN+k] * emW1[(2*HD+k)*HD + j];
    }
    emb1f[j] = acc;
  }
}

template<int C>
__global__ void normalize_kernel(const float* __restrict__ in, float* __restrict__ outp,
                                 const float* __restrict__ ss, int rows){
  int n = rows * C;
  int stride = gridDim.x * blockDim.x;
  for(int i = blockIdx.x*blockDim.x + threadIdx.x; i < n; i += stride){
    int c = i % C;
    outp[i] = in[i] * ss[c] + ss[C + c];
  }
}

// ---------------------------------------------------------------- pack W2 into B-fragment layout (bf16)
template<int DIN, int NCH>
__global__ void w2pack_kernel(const float* __restrict__ W2, short* __restrict__ outp){
  int idx = blockIdx.x*blockDim.x + threadIdx.x;
  if(idx >= NCH*512) return;
  int c = idx >> 9, l = (idx >> 3) & 63, j = idx & 7;
  int k = 8*(l>>4) + j;
  int n = c*16 + (l & 15);
  float v = (k < DIN) ? W2[(size_t)k*(DIN*HD) + n] : 0.f;
  outp[idx] = (short)f2bf(v);
}

// ---------------------------------------------------------------- predictor weight staging: predW [224][32] fp32
// rows 0..63 emW1(xr,xc) | 64..82 emW1f(e, BN-folded) | 83..95 zero | 96..127 emW2 | 128..191 nm1W1 | 192..223 nm1W2
__global__ void predprep_kernel(const float* __restrict__ emW1,
                                const float* __restrict__ emW1f, const float* __restrict__ emb1f,
                                const float* __restrict__ emW2,  const float* __restrict__ emb2,
                                const float* __restrict__ nm1W1, const float* __restrict__ nm1b1,
                                const float* __restrict__ nm1W2, const float* __restrict__ nm1b2,
                                float* __restrict__ predW, float* __restrict__ biasP){
  int i = blockIdx.x*blockDim.x + threadIdx.x;
  if(i < 224*32){
    int k = i >> 5, n = i & 31;
    float v;
    if(k < 64)       v = emW1[k*32 + n];
    else if(k < 83)  v = emW1f[(k-64)*32 + n];
    else if(k < 96)  v = 0.f;
    else if(k < 128) v = emW2[(k-96)*32 + n];
    else if(k < 192) v = nm1W1[(k-128)*32 + n];
    else             v = nm1W2[(k-192)*32 + n];
    predW[i] = v;
  } else if(i < 224*32 + 128){
    int j = i - 224*32; int s = j >> 5, n = j & 31;
    biasP[j] = (s==0) ? emb1f[n] : (s==1) ? emb2[n] : (s==2) ? nm1b1[n] : nm1b2[n];
  }
}

// pack predW into 14 B-frag chunks (kbg 0..6 x nc 0..1), bf16
__global__ void packpred_kernel(const float* __restrict__ predW, short* __restrict__ outp){
  int idx = blockIdx.x*blockDim.x + threadIdx.x;
  if(idx >= 14*512) return;
  int c = idx >> 9, l = (idx >> 3) & 63, j = idx & 7;
  int kbg = c >> 1, nc = c & 1;
  int k = kbg*32 + 8*(l>>4) + j;
  int n = nc*16 + (l & 15);
  outp[idx] = (short)f2bf(predW[k*32 + n]);
}

// ---------------------------------------------------------------- T1 = leaky(e_raw @ W1f + b1f) -> bf16 [E,32]
template<int DIN>
__global__ __launch_bounds__(256) void t1_kernel(const float* __restrict__ eraw,
                                                 const float* __restrict__ W1f,
                                                 const float* __restrict__ b1f,
                                                 short* __restrict__ T1){
  int idx = blockIdx.x*blockDim.x + threadIdx.x;
  if(idx >= NE*16) return;
  int e = idx >> 4, j0 = idx & 15;
  const float* ep = eraw + (size_t)e*EIN;
  float eb[EIN];
  #pragma unroll
  for(int k = 0; k < EIN; k++) eb[k] = ep[k];

  float a = b1f[j0];
  #pragma unroll
  for(int k = 0; k < EIN; k++) a = fmaf(eb[k], W1f[k*DIN + j0], a);
  short r0 = (short)f2bf(lky(a));
  short r1 = 0;
  if(DIN == 32){
    float b = b1f[j0 + 16];
    #pragma unroll
    for(int k = 0; k < EIN; k++) b = fmaf(eb[k], W1f[k*DIN + j0 + 16], b);
    r1 = (short)f2bf(lky(b));
  }
  T1[(size_t)e*32 + j0]      = r0;
  T1[(size_t)e*32 + j0 + 16] = r1;
}

// ---------------------------------------------------------------- x_next = x @ root + bias
template<int DIN>
__global__ __launch_bounds__(256) void root_kernel(const float* __restrict__ xin,
                                                   const float* __restrict__ root,
                                                   const float* __restrict__ bias,
                                                   float* __restrict__ xout){
  int idx = blockIdx.x*blockDim.x + threadIdx.x;
  if(idx >= NN * HD) return;
  int node = idx / HD, o = idx % HD;
  const float* xr = xin + (size_t)node * DIN;
  float acc = bias[o];
  #pragma unroll
  for(int k = 0; k < DIN; k++) acc += xr[k] * root[k*HD + o];
  xout[idx] = acc;
}

// ---------------------------------------------------------------- MFMA msg (unchanged — proven)
template<int DIN, int NCH>
__global__ __launch_bounds__(256) void msg3_kernel(const short* __restrict__ T1,
                                                   const int* __restrict__ rowp,
                                                   const int* __restrict__ colp,
                                                   const float* __restrict__ xin,
                                                   const short* __restrict__ w2p,
                                                   const float* __restrict__ b2,
                                                   float* __restrict__ xout){
  constexpr int XGP = DIN + 4;
  __shared__ short w2s[NCH*512];
  __shared__ float b2s[NCH*16];
  __shared__ float xgs[4][16][XGP];

  const int tid  = threadIdx.x;
  const int l    = tid & 63;
  const int wid  = tid >> 6;
  const int grp  = l >> 4, lo16 = l & 15;

  for(int t = tid; t < NCH*64; t += 256)
    ((i32x4*)w2s)[t] = ((const i32x4*)w2p)[t];
  for(int t = tid; t < NCH*16; t += 256) b2s[t] = b2[t];
  __syncthreads();

  int tile = blockIdx.x*4 + wid;
  if(tile >= NTILES) return;
  int e0 = tile * 16;

  {
    int r = rowp[e0 + lo16];
    if(DIN == 32){
      const f32x4* xp = (const f32x4*)(xin + (size_t)r*32 + grp*8);
      *(f32x4*)&xgs[wid][lo16][grp*8]     = xp[0];
      *(f32x4*)&xgs[wid][lo16][grp*8 + 4] = xp[1];
    } else {
      const f32x4* xp = (const f32x4*)(xin + (size_t)r*16 + grp*4);
      *(f32x4*)&xgs[wid][lo16][grp*4] = xp[0];
    }
  }

  bfrag af = *(const bfrag*)(T1 + (size_t)(e0 + lo16)*32 + grp*8);

  f32x4 m0; m0[0]=0.f; m0[1]=0.f; m0[2]=0.f; m0[3]=0.f;
  f32x4 m1 = m0;
  const f32x4 z = m0;

  #pragma unroll 4
  for(int i = 0; i < NCH/2; i++){
    bfrag b0 = *(const bfrag*)&w2s[((2*i  )*64 + l)*8];
    bfrag b1 = *(const bfrag*)&w2s[((2*i+1)*64 + l)*8];
    f32x4 u0 = __builtin_amdgcn_mfma_f32_16x16x32_bf16(af, b0, z, 0, 0, 0);
    f32x4 u1 = __builtin_amdgcn_mfma_f32_16x16x32_bf16(af, b1, z, 0, 0, 0);
    float bv0 = b2s[(2*i)*16 + lo16];
    float bv1 = b2s[(2*i+1)*16 + lo16];
    #pragma unroll
    for(int reg = 0; reg < 4; reg++){
      float xv = xgs[wid][grp*4 + reg][i];
      float a0 = u0[reg] + bv0; a0 = fmaxf(a0, LEAK*a0);
      float a1 = u1[reg] + bv1; a1 = fmaxf(a1, LEAK*a1);
      m0[reg] = fmaf(xv, a0, m0[reg]);
      m1[reg] = fmaf(xv, a1, m1[reg]);
    }
  }

  #pragma unroll
  for(int reg = 0; reg < 4; reg++){
    int ce = colp[e0 + grp*4 + reg];
    atomicAdd(&xout[(size_t)ce*HD + lo16],      m0[reg]);
    atomicAdd(&xout[(size_t)ce*HD + 16 + lo16], m1[reg]);
  }
}

// ---------------------------------------------------------------- predictor v3: MFMA 16-edge tiles, split-bf16 activations
// stages: u = lky([xr|xc|e]@W + b) ; e2 = u@W + b ; vv = lky([xr|e2]@W + b) ; h = vv@W + b -> scatter
__global__ __launch_bounds__(256) void pred4_kernel(const float* __restrict__ x,
                                                    const float* __restrict__ eraw,
                                                    const int* __restrict__ rowp,
                                                    const int* __restrict__ colp,
                                                    const short* __restrict__ predpk,
                                                    const float* __restrict__ biasP,
                                                    float* __restrict__ agg,
                                                    float* __restrict__ cnt){
  __shared__ short predw[14*512];          // B-frags
  __shared__ float biasl[128];
  __shared__ short fAhi[4][16][104];       // features [xr|xc|e] (cols 32..63 reused for e2)
  __shared__ short fAlo[4][16][104];
  __shared__ short uAhi[4][16][40];        // u, then vv
  __shared__ short uAlo[4][16][40];

  const int tid = threadIdx.x;
  for(int t = tid; t < 14*512/8; t += 256)
    ((i32x4*)predw)[t] = ((const i32x4*)predpk)[t];
  if(tid < 128) biasl[tid] = biasP[tid];
  __syncthreads();

  const int l = tid & 63, wid = tid >> 6;
  const int grp = l >> 4, lo16 = l & 15;
  const int tile = blockIdx.x*4 + wid;
  if(tile >= NTILES) return;
  const int e0 = tile * 16;

  // ---- build feature tile (hi/lo)
  {
    float v[8];
    i32x4 h4, l4;
    int r = rowp[e0 + lo16];
    const float* xp = x + (size_t)r*32 + grp*8;
    #pragma unroll
    for(int j = 0; j < 8; j++) v[j] = xp[j];
    split8(v, h4, l4);
    *(i32x4*)&fAhi[wid][lo16][grp*8] = h4;
    *(i32x4*)&fAlo[wid][lo16][grp*8] = l4;

    int c = colp[e0 + lo16];
    const float* xq = x + (size_t)c*32 + grp*8;
    #pragma unroll
    for(int j = 0; j < 8; j++) v[j] = xq[j];
    split8(v, h4, l4);
    *(i32x4*)&fAhi[wid][lo16][32 + grp*8] = h4;
    *(i32x4*)&fAlo[wid][lo16][32 + grp*8] = l4;

    const float* ep = eraw + (size_t)(e0 + lo16)*EIN;
    #pragma unroll
    for(int j = 0; j < 8; j++){ int f = grp*8 + j; v[j] = (f < EIN) ? ep[f] : 0.f; }
    split8(v, h4, l4);
    *(i32x4*)&fAhi[wid][lo16][64 + grp*8] = h4;
    *(i32x4*)&fAlo[wid][lo16][64 + grp*8] = l4;
  }

  f32x4 z; z[0]=0.f; z[1]=0.f; z[2]=0.f; z[3]=0.f;

  // ---- stage u: K=96 (kbg 0..2), leaky -> uA
  #pragma unroll
  for(int nc = 0; nc < 2; nc++){
    f32x4 acc = z;
    #pragma unroll
    for(int kb = 0; kb < 3; kb++){
      bfrag b  = *(const bfrag*)&predw[((kb*2 + nc)*64 + l)*8];
      bfrag ah = *(const bfrag*)&fAhi[wid][lo16][kb*32 + grp*8];
      bfrag al = *(const bfrag*)&fAlo[wid][lo16][kb*32 + grp*8];
      acc = __builtin_amdgcn_mfma_f32_16x16x32_bf16(ah, b, acc, 0, 0, 0);
      acc = __builtin_amdgcn_mfma_f32_16x16x32_bf16(al, b, acc, 0, 0, 0);
    }
    int n = nc*16 + lo16;
    float bv = biasl[n];
    #pragma unroll
    for(int reg = 0; reg < 4; reg++){
      float uv = acc[reg] + bv; uv = fmaxf(uv, LEAK*uv);
      unsigned hh = f2bf(uv);
      float hf = __uint_as_float(hh << 16);
      uAhi[wid][grp*4 + reg][n] = (short)hh;
      uAlo[wid][grp*4 + reg][n] = (short)f2bf(uv - hf);
    }
  }

  // ---- stage e2: K=32 (kbg 3), linear -> fA cols 32..63
  #pragma unroll
  for(int nc = 0; nc < 2; nc++){
    f32x4 acc = z;
    bfrag b  = *(const bfrag*)&predw[((6 + nc)*64 + l)*8];
    bfrag ah = *(const bfrag*)&uAhi[wid][lo16][grp*8];
    bfrag al = *(const bfrag*)&uAlo[wid][lo16][grp*8];
    acc = __builtin_amdgcn_mfma_f32_16x16x32_bf16(ah, b, acc, 0, 0, 0);
    acc = __builtin_amdgcn_mfma_f32_16x16x32_bf16(al, b, acc, 0, 0, 0);
    int n = nc*16 + lo16;
    float bv = biasl[32 + n];
    #pragma unroll
    for(int reg = 0; reg < 4; reg++){
      float ev = acc[reg] + bv;
      unsigned hh = f2bf(ev);
      float hf = __uint_as_float(hh << 16);
      fAhi[wid][grp*4 + reg][32 + n] = (short)hh;
      fAlo[wid][grp*4 + reg][32 + n] = (short)f2bf(ev - hf);
    }
  }

  // ---- stage vv: K=64 (kbg 4..5: [xr|e2]), leaky -> uA
  #pragma unroll
  for(int nc = 0; nc < 2; nc++){
    f32x4 acc = z;
    #pragma unroll
    for(int kb = 0; kb < 2; kb++){
      bfrag b  = *(const bfrag*)&predw[(((4 + kb)*2 + nc)*64 + l)*8];
      bfrag ah = *(const bfrag*)&fAhi[wid][lo16][kb*32 + grp*8];
      bfrag al = *(const bfrag*)&fAlo[wid][lo16][kb*32 + grp*8];
      acc = __builtin_amdgcn_mfma_f32_16x16x32_bf16(ah, b, acc, 0, 0, 0);
      acc = __builtin_amdgcn_mfma_f32_16x16x32_bf16(al, b, acc, 0, 0, 0);
    }
    int n = nc*16 + lo16;
    float bv = biasl[64 + n];
    #pragma unroll
    for(int reg = 0; reg < 4; reg++){
      float vv = acc[reg] + bv; vv = fmaxf(vv, LEAK*vv);
      unsigned hh = f2bf(vv);
      float hf = __uint_as_float(hh << 16);
      uAhi[wid][grp*4 + reg][n] = (short)hh;
      uAlo[wid][grp*4 + reg][n] = (short)f2bf(vv - hf);
    }
  }

  // ---- stage h: K=32 (kbg 6), linear -> atomic scatter
  int ce[4];
  #pragma unroll
  for(int reg = 0; reg < 4; reg++) ce[reg] = colp[e0 + grp*4 + reg];

  #pragma unroll
  for(int nc = 0; nc < 2; nc++){
    f32x4 acc = z;
    bfrag b  = *(const bfrag*)&predw[((12 + nc)*64 + l)*8];
    bfrag ah = *(const bfrag*)&uAhi[wid][lo16][grp*8];
    bfrag al = *(const bfrag*)&uAlo[wid][lo16][grp*8];
    acc = __builtin_amdgcn_mfma_f32_16x16x32_bf16(ah, b, acc, 0, 0, 0);
    acc = __builtin_amdgcn_mfma_f32_16x16x32_bf16(al, b, acc, 0, 0, 0);
    int n = nc*16 + lo16;
    float bv = biasl[96 + n];
    #pragma unroll
    for(int reg = 0; reg < 4; reg++)
      atomicAdd(&agg[(size_t)ce[reg]*HD + n], acc[reg] + bv);
  }

  if(l < 16) atomicAdd(&cnt[colp[e0 + l]], 1.f);
}

// ---------------------------------------------------------------- final node model + log_softmax
__global__ __launch_bounds__(256) void final_kernel(const float* __restrict__ x,
                                                    const float* __restrict__ agg,
                                                    const float* __restrict__ cnt,
                                                    const float* __restrict__ W1,
                                                    const float* __restrict__ b1,
                                                    const float* __restrict__ W2,
                                                    const float* __restrict__ b2,
                                                    float* __restrict__ out){
  int n = blockIdx.x*blockDim.x + threadIdx.x;
  if(n >= NN) return;
  float inv = 1.f / fmaxf(cnt[n], 1.f);
  const float* xp = x + (size_t)n * HD;
  const float* ap = agg + (size_t)n * HD;

  float t[HD];
  #pragma unroll
  for(int o = 0; o < HD; o++) t[o] = b1[o];
  #pragma unroll
  for(int k = 0; k < HD; k++){ float v = xp[k]; const float* wp = W1 + k*HD;
    #pragma unroll
    for(int o = 0; o < HD; o++) t[o] += v * wp[o]; }
  #pragma unroll
  for(int k = 0; k < HD; k++){ float v = ap[k] * inv; const float* wp = W1 + (HD+k)*HD;
    #pragma unroll
    for(int o = 0; o < HD; o++) t[o] += v * wp[o]; }

  float a0 = b2[0], a1 = b2[1];
  #pragma unroll
  for(int k = 0; k < HD; k++){ float v = lky(t[k]); a0 += v * W2[k*2]; a1 += v * W2[k*2+1]; }

  float m  = fmaxf(a0, a1);
  float ls = m + logf(expf(a0 - m) + expf(a1 - m));
  out[(size_t)n*2]   = a0 - ls;
  out[(size_t)n*2+1] = a1 - ls;
}

// ---------------------------------------------------------------- launch
extern "C" void kernel_launch(void* const* d_in, const int* in_sizes, int n_in,
                              void* d_out, int out_size, void* d_ws, size_t ws_size,
                              hipStream_t stream){
  const float* x  = (const float*)d_in[0];
  const int*   ei = (const int*)  d_in[1];
  const float* e  = (const float*)d_in[2];
  const float* bn_node_g = (const float*)d_in[4];
  const float* bn_node_b = (const float*)d_in[5];
  const float* bn_edge_g = (const float*)d_in[6];
  const float* bn_edge_b = (const float*)d_in[7];
  const float* lW1[3], *lb1[3], *lW2[3], *lb2[3], *lroot[3], *lbias[3];
  for(int l = 0; l < 3; l++){
    lW1[l]   = (const float*)d_in[8 + 6*l + 0];
    lb1[l]   = (const float*)d_in[8 + 6*l + 1];
    lW2[l]   = (const float*)d_in[8 + 6*l + 2];
    lb2[l]   = (const float*)d_in[8 + 6*l + 3];
    lroot[l] = (const float*)d_in[8 + 6*l + 4];
    lbias[l] = (const float*)d_in[8 + 6*l + 5];
  }
  const float* emW1  = (const float*)d_in[26];
  const float* emb1  = (const float*)d_in[27];
  const float* emW2  = (const float*)d_in[28];
  const float* emb2  = (const float*)d_in[29];
  const float* nm1W1 = (const float*)d_in[30];
  const float* nm1b1 = (const float*)d_in[31];
  const float* nm1W2 = (const float*)d_in[32];
  const float* nm1b2 = (const float*)d_in[33];
  const float* nm2W1 = (const float*)d_in[34];
  const float* nm2b1 = (const float*)d_in[35];
  const float* nm2W2 = (const float*)d_in[36];
  const float* nm2b2 = (const float*)d_in[37];

  const int* rowp = ei;
  const int* colp = ei + NE;

  // workspace layout (float units)
  float* ws   = (float*)d_ws;
  float* x_bn = ws;                                 // NN*16
  float* x_a  = x_bn + (size_t)NN*NIN;              // NN*32
  float* x_b  = x_a  + (size_t)NN*HD;               // NN*32
  float* scr  = x_b  + (size_t)NN*HD;               // 16384 floats
  float* sums_e = scr;           // 38
  float* sums_x = scr + 64;      // 32
  float* ss     = scr + 128;     // 70
  float* W1f    = scr + 256;     // 1920
  float* b1f    = scr + 2304;    // 96
  float* emW1f  = scr + 2432;    // 608
  float* emb1f  = scr + 3072;    // 32
  float* biasP  = scr + 3104;    // 128
  float* predW  = scr + 3232;    // 7168
  short* w2pk   = (short*)(scr + 16384);            // 3*32768 shorts
  short* predpk = w2pk + 3*32768;                   // 7168 shorts (pad to 8192)
  short* T1     = predpk + 8192;                    // NE*32 bf16
  float* agg    = (float*)T1;                       // alias (T1 dead after layer-2 msg)
  float* cnt    = agg + (size_t)NN*HD;

  zero_kernel<<<1, 256, 0, stream>>>(scr, 256);
  stats_kernel<EIN><<<256, 256, 0, stream>>>(e, NE, sums_e);
  stats_kernel<NIN><<<256, 256, 0, stream>>>(x, NN, sums_x);
  finalize_stats<<<1, 64, 0, stream>>>(sums_e, sums_x, bn_edge_g, bn_edge_b,
                                       bn_node_g, bn_node_b, ss);
  fold_kernel<<<1, 128, 0, stream>>>(ss, lW1[0], lb1[0], lW1[1], lb1[1], lW1[2], lb1[2],
                                     emW1, emb1, W1f, b1f, emW1f, emb1f);
  predprep_kernel<<<29, 256, 0, stream>>>(emW1, emW1f, emb1f, emW2, emb2,
                                          nm1W1, nm1b1, nm1W2, nm1b2, predW, biasP);
  packpred_kernel<<<28, 256, 0, stream>>>(predW, predpk);
  normalize_kernel<NIN><<<1024, 256, 0, stream>>>(x, x_bn, ss + 2*EIN, NN);

  w2pack_kernel<NIN, 32><<<(32*512 + 255)/256, 256, 0, stream>>>(lW2[0], w2pk + 0*32768);
  w2pack_kernel<HD,  64><<<(64*512 + 255)/256, 256, 0, stream>>>(lW2[1], w2pk + 1*32768);
  w2pack_kernel<HD,  64><<<(64*512 + 255)/256, 256, 0, stream>>>(lW2[2], w2pk + 2*32768);

  const int t1blocks = (NE*16 + 255)/256;
  const int nblocks  = (NN*HD + 255)/256;
  const int mblocks  = (NTILES + 3)/4;

  // layer 0 (din=16): x_bn -> x_a
  root_kernel<NIN><<<nblocks, 256, 0, stream>>>(x_bn, lroot[0], lbias[0], x_a);
  t1_kernel<NIN><<<t1blocks, 256, 0, stream>>>(e, W1f + 0*640, b1f + 0*32, T1);
  msg3_kernel<NIN, 32><<<mblocks, 256, 0, stream>>>(T1, rowp, colp, x_bn,
                                                    w2pk + 0*32768, lb2[0], x_a);
  // layer 1 (din=32): x_a -> x_b
  root_kernel<HD><<<nblocks, 256, 0, stream>>>(x_a, lroot[1], lbias[1], x_b);
  t1_kernel<HD><<<t1blocks, 256, 0, stream>>>(e, W1f + 1*640, b1f + 1*32, T1);
  msg3_kernel<HD, 64><<<mblocks, 256, 0, stream>>>(T1, rowp, colp, x_a,
                                                   w2pk + 1*32768, lb2[1], x_b);
  // layer 2 (din=32): x_b -> x_a
  root_kernel<HD><<<nblocks, 256, 0, stream>>>(x_b, lroot[2], lbias[2], x_a);
  t1_kernel<HD><<<t1blocks, 256, 0, stream>>>(e, W1f + 2*640, b1f + 2*32, T1);
  msg3_kernel<HD, 64><<<mblocks, 256, 0, stream>>>(T1, rowp, colp, x_b,
                                                   w2pk + 2*32768, lb2[2], x_a);

  // predictor (agg/cnt alias T1 region — zero first)
  zero_kernel<<<2048, 256, 0, stream>>>(agg, NN*HD + NN);
  pred4_kernel<<<mblocks, 256, 0, stream>>>(x_a, e, rowp, colp, predpk, biasP, agg, cnt);
  final_kernel<<<(NN + 255)/256, 256, 0, stream>>>(x_a, agg, cnt,
                                                   nm2W1, nm2b1, nm2W2, nm2b2,
                                                   (float*)d_out);
}

// Round 6
// 305.763 us; speedup vs baseline: 2.5765x; 1.5029x over previous
//
#include <hip/hip_runtime.h>
#include <math.h>

constexpr int NN  = 50000;   // nodes
constexpr int NE  = 150000;  // edges
constexpr int NIN = 16;      // node features in
constexpr int EIN = 19;      // edge features in
constexpr int HD  = 32;      // hidden H
constexpr int NTILES = NE / 16;  // 9375
constexpr int NBLK_E = 128;
constexpr int NBLK_X = 64;

#define LEAK  0.1f
#define BNEPS 1e-5f

typedef __attribute__((ext_vector_type(8))) short bfrag;
typedef __attribute__((ext_vector_type(4))) float f32x4;
typedef __attribute__((ext_vector_type(4))) int   i32x4;

__device__ __forceinline__ float lky(float v){ return fmaxf(v, LEAK*v); }
__device__ __forceinline__ unsigned f2bf(float f){
  unsigned u = __float_as_uint(f);
  return ((u + 0x7FFFu + ((u >> 16) & 1u)) >> 16);   // RNE
}
__device__ __forceinline__ void split8(const float* v, i32x4& h4, i32x4& l4){
  unsigned hs[8], ls[8];
  #pragma unroll
  for(int j = 0; j < 8; j++){
    unsigned hh = f2bf(v[j]);
    float hf = __uint_as_float(hh << 16);
    hs[j] = hh; ls[j] = f2bf(v[j] - hf);
  }
  h4[0] = (int)(hs[0] | (hs[1]<<16)); h4[1] = (int)(hs[2] | (hs[3]<<16));
  h4[2] = (int)(hs[4] | (hs[5]<<16)); h4[3] = (int)(hs[6] | (hs[7]<<16));
  l4[0] = (int)(ls[0] | (ls[1]<<16)); l4[1] = (int)(ls[2] | (ls[3]<<16));
  l4[2] = (int)(ls[4] | (ls[5]<<16)); l4[3] = (int)(ls[6] | (ls[7]<<16));
}

// ---------------------------------------------------------------- zero
__global__ void zero_kernel(float* __restrict__ p, int n){
  int stride = gridDim.x * blockDim.x;
  for(int i = blockIdx.x*blockDim.x + threadIdx.x; i < n; i += stride) p[i] = 0.f;
}

// ---------------------------------------------------------------- stats: coalesced, static col idx, block partials
// e-section (blocks 0..127): groups of 4 rows = 19 float4, col = (4m+j)%19 (static)
// x-section (blocks 128..191): 1 row = 4 float4, col = 4m+j (static)
__global__ __launch_bounds__(256) void stats_all_kernel(const float* __restrict__ e,
                                                        const float* __restrict__ x,
                                                        float* __restrict__ partial_e,
                                                        float* __restrict__ partial_x){
  __shared__ float red[4][40];
  const int tid = threadIdx.x, lane = tid & 63, wid = tid >> 6;
  if(blockIdx.x < NBLK_E){
    float s[EIN], q[EIN];
    #pragma unroll
    for(int c = 0; c < EIN; c++){ s[c] = 0.f; q[c] = 0.f; }
    const int gstride = NBLK_E * 256;
    for(int g = blockIdx.x*256 + tid; g < NE/4; g += gstride){
      const f32x4* p = (const f32x4*)(e + (size_t)g * 76);
      #pragma unroll
      for(int m = 0; m < 19; m++){
        f32x4 v = p[m];
        #pragma unroll
        for(int j = 0; j < 4; j++){
          int c = (4*m + j) % 19;
          s[c] += v[j]; q[c] = fmaf(v[j], v[j], q[c]);
        }
      }
    }
    #pragma unroll
    for(int off = 32; off; off >>= 1){
      #pragma unroll
      for(int c = 0; c < EIN; c++){ s[c] += __shfl_xor(s[c], off); q[c] += __shfl_xor(q[c], off); }
    }
    if(lane == 0){
      #pragma unroll
      for(int c = 0; c < EIN; c++){ red[wid][c] = s[c]; red[wid][20 + c] = q[c]; }
    }
    __syncthreads();
    if(tid < 39 && tid != 19)
      partial_e[blockIdx.x*40 + tid] = red[0][tid] + red[1][tid] + red[2][tid] + red[3][tid];
  } else {
    float s[NIN], q[NIN];
    #pragma unroll
    for(int c = 0; c < NIN; c++){ s[c] = 0.f; q[c] = 0.f; }
    const int bid = blockIdx.x - NBLK_E;
    const int gstride = NBLK_X * 256;
    for(int r = bid*256 + tid; r < NN; r += gstride){
      const f32x4* p = (const f32x4*)(x + (size_t)r * NIN);
      #pragma unroll
      for(int m = 0; m < 4; m++){
        f32x4 v = p[m];
        #pragma unroll
        for(int j = 0; j < 4; j++){
          int c = 4*m + j;
          s[c] += v[j]; q[c] = fmaf(v[j], v[j], q[c]);
        }
      }
    }
    #pragma unroll
    for(int off = 32; off; off >>= 1){
      #pragma unroll
      for(int c = 0; c < NIN; c++){ s[c] += __shfl_xor(s[c], off); q[c] += __shfl_xor(q[c], off); }
    }
    if(lane == 0){
      #pragma unroll
      for(int c = 0; c < NIN; c++){ red[wid][c] = s[c]; red[wid][16 + c] = q[c]; }
    }
    __syncthreads();
    if(tid < 32)
      partial_x[bid*32 + tid] = red[0][tid] + red[1][tid] + red[2][tid] + red[3][tid];
  }
}

// ---------------------------------------------------------------- prep: reduce partials -> ss; fold; predprep; packpred
__global__ __launch_bounds__(1024) void prep_kernel(const float* __restrict__ partial_e,
                                                    const float* __restrict__ partial_x,
                                                    const float* __restrict__ ge, const float* __restrict__ be,
                                                    const float* __restrict__ gx, const float* __restrict__ bx,
                                                    const float* __restrict__ l0W1, const float* __restrict__ l0b1,
                                                    const float* __restrict__ l1W1, const float* __restrict__ l1b1,
                                                    const float* __restrict__ l2W1, const float* __restrict__ l2b1,
                                                    const float* __restrict__ emW1, const float* __restrict__ emb1,
                                                    const float* __restrict__ emW2, const float* __restrict__ emb2,
                                                    const float* __restrict__ nm1W1, const float* __restrict__ nm1b1,
                                                    const float* __restrict__ nm1W2, const float* __restrict__ nm1b2,
                                                    float* __restrict__ ss_g, float* __restrict__ W1f,
                                                    float* __restrict__ b1f, float* __restrict__ biasP,
                                                    short* __restrict__ predpk){
  __shared__ float ss[70];
  __shared__ float emW1f[608];
  __shared__ float emb1f[32];
  __shared__ float predW[7168];
  const int t = threadIdx.x;

  // phase 0/1: reduce partials, finalize scale/shift
  if(t < EIN){
    float s = 0.f, q = 0.f;
    for(int b = 0; b < NBLK_E; b++){ s += partial_e[b*40 + t]; q += partial_e[b*40 + 20 + t]; }
    float m = s / (float)NE;
    float v = q / (float)NE - m*m;
    float sc = ge[t] * rsqrtf(v + BNEPS);
    ss[t] = sc; ss[EIN + t] = be[t] - m*sc;
  } else if(t >= 32 && t < 32 + NIN){
    int c = t - 32;
    float s = 0.f, q = 0.f;
    for(int b = 0; b < NBLK_X; b++){ s += partial_x[b*32 + c]; q += partial_x[b*32 + 16 + c]; }
    float m = s / (float)NN;
    float v = q / (float)NN - m*m;
    float sc = gx[c] * rsqrtf(v + BNEPS);
    ss[2*EIN + c] = sc; ss[2*EIN + NIN + c] = bx[c] - m*sc;
  }
  __syncthreads();
  if(t < 70) ss_g[t] = ss[t];

  // phase 2: fold BN(e) into layer W1/b1 (global) and predictor edge rows (LDS)
  if(t < 128){
    int seg = t >> 5, j = t & 31;
    if(seg == 0){
      if(j < NIN){
        float acc = l0b1[j];
        for(int k = 0; k < EIN; k++){
          W1f[0*640 + k*NIN + j] = ss[k] * l0W1[k*NIN + j];
          acc += ss[EIN+k] * l0W1[k*NIN + j];
        }
        b1f[0*32 + j] = acc;
      }
    } else if(seg == 1){
      float acc = l1b1[j];
      for(int k = 0; k < EIN; k++){
        W1f[1*640 + k*HD + j] = ss[k] * l1W1[k*HD + j];
        acc += ss[EIN+k] * l1W1[k*HD + j];
      }
      b1f[1*32 + j] = acc;
    } else if(seg == 2){
      float acc = l2b1[j];
      for(int k = 0; k < EIN; k++){
        W1f[2*640 + k*HD + j] = ss[k] * l2W1[k*HD + j];
        acc += ss[EIN+k] * l2W1[k*HD + j];
      }
      b1f[2*32 + j] = acc;
    } else {
      float acc = emb1[j];
      for(int k = 0; k < EIN; k++){
        emW1f[k*HD + j] = ss[k] * emW1[(2*HD+k)*HD + j];
        acc += ss[EIN+k] * emW1[(2*HD+k)*HD + j];
      }
      emb1f[j] = acc;
    }
  }
  __syncthreads();

  // phase 3: assemble predictor weight block [224][32] (LDS) + biases (global)
  for(int i = t; i < 224*32; i += 1024){
    int k = i >> 5, n = i & 31;
    float v;
    if(k < 64)       v = emW1[k*32 + n];
    else if(k < 83)  v = emW1f[(k-64)*32 + n];
    else if(k < 96)  v = 0.f;
    else if(k < 128) v = emW2[(k-96)*32 + n];
    else if(k < 192) v = nm1W1[(k-128)*32 + n];
    else             v = nm1W2[(k-192)*32 + n];
    predW[i] = v;
  }
  if(t < 128){
    int s = t >> 5, n = t & 31;
    biasP[t] = (s==0) ? emb1f[n] : (s==1) ? emb2[n] : (s==2) ? nm1b1[n] : nm1b2[n];
  }
  __syncthreads();

  // phase 4: pack predW -> B-frag bf16 (global)
  for(int idx = t; idx < 14*512; idx += 1024){
    int c = idx >> 9, l = (idx >> 3) & 63, j = idx & 7;
    int kbg = c >> 1, nc = c & 1;
    int k = kbg*32 + 8*(l>>4) + j;
    int n = nc*16 + (l & 15);
    predpk[idx] = (short)f2bf(predW[k*32 + n]);
  }
}

// ---------------------------------------------------------------- pack all three W2 -> bf16 B-frag layout
__global__ __launch_bounds__(256) void w2pack_all_kernel(const float* __restrict__ W20,
                                                         const float* __restrict__ W21,
                                                         const float* __restrict__ W22,
                                                         short* __restrict__ w2pk){
  int idx = blockIdx.x*256 + threadIdx.x;
  if(idx >= 81920) return;
  const float* W2; int DIN, base, ci;
  if(idx < 16384){ W2 = W20; DIN = 16; base = 0;     ci = idx; }
  else if(idx < 49152){ W2 = W21; DIN = 32; base = 32768; ci = idx - 16384; }
  else { W2 = W22; DIN = 32; base = 65536; ci = idx - 49152; }
  int c = ci >> 9, l = (ci >> 3) & 63, j = ci & 7;
  int k = 8*(l>>4) + j;
  int n = c*16 + (l & 15);
  float v = (k < DIN) ? W2[(size_t)k*(DIN*HD) + n] : 0.f;
  w2pk[base + ci] = (short)f2bf(v);
}

// ---------------------------------------------------------------- normalize x
template<int C>
__global__ void normalize_kernel(const float* __restrict__ in, float* __restrict__ outp,
                                 const float* __restrict__ ss, int rows){
  int n = rows * C;
  int stride = gridDim.x * blockDim.x;
  for(int i = blockIdx.x*blockDim.x + threadIdx.x; i < n; i += stride){
    int c = i % C;
    outp[i] = in[i] * ss[c] + ss[C + c];
  }
}

// ---------------------------------------------------------------- T1: one thread per edge, full row
template<int DIN>
__global__ __launch_bounds__(256) void t1v2_kernel(const float* __restrict__ eraw,
                                                   const float* __restrict__ W1f,
                                                   const float* __restrict__ b1f,
                                                   short* __restrict__ T1){
  int e = blockIdx.x*256 + threadIdx.x;
  if(e >= NE) return;
  const float* ep = eraw + (size_t)e*EIN;
  float eb[EIN];
  #pragma unroll
  for(int k = 0; k < EIN; k++) eb[k] = ep[k];

  float tv[DIN];
  #pragma unroll
  for(int j = 0; j < DIN; j++) tv[j] = b1f[j];
  #pragma unroll
  for(int k = 0; k < EIN; k++){
    float v = eb[k];
    #pragma unroll
    for(int j = 0; j < DIN; j++) tv[j] = fmaf(v, W1f[k*DIN + j], tv[j]);
  }
  unsigned pk[16];
  #pragma unroll
  for(int p = 0; p < 16; p++){
    unsigned lo, hi;
    if(2*p < DIN){ float a = tv[2*p];   lo = f2bf(fmaxf(a, LEAK*a)); } else lo = 0;
    if(2*p+1 < DIN){ float a = tv[2*p+1]; hi = f2bf(fmaxf(a, LEAK*a)); } else hi = 0;
    pk[p] = lo | (hi << 16);
  }
  i32x4* outp = (i32x4*)(T1 + (size_t)e*32);
  #pragma unroll
  for(int g = 0; g < 4; g++){
    i32x4 v; v[0] = (int)pk[g*4]; v[1] = (int)pk[g*4+1]; v[2] = (int)pk[g*4+2]; v[3] = (int)pk[g*4+3];
    outp[g] = v;
  }
}

// ---------------------------------------------------------------- root: one thread per node, full row
template<int DIN>
__global__ __launch_bounds__(256) void rootv2_kernel(const float* __restrict__ xin,
                                                     const float* __restrict__ root,
                                                     const float* __restrict__ bias,
                                                     float* __restrict__ xout){
  int n = blockIdx.x*256 + threadIdx.x;
  if(n >= NN) return;
  float xr[DIN];
  const f32x4* xp = (const f32x4*)(xin + (size_t)n*DIN);
  #pragma unroll
  for(int g = 0; g < DIN/4; g++){ f32x4 v = xp[g];
    #pragma unroll
    for(int j = 0; j < 4; j++) xr[g*4+j] = v[j]; }
  float acc[HD];
  #pragma unroll
  for(int o = 0; o < HD; o++) acc[o] = bias[o];
  #pragma unroll
  for(int k = 0; k < DIN; k++){
    float v = xr[k];
    #pragma unroll
    for(int o = 0; o < HD; o++) acc[o] = fmaf(v, root[k*HD + o], acc[o]);
  }
  f32x4* outp = (f32x4*)(xout + (size_t)n*HD);
  #pragma unroll
  for(int g = 0; g < 8; g++){ f32x4 v; v[0]=acc[g*4]; v[1]=acc[g*4+1]; v[2]=acc[g*4+2]; v[3]=acc[g*4+3]; outp[g] = v; }
}

// ---------------------------------------------------------------- MFMA msg v4: 4 tiles per wave, bias in C
template<int DIN, int NCH, int TPW>
__global__ __launch_bounds__(256) void msg4_kernel(const short* __restrict__ T1,
                                                   const int* __restrict__ rowp,
                                                   const int* __restrict__ colp,
                                                   const float* __restrict__ xin,
                                                   const short* __restrict__ w2p,
                                                   const float* __restrict__ b2,
                                                   float* __restrict__ xout){
  constexpr int XGP = DIN + 5;
  __shared__ short w2s[NCH*512];
  __shared__ float b2s[NCH*16];
  __shared__ float xgs[4][16][XGP];

  const int tid = threadIdx.x;
  const int l   = tid & 63;
  const int wid = tid >> 6;
  const int grp = l >> 4, lo16 = l & 15;

  for(int t = tid; t < NCH*64; t += 256)
    ((i32x4*)w2s)[t] = ((const i32x4*)w2p)[t];
  for(int t = tid; t < NCH*16; t += 256) b2s[t] = b2[t];
  __syncthreads();

  const int tbase = (blockIdx.x*4 + wid) * TPW;
  for(int tt = 0; tt < TPW; tt++){
    int tile = tbase + tt;
    if(tile >= NTILES) break;
    int e0 = tile * 16;

    {
      int r = rowp[e0 + lo16];
      if(DIN == 32){
        const f32x4* xp = (const f32x4*)(xin + (size_t)r*32 + grp*8);
        *(f32x4*)&xgs[wid][lo16][grp*8]     = xp[0];
        *(f32x4*)&xgs[wid][lo16][grp*8 + 4] = xp[1];
      } else {
        const f32x4* xp = (const f32x4*)(xin + (size_t)r*16 + grp*4);
        *(f32x4*)&xgs[wid][lo16][grp*4] = xp[0];
      }
    }

    bfrag af = *(const bfrag*)(T1 + (size_t)(e0 + lo16)*32 + grp*8);

    f32x4 m0 = {0.f,0.f,0.f,0.f};
    f32x4 m1 = {0.f,0.f,0.f,0.f};

    #pragma unroll 4
    for(int i = 0; i < NCH/2; i++){
      float bv0 = b2s[(2*i)*16 + lo16];
      float bv1 = b2s[(2*i+1)*16 + lo16];
      f32x4 c0 = {bv0,bv0,bv0,bv0};
      f32x4 c1 = {bv1,bv1,bv1,bv1};
      bfrag b0 = *(const bfrag*)&w2s[((2*i  )*64 + l)*8];
      bfrag b1 = *(const bfrag*)&w2s[((2*i+1)*64 + l)*8];
      f32x4 u0 = __builtin_amdgcn_mfma_f32_16x16x32_bf16(af, b0, c0, 0, 0, 0);
      f32x4 u1 = __builtin_amdgcn_mfma_f32_16x16x32_bf16(af, b1, c1, 0, 0, 0);
      #pragma unroll
      for(int reg = 0; reg < 4; reg++){
        float xv = xgs[wid][grp*4 + reg][i];
        float a0 = fmaxf(u0[reg], LEAK*u0[reg]);
        float a1 = fmaxf(u1[reg], LEAK*u1[reg]);
        m0[reg] = fmaf(xv, a0, m0[reg]);
        m1[reg] = fmaf(xv, a1, m1[reg]);
      }
    }

    #pragma unroll
    for(int reg = 0; reg < 4; reg++){
      int ce = colp[e0 + grp*4 + reg];
      atomicAdd(&xout[(size_t)ce*HD + lo16],      m0[reg]);
      atomicAdd(&xout[(size_t)ce*HD + 16 + lo16], m1[reg]);
    }
  }
}

// ---------------------------------------------------------------- predictor v3 (unchanged — proven)
__global__ __launch_bounds__(256) void pred4_kernel(const float* __restrict__ x,
                                                    const float* __restrict__ eraw,
                                                    const int* __restrict__ rowp,
                                                    const int* __restrict__ colp,
                                                    const short* __restrict__ predpk,
                                                    const float* __restrict__ biasP,
                                                    float* __restrict__ agg,
                                                    float* __restrict__ cnt){
  __shared__ short predw[14*512];
  __shared__ float biasl[128];
  __shared__ short fAhi[4][16][104];
  __shared__ short fAlo[4][16][104];
  __shared__ short uAhi[4][16][40];
  __shared__ short uAlo[4][16][40];

  const int tid = threadIdx.x;
  for(int t = tid; t < 14*512/8; t += 256)
    ((i32x4*)predw)[t] = ((const i32x4*)predpk)[t];
  if(tid < 128) biasl[tid] = biasP[tid];
  __syncthreads();

  const int l = tid & 63, wid = tid >> 6;
  const int grp = l >> 4, lo16 = l & 15;
  const int tile = blockIdx.x*4 + wid;
  if(tile >= NTILES) return;
  const int e0 = tile * 16;

  {
    float v[8];
    i32x4 h4, l4;
    int r = rowp[e0 + lo16];
    const float* xp = x + (size_t)r*32 + grp*8;
    #pragma unroll
    for(int j = 0; j < 8; j++) v[j] = xp[j];
    split8(v, h4, l4);
    *(i32x4*)&fAhi[wid][lo16][grp*8] = h4;
    *(i32x4*)&fAlo[wid][lo16][grp*8] = l4;

    int c = colp[e0 + lo16];
    const float* xq = x + (size_t)c*32 + grp*8;
    #pragma unroll
    for(int j = 0; j < 8; j++) v[j] = xq[j];
    split8(v, h4, l4);
    *(i32x4*)&fAhi[wid][lo16][32 + grp*8] = h4;
    *(i32x4*)&fAlo[wid][lo16][32 + grp*8] = l4;

    const float* ep = eraw + (size_t)(e0 + lo16)*EIN;
    #pragma unroll
    for(int j = 0; j < 8; j++){ int f = grp*8 + j; v[j] = (f < EIN) ? ep[f] : 0.f; }
    split8(v, h4, l4);
    *(i32x4*)&fAhi[wid][lo16][64 + grp*8] = h4;
    *(i32x4*)&fAlo[wid][lo16][64 + grp*8] = l4;
  }

  f32x4 z; z[0]=0.f; z[1]=0.f; z[2]=0.f; z[3]=0.f;

  #pragma unroll
  for(int nc = 0; nc < 2; nc++){
    f32x4 acc = z;
    #pragma unroll
    for(int kb = 0; kb < 3; kb++){
      bfrag b  = *(const bfrag*)&predw[((kb*2 + nc)*64 + l)*8];
      bfrag ah = *(const bfrag*)&fAhi[wid][lo16][kb*32 + grp*8];
      bfrag al = *(const bfrag*)&fAlo[wid][lo16][kb*32 + grp*8];
      acc = __builtin_amdgcn_mfma_f32_16x16x32_bf16(ah, b, acc, 0, 0, 0);
      acc = __builtin_amdgcn_mfma_f32_16x16x32_bf16(al, b, acc, 0, 0, 0);
    }
    int n = nc*16 + lo16;
    float bv = biasl[n];
    #pragma unroll
    for(int reg = 0; reg < 4; reg++){
      float uv = acc[reg] + bv; uv = fmaxf(uv, LEAK*uv);
      unsigned hh = f2bf(uv);
      float hf = __uint_as_float(hh << 16);
      uAhi[wid][grp*4 + reg][n] = (short)hh;
      uAlo[wid][grp*4 + reg][n] = (short)f2bf(uv - hf);
    }
  }

  #pragma unroll
  for(int nc = 0; nc < 2; nc++){
    f32x4 acc = z;
    bfrag b  = *(const bfrag*)&predw[((6 + nc)*64 + l)*8];
    bfrag ah = *(const bfrag*)&uAhi[wid][lo16][grp*8];
    bfrag al = *(const bfrag*)&uAlo[wid][lo16][grp*8];
    acc = __builtin_amdgcn_mfma_f32_16x16x32_bf16(ah, b, acc, 0, 0, 0);
    acc = __builtin_amdgcn_mfma_f32_16x16x32_bf16(al, b, acc, 0, 0, 0);
    int n = nc*16 + lo16;
    float bv = biasl[32 + n];
    #pragma unroll
    for(int reg = 0; reg < 4; reg++){
      float ev = acc[reg] + bv;
      unsigned hh = f2bf(ev);
      float hf = __uint_as_float(hh << 16);
      fAhi[wid][grp*4 + reg][32 + n] = (short)hh;
      fAlo[wid][grp*4 + reg][32 + n] = (short)f2bf(ev - hf);
    }
  }

  #pragma unroll
  for(int nc = 0; nc < 2; nc++){
    f32x4 acc = z;
    #pragma unroll
    for(int kb = 0; kb < 2; kb++){
      bfrag b  = *(const bfrag*)&predw[(((4 + kb)*2 + nc)*64 + l)*8];
      bfrag ah = *(const bfrag*)&fAhi[wid][lo16][kb*32 + grp*8];
      bfrag al = *(const bfrag*)&fAlo[wid][lo16][kb*32 + grp*8];
      acc = __builtin_amdgcn_mfma_f32_16x16x32_bf16(ah, b, acc, 0, 0, 0);
      acc = __builtin_amdgcn_mfma_f32_16x16x32_bf16(al, b, acc, 0, 0, 0);
    }
    int n = nc*16 + lo16;
    float bv = biasl[64 + n];
    #pragma unroll
    for(int reg = 0; reg < 4; reg++){
      float vv = acc[reg] + bv; vv = fmaxf(vv, LEAK*vv);
      unsigned hh = f2bf(vv);
      float hf = __uint_as_float(hh << 16);
      uAhi[wid][grp*4 + reg][n] = (short)hh;
      uAlo[wid][grp*4 + reg][n] = (short)f2bf(vv - hf);
    }
  }

  int ce[4];
  #pragma unroll
  for(int reg = 0; reg < 4; reg++) ce[reg] = colp[e0 + grp*4 + reg];

  #pragma unroll
  for(int nc = 0; nc < 2; nc++){
    f32x4 acc = z;
    bfrag b  = *(const bfrag*)&predw[((12 + nc)*64 + l)*8];
    bfrag ah = *(const bfrag*)&uAhi[wid][lo16][grp*8];
    bfrag al = *(const bfrag*)&uAlo[wid][lo16][grp*8];
    acc = __builtin_amdgcn_mfma_f32_16x16x32_bf16(ah, b, acc, 0, 0, 0);
    acc = __builtin_amdgcn_mfma_f32_16x16x32_bf16(al, b, acc, 0, 0, 0);
    int n = nc*16 + lo16;
    float bv = biasl[96 + n];
    #pragma unroll
    for(int reg = 0; reg < 4; reg++)
      atomicAdd(&agg[(size_t)ce[reg]*HD + n], acc[reg] + bv);
  }

  if(l < 16) atomicAdd(&cnt[colp[e0 + l]], 1.f);
}

// ---------------------------------------------------------------- final node model + log_softmax
__global__ __launch_bounds__(256) void final_kernel(const float* __restrict__ x,
                                                    const float* __restrict__ agg,
                                                    const float* __restrict__ cnt,
                                                    const float* __restrict__ W1,
                                                    const float* __restrict__ b1,
                                                    const float* __restrict__ W2,
                                                    const float* __restrict__ b2,
                                                    float* __restrict__ out){
  int n = blockIdx.x*blockDim.x + threadIdx.x;
  if(n >= NN) return;
  float inv = 1.f / fmaxf(cnt[n], 1.f);
  const float* xp = x + (size_t)n * HD;
  const float* ap = agg + (size_t)n * HD;

  float t[HD];
  #pragma unroll
  for(int o = 0; o < HD; o++) t[o] = b1[o];
  #pragma unroll
  for(int k = 0; k < HD; k++){ float v = xp[k]; const float* wp = W1 + k*HD;
    #pragma unroll
    for(int o = 0; o < HD; o++) t[o] += v * wp[o]; }
  #pragma unroll
  for(int k = 0; k < HD; k++){ float v = ap[k] * inv; const float* wp = W1 + (HD+k)*HD;
    #pragma unroll
    for(int o = 0; o < HD; o++) t[o] += v * wp[o]; }

  float a0 = b2[0], a1 = b2[1];
  #pragma unroll
  for(int k = 0; k < HD; k++){ float v = lky(t[k]); a0 += v * W2[k*2]; a1 += v * W2[k*2+1]; }

  float m  = fmaxf(a0, a1);
  float ls = m + logf(expf(a0 - m) + expf(a1 - m));
  out[(size_t)n*2]   = a0 - ls;
  out[(size_t)n*2+1] = a1 - ls;
}

// ---------------------------------------------------------------- launch
extern "C" void kernel_launch(void* const* d_in, const int* in_sizes, int n_in,
                              void* d_out, int out_size, void* d_ws, size_t ws_size,
                              hipStream_t stream){
  const float* x  = (const float*)d_in[0];
  const int*   ei = (const int*)  d_in[1];
  const float* e  = (const float*)d_in[2];
  const float* bn_node_g = (const float*)d_in[4];
  const float* bn_node_b = (const float*)d_in[5];
  const float* bn_edge_g = (const float*)d_in[6];
  const float* bn_edge_b = (const float*)d_in[7];
  const float* lW1[3], *lb1[3], *lW2[3], *lb2[3], *lroot[3], *lbias[3];
  for(int l = 0; l < 3; l++){
    lW1[l]   = (const float*)d_in[8 + 6*l + 0];
    lb1[l]   = (const float*)d_in[8 + 6*l + 1];
    lW2[l]   = (const float*)d_in[8 + 6*l + 2];
    lb2[l]   = (const float*)d_in[8 + 6*l + 3];
    lroot[l] = (const float*)d_in[8 + 6*l + 4];
    lbias[l] = (const float*)d_in[8 + 6*l + 5];
  }
  const float* emW1  = (const float*)d_in[26];
  const float* emb1  = (const float*)d_in[27];
  const float* emW2  = (const float*)d_in[28];
  const float* emb2  = (const float*)d_in[29];
  const float* nm1W1 = (const float*)d_in[30];
  const float* nm1b1 = (const float*)d_in[31];
  const float* nm1W2 = (const float*)d_in[32];
  const float* nm1b2 = (const float*)d_in[33];
  const float* nm2W1 = (const float*)d_in[34];
  const float* nm2b1 = (const float*)d_in[35];
  const float* nm2W2 = (const float*)d_in[36];
  const float* nm2b2 = (const float*)d_in[37];

  const int* rowp = ei;
  const int* colp = ei + NE;

  // workspace layout (float units)
  float* ws   = (float*)d_ws;
  float* x_bn = ws;                                 // NN*16
  float* x_a  = x_bn + (size_t)NN*NIN;              // NN*32
  float* x_b  = x_a  + (size_t)NN*HD;               // NN*32
  float* scr  = x_b  + (size_t)NN*HD;               // 16384 floats
  float* partial_e = scr;            // 128*40 = 5120
  float* partial_x = scr + 5120;     // 64*32 = 2048
  float* ss_g      = scr + 7168;     // 70
  float* W1f       = scr + 7424;     // 1920
  float* b1f       = scr + 9344;     // 96
  float* biasP     = scr + 9440;     // 128
  short* w2pk   = (short*)(scr + 16384);            // 3*32768 shorts
  short* predpk = w2pk + 3*32768;                   // 8192 shorts
  short* T1     = predpk + 8192;                    // NE*32 bf16
  float* agg    = (float*)T1;                       // alias (T1 dead after layer-2 msg)
  float* cnt    = agg + (size_t)NN*HD;

  // stats (block partials, no atomics, no pre-zero)
  stats_all_kernel<<<NBLK_E + NBLK_X, 256, 0, stream>>>(e, x, partial_e, partial_x);
  // fused: reduce+finalize+fold+predprep+packpred
  prep_kernel<<<1, 1024, 0, stream>>>(partial_e, partial_x,
                                      bn_edge_g, bn_edge_b, bn_node_g, bn_node_b,
                                      lW1[0], lb1[0], lW1[1], lb1[1], lW1[2], lb1[2],
                                      emW1, emb1, emW2, emb2,
                                      nm1W1, nm1b1, nm1W2, nm1b2,
                                      ss_g, W1f, b1f, biasP, predpk);
  w2pack_all_kernel<<<320, 256, 0, stream>>>(lW2[0], lW2[1], lW2[2], w2pk);
  normalize_kernel<NIN><<<1024, 256, 0, stream>>>(x, x_bn, ss_g + 2*EIN, NN);

  const int eblocks = (NE + 255)/256;     // 586
  const int nblocks = (NN + 255)/256;     // 196
  const int mblocks = (NTILES + 15)/16;   // 586 (4 waves x 4 tiles)

  // layer 0 (din=16): x_bn -> x_a
  rootv2_kernel<NIN><<<nblocks, 256, 0, stream>>>(x_bn, lroot[0], lbias[0], x_a);
  t1v2_kernel<NIN><<<eblocks, 256, 0, stream>>>(e, W1f + 0*640, b1f + 0*32, T1);
  msg4_kernel<NIN, 32, 4><<<mblocks, 256, 0, stream>>>(T1, rowp, colp, x_bn,
                                                       w2pk + 0*32768, lb2[0], x_a);
  // layer 1 (din=32): x_a -> x_b
  rootv2_kernel<HD><<<nblocks, 256, 0, stream>>>(x_a, lroot[1], lbias[1], x_b);
  t1v2_kernel<HD><<<eblocks, 256, 0, stream>>>(e, W1f + 1*640, b1f + 1*32, T1);
  msg4_kernel<HD, 64, 4><<<mblocks, 256, 0, stream>>>(T1, rowp, colp, x_a,
                                                      w2pk + 1*32768, lb2[1], x_b);
  // layer 2 (din=32): x_b -> x_a
  rootv2_kernel<HD><<<nblocks, 256, 0, stream>>>(x_b, lroot[2], lbias[2], x_a);
  t1v2_kernel<HD><<<eblocks, 256, 0, stream>>>(e, W1f + 2*640, b1f + 2*32, T1);
  msg4_kernel<HD, 64, 4><<<mblocks, 256, 0, stream>>>(T1, rowp, colp, x_b,
                                                      w2pk + 2*32768, lb2[2], x_a);

  // predictor (agg/cnt alias T1 region — zero first)
  zero_kernel<<<2048, 256, 0, stream>>>(agg, NN*HD + NN);
  pred4_kernel<<<(NTILES + 3)/4, 256, 0, stream>>>(x_a, e, rowp, colp, predpk, biasP, agg, cnt);
  final_kernel<<<(NN + 255)/256, 256, 0, stream>>>(x_a, agg, cnt,
                                                   nm2W1, nm2b1, nm2W2, nm2b2,
                                                   (float*)d_out);
}

// Round 7
// 269.193 us; speedup vs baseline: 2.9266x; 1.1359x over previous
//
#include <hip/hip_runtime.h>
#include <math.h>

constexpr int NN  = 50000;   // nodes
constexpr int NE  = 150000;  // edges
constexpr int NIN = 16;      // node features in
constexpr int EIN = 19;      // edge features in
constexpr int HD  = 32;      // hidden H
constexpr int NTILES = NE / 16;  // 9375
constexpr int NBLK_E = 128;
constexpr int NBLK_X = 64;

#define LEAK  0.1f
#define BNEPS 1e-5f

typedef __attribute__((ext_vector_type(8))) short bfrag;
typedef __attribute__((ext_vector_type(4))) float f32x4;
typedef __attribute__((ext_vector_type(2))) float f32x2;
typedef __attribute__((ext_vector_type(4))) int   i32x4;

__device__ __forceinline__ float lky(float v){ return fmaxf(v, LEAK*v); }
__device__ __forceinline__ unsigned f2bf(float f){
  unsigned u = __float_as_uint(f);
  return ((u + 0x7FFFu + ((u >> 16) & 1u)) >> 16);   // RNE
}
__device__ __forceinline__ void split8(const float* v, i32x4& h4, i32x4& l4){
  unsigned hs[8], ls[8];
  #pragma unroll
  for(int j = 0; j < 8; j++){
    unsigned hh = f2bf(v[j]);
    float hf = __uint_as_float(hh << 16);
    hs[j] = hh; ls[j] = f2bf(v[j] - hf);
  }
  h4[0] = (int)(hs[0] | (hs[1]<<16)); h4[1] = (int)(hs[2] | (hs[3]<<16));
  h4[2] = (int)(hs[4] | (hs[5]<<16)); h4[3] = (int)(hs[6] | (hs[7]<<16));
  l4[0] = (int)(ls[0] | (ls[1]<<16)); l4[1] = (int)(ls[2] | (ls[3]<<16));
  l4[2] = (int)(ls[4] | (ls[5]<<16)); l4[3] = (int)(ls[6] | (ls[7]<<16));
}

// ---------------------------------------------------------------- zero
__global__ void zero_kernel(float* __restrict__ p, int n){
  int stride = gridDim.x * blockDim.x;
  for(int i = blockIdx.x*blockDim.x + threadIdx.x; i < n; i += stride) p[i] = 0.f;
}

// ---------------------------------------------------------------- stats (proven R5)
__global__ __launch_bounds__(256) void stats_all_kernel(const float* __restrict__ e,
                                                        const float* __restrict__ x,
                                                        float* __restrict__ partial_e,
                                                        float* __restrict__ partial_x){
  __shared__ float red[4][40];
  const int tid = threadIdx.x, lane = tid & 63, wid = tid >> 6;
  if(blockIdx.x < NBLK_E){
    float s[EIN], q[EIN];
    #pragma unroll
    for(int c = 0; c < EIN; c++){ s[c] = 0.f; q[c] = 0.f; }
    const int gstride = NBLK_E * 256;
    for(int g = blockIdx.x*256 + tid; g < NE/4; g += gstride){
      const f32x4* p = (const f32x4*)(e + (size_t)g * 76);
      #pragma unroll
      for(int m = 0; m < 19; m++){
        f32x4 v = p[m];
        #pragma unroll
        for(int j = 0; j < 4; j++){
          int c = (4*m + j) % 19;
          s[c] += v[j]; q[c] = fmaf(v[j], v[j], q[c]);
        }
      }
    }
    #pragma unroll
    for(int off = 32; off; off >>= 1){
      #pragma unroll
      for(int c = 0; c < EIN; c++){ s[c] += __shfl_xor(s[c], off); q[c] += __shfl_xor(q[c], off); }
    }
    if(lane == 0){
      #pragma unroll
      for(int c = 0; c < EIN; c++){ red[wid][c] = s[c]; red[wid][20 + c] = q[c]; }
    }
    __syncthreads();
    if(tid < 39 && tid != 19)
      partial_e[blockIdx.x*40 + tid] = red[0][tid] + red[1][tid] + red[2][tid] + red[3][tid];
  } else {
    float s[NIN], q[NIN];
    #pragma unroll
    for(int c = 0; c < NIN; c++){ s[c] = 0.f; q[c] = 0.f; }
    const int bid = blockIdx.x - NBLK_E;
    const int gstride = NBLK_X * 256;
    for(int r = bid*256 + tid; r < NN; r += gstride){
      const f32x4* p = (const f32x4*)(x + (size_t)r * NIN);
      #pragma unroll
      for(int m = 0; m < 4; m++){
        f32x4 v = p[m];
        #pragma unroll
        for(int j = 0; j < 4; j++){
          int c = 4*m + j;
          s[c] += v[j]; q[c] = fmaf(v[j], v[j], q[c]);
        }
      }
    }
    #pragma unroll
    for(int off = 32; off; off >>= 1){
      #pragma unroll
      for(int c = 0; c < NIN; c++){ s[c] += __shfl_xor(s[c], off); q[c] += __shfl_xor(q[c], off); }
    }
    if(lane == 0){
      #pragma unroll
      for(int c = 0; c < NIN; c++){ red[wid][c] = s[c]; red[wid][16 + c] = q[c]; }
    }
    __syncthreads();
    if(tid < 32)
      partial_x[bid*32 + tid] = red[0][tid] + red[1][tid] + red[2][tid] + red[3][tid];
  }
}

// ---------------------------------------------------------------- prep (proven R5)
__global__ __launch_bounds__(1024) void prep_kernel(const float* __restrict__ partial_e,
                                                    const float* __restrict__ partial_x,
                                                    const float* __restrict__ ge, const float* __restrict__ be,
                                                    const float* __restrict__ gx, const float* __restrict__ bx,
                                                    const float* __restrict__ l0W1, const float* __restrict__ l0b1,
                                                    const float* __restrict__ l1W1, const float* __restrict__ l1b1,
                                                    const float* __restrict__ l2W1, const float* __restrict__ l2b1,
                                                    const float* __restrict__ emW1, const float* __restrict__ emb1,
                                                    const float* __restrict__ emW2, const float* __restrict__ emb2,
                                                    const float* __restrict__ nm1W1, const float* __restrict__ nm1b1,
                                                    const float* __restrict__ nm1W2, const float* __restrict__ nm1b2,
                                                    float* __restrict__ ss_g, float* __restrict__ W1f,
                                                    float* __restrict__ b1f, float* __restrict__ biasP,
                                                    short* __restrict__ predpk){
  __shared__ float ss[70];
  __shared__ float emW1f[608];
  __shared__ float emb1f[32];
  __shared__ float predW[7168];
  const int t = threadIdx.x;

  if(t < EIN){
    float s = 0.f, q = 0.f;
    for(int b = 0; b < NBLK_E; b++){ s += partial_e[b*40 + t]; q += partial_e[b*40 + 20 + t]; }
    float m = s / (float)NE;
    float v = q / (float)NE - m*m;
    float sc = ge[t] * rsqrtf(v + BNEPS);
    ss[t] = sc; ss[EIN + t] = be[t] - m*sc;
  } else if(t >= 32 && t < 32 + NIN){
    int c = t - 32;
    float s = 0.f, q = 0.f;
    for(int b = 0; b < NBLK_X; b++){ s += partial_x[b*32 + c]; q += partial_x[b*32 + 16 + c]; }
    float m = s / (float)NN;
    float v = q / (float)NN - m*m;
    float sc = gx[c] * rsqrtf(v + BNEPS);
    ss[2*EIN + c] = sc; ss[2*EIN + NIN + c] = bx[c] - m*sc;
  }
  __syncthreads();
  if(t < 70) ss_g[t] = ss[t];

  if(t < 128){
    int seg = t >> 5, j = t & 31;
    if(seg == 0){
      if(j < NIN){
        float acc = l0b1[j];
        for(int k = 0; k < EIN; k++){
          W1f[0*640 + k*NIN + j] = ss[k] * l0W1[k*NIN + j];
          acc += ss[EIN+k] * l0W1[k*NIN + j];
        }
        b1f[0*32 + j] = acc;
      }
    } else if(seg == 1){
      float acc = l1b1[j];
      for(int k = 0; k < EIN; k++){
        W1f[1*640 + k*HD + j] = ss[k] * l1W1[k*HD + j];
        acc += ss[EIN+k] * l1W1[k*HD + j];
      }
      b1f[1*32 + j] = acc;
    } else if(seg == 2){
      float acc = l2b1[j];
      for(int k = 0; k < EIN; k++){
        W1f[2*640 + k*HD + j] = ss[k] * l2W1[k*HD + j];
        acc += ss[EIN+k] * l2W1[k*HD + j];
      }
      b1f[2*32 + j] = acc;
    } else {
      float acc = emb1[j];
      for(int k = 0; k < EIN; k++){
        emW1f[k*HD + j] = ss[k] * emW1[(2*HD+k)*HD + j];
        acc += ss[EIN+k] * emW1[(2*HD+k)*HD + j];
      }
      emb1f[j] = acc;
    }
  }
  __syncthreads();

  for(int i = t; i < 224*32; i += 1024){
    int k = i >> 5, n = i & 31;
    float v;
    if(k < 64)       v = emW1[k*32 + n];
    else if(k < 83)  v = emW1f[(k-64)*32 + n];
    else if(k < 96)  v = 0.f;
    else if(k < 128) v = emW2[(k-96)*32 + n];
    else if(k < 192) v = nm1W1[(k-128)*32 + n];
    else             v = nm1W2[(k-192)*32 + n];
    predW[i] = v;
  }
  if(t < 128){
    int s = t >> 5, n = t & 31;
    biasP[t] = (s==0) ? emb1f[n] : (s==1) ? emb2[n] : (s==2) ? nm1b1[n] : nm1b2[n];
  }
  __syncthreads();

  for(int idx = t; idx < 14*512; idx += 1024){
    int c = idx >> 9, l = (idx >> 3) & 63, j = idx & 7;
    int kbg = c >> 1, nc = c & 1;
    int k = kbg*32 + 8*(l>>4) + j;
    int n = nc*16 + (l & 15);
    predpk[idx] = (short)f2bf(predW[k*32 + n]);
  }
}

// ---------------------------------------------------------------- pack all three W2
__global__ __launch_bounds__(256) void w2pack_all_kernel(const float* __restrict__ W20,
                                                         const float* __restrict__ W21,
                                                         const float* __restrict__ W22,
                                                         short* __restrict__ w2pk){
  int idx = blockIdx.x*256 + threadIdx.x;
  if(idx >= 81920) return;
  const float* W2; int DIN, base, ci;
  if(idx < 16384){ W2 = W20; DIN = 16; base = 0;     ci = idx; }
  else if(idx < 49152){ W2 = W21; DIN = 32; base = 32768; ci = idx - 16384; }
  else { W2 = W22; DIN = 32; base = 65536; ci = idx - 49152; }
  int c = ci >> 9, l = (ci >> 3) & 63, j = ci & 7;
  int k = 8*(l>>4) + j;
  int n = c*16 + (l & 15);
  float v = (k < DIN) ? W2[(size_t)k*(DIN*HD) + n] : 0.f;
  w2pk[base + ci] = (short)f2bf(v);
}

// ---------------------------------------------------------------- normalize x
template<int C>
__global__ void normalize_kernel(const float* __restrict__ in, float* __restrict__ outp,
                                 const float* __restrict__ ss, int rows){
  int n = rows * C;
  int stride = gridDim.x * blockDim.x;
  for(int i = blockIdx.x*blockDim.x + threadIdx.x; i < n; i += stride){
    int c = i % C;
    outp[i] = in[i] * ss[c] + ss[C + c];
  }
}

// ---------------------------------------------------------------- T1 (proven R5)
template<int DIN>
__global__ __launch_bounds__(256) void t1v2_kernel(const float* __restrict__ eraw,
                                                   const float* __restrict__ W1f,
                                                   const float* __restrict__ b1f,
                                                   short* __restrict__ T1){
  int e = blockIdx.x*256 + threadIdx.x;
  if(e >= NE) return;
  const float* ep = eraw + (size_t)e*EIN;
  float eb[EIN];
  #pragma unroll
  for(int k = 0; k < EIN; k++) eb[k] = ep[k];

  float tv[DIN];
  #pragma unroll
  for(int j = 0; j < DIN; j++) tv[j] = b1f[j];
  #pragma unroll
  for(int k = 0; k < EIN; k++){
    float v = eb[k];
    #pragma unroll
    for(int j = 0; j < DIN; j++) tv[j] = fmaf(v, W1f[k*DIN + j], tv[j]);
  }
  unsigned pk[16];
  #pragma unroll
  for(int p = 0; p < 16; p++){
    unsigned lo, hi;
    if(2*p < DIN){ float a = tv[2*p];   lo = f2bf(fmaxf(a, LEAK*a)); } else lo = 0;
    if(2*p+1 < DIN){ float a = tv[2*p+1]; hi = f2bf(fmaxf(a, LEAK*a)); } else hi = 0;
    pk[p] = lo | (hi << 16);
  }
  i32x4* outp = (i32x4*)(T1 + (size_t)e*32);
  #pragma unroll
  for(int g = 0; g < 4; g++){
    i32x4 v; v[0] = (int)pk[g*4]; v[1] = (int)pk[g*4+1]; v[2] = (int)pk[g*4+2]; v[3] = (int)pk[g*4+3];
    outp[g] = v;
  }
}

// ---------------------------------------------------------------- root (proven R5)
template<int DIN>
__global__ __launch_bounds__(256) void rootv2_kernel(const float* __restrict__ xin,
                                                     const float* __restrict__ root,
                                                     const float* __restrict__ bias,
                                                     float* __restrict__ xout){
  int n = blockIdx.x*256 + threadIdx.x;
  if(n >= NN) return;
  float xr[DIN];
  const f32x4* xp = (const f32x4*)(xin + (size_t)n*DIN);
  #pragma unroll
  for(int g = 0; g < DIN/4; g++){ f32x4 v = xp[g];
    #pragma unroll
    for(int j = 0; j < 4; j++) xr[g*4+j] = v[j]; }
  float acc[HD];
  #pragma unroll
  for(int o = 0; o < HD; o++) acc[o] = bias[o];
  #pragma unroll
  for(int k = 0; k < DIN; k++){
    float v = xr[k];
    #pragma unroll
    for(int o = 0; o < HD; o++) acc[o] = fmaf(v, root[k*HD + o], acc[o]);
  }
  f32x4* outp = (f32x4*)(xout + (size_t)n*HD);
  #pragma unroll
  for(int g = 0; g < 8; g++){ f32x4 v; v[0]=acc[g*4]; v[1]=acc[g*4+1]; v[2]=acc[g*4+2]; v[3]=acc[g*4+3]; outp[g] = v; }
}

// ---------------------------------------------------------------- msg v5: 512 threads, halved W2 stage, pk epilogue
// wave = 1 tile; 8 waves share w2s; W2 staged in HALVES, partial msg kept in regs across syncs
template<int DIN, int NCH, int HALVES>
__global__ __launch_bounds__(512) void msg5_kernel(const short* __restrict__ T1,
                                                   const int* __restrict__ rowp,
                                                   const int* __restrict__ colp,
                                                   const float* __restrict__ xin,
                                                   const short* __restrict__ w2p,
                                                   const float* __restrict__ b2,
                                                   float* __restrict__ xout){
  constexpr int CH  = NCH / HALVES;     // chunks per half
  constexpr int XGP = DIN + 1;          // bank-spread pad
  __shared__ short w2s[CH*512];
  __shared__ float b2s[NCH*16];
  __shared__ float xgs[8][16][XGP];

  const int tid = threadIdx.x;
  const int l   = tid & 63;
  const int wid = tid >> 6;             // 0..7
  const int grp = l >> 4, lo16 = l & 15;
  const int tile = blockIdx.x*8 + wid;
  const bool active = tile < NTILES;
  const int e0 = tile * 16;

  // stage x rows (per-wave slice — no cross-wave hazard)
  if(active){
    int r = rowp[e0 + lo16];
    if(DIN == 32){
      const f32x4* xp = (const f32x4*)(xin + (size_t)r*32 + grp*8);
      *(f32x4*)&xgs[wid][lo16][grp*8]     = xp[0];
      *(f32x4*)&xgs[wid][lo16][grp*8 + 4] = xp[1];
    } else {
      const f32x4* xp = (const f32x4*)(xin + (size_t)r*16 + grp*4);
      *(f32x4*)&xgs[wid][lo16][grp*4] = xp[0];
    }
  }

  bfrag af = {0,0,0,0,0,0,0,0};
  if(active) af = *(const bfrag*)(T1 + (size_t)(e0 + lo16)*32 + grp*8);

  f32x2 m0a = {0.f,0.f}, m0b = {0.f,0.f}, m1a = {0.f,0.f}, m1b = {0.f,0.f};

  for(int h = 0; h < HALVES; h++){
    if(h) __syncthreads();                       // drain readers of previous half
    for(int t = tid; t < CH*64; t += 512)
      ((i32x4*)w2s)[t] = ((const i32x4*)w2p)[h*CH*64 + t];
    if(h == 0)
      for(int t = tid; t < NCH*16; t += 512) b2s[t] = b2[t];
    __syncthreads();

    if(active){
      #pragma unroll 4
      for(int i = 0; i < CH/2; i++){
        const int cg = h*CH + 2*i;               // global even chunk
        const int ig = cg >> 1;                  // global i index
        float bv0 = b2s[cg*16 + lo16];
        float bv1 = b2s[(cg+1)*16 + lo16];
        f32x4 c0 = {bv0,bv0,bv0,bv0};
        f32x4 c1 = {bv1,bv1,bv1,bv1};
        bfrag b0 = *(const bfrag*)&w2s[((2*i  )*64 + l)*8];
        bfrag b1 = *(const bfrag*)&w2s[((2*i+1)*64 + l)*8];
        f32x4 u0 = __builtin_amdgcn_mfma_f32_16x16x32_bf16(af, b0, c0, 0, 0, 0);
        f32x4 u1 = __builtin_amdgcn_mfma_f32_16x16x32_bf16(af, b1, c1, 0, 0, 0);

        f32x2 xva = {xgs[wid][grp*4+0][ig], xgs[wid][grp*4+1][ig]};
        f32x2 xvb = {xgs[wid][grp*4+2][ig], xgs[wid][grp*4+3][ig]};
        f32x2 u0a = {u0[0],u0[1]}, u0b = {u0[2],u0[3]};
        f32x2 u1a = {u1[0],u1[1]}, u1b = {u1[2],u1[3]};
        f32x2 a0a = __builtin_elementwise_max(u0a, u0a*LEAK);
        f32x2 a0b = __builtin_elementwise_max(u0b, u0b*LEAK);
        f32x2 a1a = __builtin_elementwise_max(u1a, u1a*LEAK);
        f32x2 a1b = __builtin_elementwise_max(u1b, u1b*LEAK);
        m0a = __builtin_elementwise_fma(xva, a0a, m0a);
        m0b = __builtin_elementwise_fma(xvb, a0b, m0b);
        m1a = __builtin_elementwise_fma(xva, a1a, m1a);
        m1b = __builtin_elementwise_fma(xvb, a1b, m1b);
      }
    }
  }

  if(active){
    float m0[4] = {m0a[0], m0a[1], m0b[0], m0b[1]};
    float m1[4] = {m1a[0], m1a[1], m1b[0], m1b[1]};
    #pragma unroll
    for(int reg = 0; reg < 4; reg++){
      int ce = colp[e0 + grp*4 + reg];
      atomicAdd(&xout[(size_t)ce*HD + lo16],      m0[reg]);
      atomicAdd(&xout[(size_t)ce*HD + 16 + lo16], m1[reg]);
    }
  }
}

// ---------------------------------------------------------------- predictor (proven R4/R5)
__global__ __launch_bounds__(256) void pred4_kernel(const float* __restrict__ x,
                                                    const float* __restrict__ eraw,
                                                    const int* __restrict__ rowp,
                                                    const int* __restrict__ colp,
                                                    const short* __restrict__ predpk,
                                                    const float* __restrict__ biasP,
                                                    float* __restrict__ agg,
                                                    float* __restrict__ cnt){
  __shared__ short predw[14*512];
  __shared__ float biasl[128];
  __shared__ short fAhi[4][16][104];
  __shared__ short fAlo[4][16][104];
  __shared__ short uAhi[4][16][40];
  __shared__ short uAlo[4][16][40];

  const int tid = threadIdx.x;
  for(int t = tid; t < 14*512/8; t += 256)
    ((i32x4*)predw)[t] = ((const i32x4*)predpk)[t];
  if(tid < 128) biasl[tid] = biasP[tid];
  __syncthreads();

  const int l = tid & 63, wid = tid >> 6;
  const int grp = l >> 4, lo16 = l & 15;
  const int tile = blockIdx.x*4 + wid;
  if(tile >= NTILES) return;
  const int e0 = tile * 16;

  {
    float v[8];
    i32x4 h4, l4;
    int r = rowp[e0 + lo16];
    const float* xp = x + (size_t)r*32 + grp*8;
    #pragma unroll
    for(int j = 0; j < 8; j++) v[j] = xp[j];
    split8(v, h4, l4);
    *(i32x4*)&fAhi[wid][lo16][grp*8] = h4;
    *(i32x4*)&fAlo[wid][lo16][grp*8] = l4;

    int c = colp[e0 + lo16];
    const float* xq = x + (size_t)c*32 + grp*8;
    #pragma unroll
    for(int j = 0; j < 8; j++) v[j] = xq[j];
    split8(v, h4, l4);
    *(i32x4*)&fAhi[wid][lo16][32 + grp*8] = h4;
    *(i32x4*)&fAlo[wid][lo16][32 + grp*8] = l4;

    const float* ep = eraw + (size_t)(e0 + lo16)*EIN;
    #pragma unroll
    for(int j = 0; j < 8; j++){ int f = grp*8 + j; v[j] = (f < EIN) ? ep[f] : 0.f; }
    split8(v, h4, l4);
    *(i32x4*)&fAhi[wid][lo16][64 + grp*8] = h4;
    *(i32x4*)&fAlo[wid][lo16][64 + grp*8] = l4;
  }

  f32x4 z; z[0]=0.f; z[1]=0.f; z[2]=0.f; z[3]=0.f;

  #pragma unroll
  for(int nc = 0; nc < 2; nc++){
    f32x4 acc = z;
    #pragma unroll
    for(int kb = 0; kb < 3; kb++){
      bfrag b  = *(const bfrag*)&predw[((kb*2 + nc)*64 + l)*8];
      bfrag ah = *(const bfrag*)&fAhi[wid][lo16][kb*32 + grp*8];
      bfrag al = *(const bfrag*)&fAlo[wid][lo16][kb*32 + grp*8];
      acc = __builtin_amdgcn_mfma_f32_16x16x32_bf16(ah, b, acc, 0, 0, 0);
      acc = __builtin_amdgcn_mfma_f32_16x16x32_bf16(al, b, acc, 0, 0, 0);
    }
    int n = nc*16 + lo16;
    float bv = biasl[n];
    #pragma unroll
    for(int reg = 0; reg < 4; reg++){
      float uv = acc[reg] + bv; uv = fmaxf(uv, LEAK*uv);
      unsigned hh = f2bf(uv);
      float hf = __uint_as_float(hh << 16);
      uAhi[wid][grp*4 + reg][n] = (short)hh;
      uAlo[wid][grp*4 + reg][n] = (short)f2bf(uv - hf);
    }
  }

  #pragma unroll
  for(int nc = 0; nc < 2; nc++){
    f32x4 acc = z;
    bfrag b  = *(const bfrag*)&predw[((6 + nc)*64 + l)*8];
    bfrag ah = *(const bfrag*)&uAhi[wid][lo16][grp*8];
    bfrag al = *(const bfrag*)&uAlo[wid][lo16][grp*8];
    acc = __builtin_amdgcn_mfma_f32_16x16x32_bf16(ah, b, acc, 0, 0, 0);
    acc = __builtin_amdgcn_mfma_f32_16x16x32_bf16(al, b, acc, 0, 0, 0);
    int n = nc*16 + lo16;
    float bv = biasl[32 + n];
    #pragma unroll
    for(int reg = 0; reg < 4; reg++){
      float ev = acc[reg] + bv;
      unsigned hh = f2bf(ev);
      float hf = __uint_as_float(hh << 16);
      fAhi[wid][grp*4 + reg][32 + n] = (short)hh;
      fAlo[wid][grp*4 + reg][32 + n] = (short)f2bf(ev - hf);
    }
  }

  #pragma unroll
  for(int nc = 0; nc < 2; nc++){
    f32x4 acc = z;
    #pragma unroll
    for(int kb = 0; kb < 2; kb++){
      bfrag b  = *(const bfrag*)&predw[(((4 + kb)*2 + nc)*64 + l)*8];
      bfrag ah = *(const bfrag*)&fAhi[wid][lo16][kb*32 + grp*8];
      bfrag al = *(const bfrag*)&fAlo[wid][lo16][kb*32 + grp*8];
      acc = __builtin_amdgcn_mfma_f32_16x16x32_bf16(ah, b, acc, 0, 0, 0);
      acc = __builtin_amdgcn_mfma_f32_16x16x32_bf16(al, b, acc, 0, 0, 0);
    }
    int n = nc*16 + lo16;
    float bv = biasl[64 + n];
    #pragma unroll
    for(int reg = 0; reg < 4; reg++){
      float vv = acc[reg] + bv; vv = fmaxf(vv, LEAK*vv);
      unsigned hh = f2bf(vv);
      float hf = __uint_as_float(hh << 16);
      uAhi[wid][grp*4 + reg][n] = (short)hh;
      uAlo[wid][grp*4 + reg][n] = (short)f2bf(vv - hf);
    }
  }

  int ce[4];
  #pragma unroll
  for(int reg = 0; reg < 4; reg++) ce[reg] = colp[e0 + grp*4 + reg];

  #pragma unroll
  for(int nc = 0; nc < 2; nc++){
    f32x4 acc = z;
    bfrag b  = *(const bfrag*)&predw[((12 + nc)*64 + l)*8];
    bfrag ah = *(const bfrag*)&uAhi[wid][lo16][grp*8];
    bfrag al = *(const bfrag*)&uAlo[wid][lo16][grp*8];
    acc = __builtin_amdgcn_mfma_f32_16x16x32_bf16(ah, b, acc, 0, 0, 0);
    acc = __builtin_amdgcn_mfma_f32_16x16x32_bf16(al, b, acc, 0, 0, 0);
    int n = nc*16 + lo16;
    float bv = biasl[96 + n];
    #pragma unroll
    for(int reg = 0; reg < 4; reg++)
      atomicAdd(&agg[(size_t)ce[reg]*HD + n], acc[reg] + bv);
  }

  if(l < 16) atomicAdd(&cnt[colp[e0 + l]], 1.f);
}

// ---------------------------------------------------------------- final node model + log_softmax
__global__ __launch_bounds__(256) void final_kernel(const float* __restrict__ x,
                                                    const float* __restrict__ agg,
                                                    const float* __restrict__ cnt,
                                                    const float* __restrict__ W1,
                                                    const float* __restrict__ b1,
                                                    const float* __restrict__ W2,
                                                    const float* __restrict__ b2,
                                                    float* __restrict__ out){
  int n = blockIdx.x*blockDim.x + threadIdx.x;
  if(n >= NN) return;
  float inv = 1.f / fmaxf(cnt[n], 1.f);
  const float* xp = x + (size_t)n * HD;
  const float* ap = agg + (size_t)n * HD;

  float t[HD];
  #pragma unroll
  for(int o = 0; o < HD; o++) t[o] = b1[o];
  #pragma unroll
  for(int k = 0; k < HD; k++){ float v = xp[k]; const float* wp = W1 + k*HD;
    #pragma unroll
    for(int o = 0; o < HD; o++) t[o] += v * wp[o]; }
  #pragma unroll
  for(int k = 0; k < HD; k++){ float v = ap[k] * inv; const float* wp = W1 + (HD+k)*HD;
    #pragma unroll
    for(int o = 0; o < HD; o++) t[o] += v * wp[o]; }

  float a0 = b2[0], a1 = b2[1];
  #pragma unroll
  for(int k = 0; k < HD; k++){ float v = lky(t[k]); a0 += v * W2[k*2]; a1 += v * W2[k*2+1]; }

  float m  = fmaxf(a0, a1);
  float ls = m + logf(expf(a0 - m) + expf(a1 - m));
  out[(size_t)n*2]   = a0 - ls;
  out[(size_t)n*2+1] = a1 - ls;
}

// ---------------------------------------------------------------- launch
extern "C" void kernel_launch(void* const* d_in, const int* in_sizes, int n_in,
                              void* d_out, int out_size, void* d_ws, size_t ws_size,
                              hipStream_t stream){
  const float* x  = (const float*)d_in[0];
  const int*   ei = (const int*)  d_in[1];
  const float* e  = (const float*)d_in[2];
  const float* bn_node_g = (const float*)d_in[4];
  const float* bn_node_b = (const float*)d_in[5];
  const float* bn_edge_g = (const float*)d_in[6];
  const float* bn_edge_b = (const float*)d_in[7];
  const float* lW1[3], *lb1[3], *lW2[3], *lb2[3], *lroot[3], *lbias[3];
  for(int l = 0; l < 3; l++){
    lW1[l]   = (const float*)d_in[8 + 6*l + 0];
    lb1[l]   = (const float*)d_in[8 + 6*l + 1];
    lW2[l]   = (const float*)d_in[8 + 6*l + 2];
    lb2[l]   = (const float*)d_in[8 + 6*l + 3];
    lroot[l] = (const float*)d_in[8 + 6*l + 4];
    lbias[l] = (const float*)d_in[8 + 6*l + 5];
  }
  const float* emW1  = (const float*)d_in[26];
  const float* emb1  = (const float*)d_in[27];
  const float* emW2  = (const float*)d_in[28];
  const float* emb2  = (const float*)d_in[29];
  const float* nm1W1 = (const float*)d_in[30];
  const float* nm1b1 = (const float*)d_in[31];
  const float* nm1W2 = (const float*)d_in[32];
  const float* nm1b2 = (const float*)d_in[33];
  const float* nm2W1 = (const float*)d_in[34];
  const float* nm2b1 = (const float*)d_in[35];
  const float* nm2W2 = (const float*)d_in[36];
  const float* nm2b2 = (const float*)d_in[37];

  const int* rowp = ei;
  const int* colp = ei + NE;

  // workspace layout (float units)
  float* ws   = (float*)d_ws;
  float* x_bn = ws;                                 // NN*16
  float* x_a  = x_bn + (size_t)NN*NIN;              // NN*32
  float* x_b  = x_a  + (size_t)NN*HD;               // NN*32
  float* scr  = x_b  + (size_t)NN*HD;               // 16384 floats
  float* partial_e = scr;            // 5120
  float* partial_x = scr + 5120;     // 2048
  float* ss_g      = scr + 7168;     // 70
  float* W1f       = scr + 7424;     // 1920
  float* b1f       = scr + 9344;     // 96
  float* biasP     = scr + 9440;     // 128
  short* w2pk   = (short*)(scr + 16384);            // 3*32768 shorts
  short* predpk = w2pk + 3*32768;                   // 8192 shorts
  short* T1     = predpk + 8192;                    // NE*32 bf16
  float* agg    = (float*)T1;                       // alias (T1 dead after layer-2 msg)
  float* cnt    = agg + (size_t)NN*HD;

  stats_all_kernel<<<NBLK_E + NBLK_X, 256, 0, stream>>>(e, x, partial_e, partial_x);
  prep_kernel<<<1, 1024, 0, stream>>>(partial_e, partial_x,
                                      bn_edge_g, bn_edge_b, bn_node_g, bn_node_b,
                                      lW1[0], lb1[0], lW1[1], lb1[1], lW1[2], lb1[2],
                                      emW1, emb1, emW2, emb2,
                                      nm1W1, nm1b1, nm1W2, nm1b2,
                                      ss_g, W1f, b1f, biasP, predpk);
  w2pack_all_kernel<<<320, 256, 0, stream>>>(lW2[0], lW2[1], lW2[2], w2pk);
  normalize_kernel<NIN><<<1024, 256, 0, stream>>>(x, x_bn, ss_g + 2*EIN, NN);

  const int eblocks = (NE + 255)/256;     // 586
  const int nblocks = (NN + 255)/256;     // 196
  const int m5blocks = (NTILES + 7)/8;    // 1172 (8 waves x 1 tile)

  // layer 0 (din=16): x_bn -> x_a
  rootv2_kernel<NIN><<<nblocks, 256, 0, stream>>>(x_bn, lroot[0], lbias[0], x_a);
  t1v2_kernel<NIN><<<eblocks, 256, 0, stream>>>(e, W1f + 0*640, b1f + 0*32, T1);
  msg5_kernel<NIN, 32, 2><<<m5blocks, 512, 0, stream>>>(T1, rowp, colp, x_bn,
                                                        w2pk + 0*32768, lb2[0], x_a);
  // layer 1 (din=32): x_a -> x_b
  rootv2_kernel<HD><<<nblocks, 256, 0, stream>>>(x_a, lroot[1], lbias[1], x_b);
  t1v2_kernel<HD><<<eblocks, 256, 0, stream>>>(e, W1f + 1*640, b1f + 1*32, T1);
  msg5_kernel<HD, 64, 2><<<m5blocks, 512, 0, stream>>>(T1, rowp, colp, x_a,
                                                       w2pk + 1*32768, lb2[1], x_b);
  // layer 2 (din=32): x_b -> x_a
  rootv2_kernel<HD><<<nblocks, 256, 0, stream>>>(x_b, lroot[2], lbias[2], x_a);
  t1v2_kernel<HD><<<eblocks, 256, 0, stream>>>(e, W1f + 2*640, b1f + 2*32, T1);
  msg5_kernel<HD, 64, 2><<<m5blocks, 512, 0, stream>>>(T1, rowp, colp, x_b,
                                                       w2pk + 2*32768, lb2[2], x_a);

  // predictor (agg/cnt alias T1 region — zero first)
  zero_kernel<<<2048, 256, 0, stream>>>(agg, NN*HD + NN);
  pred4_kernel<<<(NTILES + 3)/4, 256, 0, stream>>>(x_a, e, rowp, colp, predpk, biasP, agg, cnt);
  final_kernel<<<(NN + 255)/256, 256, 0, stream>>>(x_a, agg, cnt,
                                                   nm2W1, nm2b1, nm2W2, nm2b2,
                                                   (float*)d_out);
}

// Round 8
// 246.248 us; speedup vs baseline: 3.1992x; 1.0932x over previous
//
#include <hip/hip_runtime.h>
#include <math.h>

constexpr int NN  = 50000;   // nodes
constexpr int NE  = 150000;  // edges
constexpr int NIN = 16;      // node features in
constexpr int EIN = 19;      // edge features in
constexpr int HD  = 32;      // hidden H
constexpr int NTILES = NE / 16;  // 9375
constexpr int NBLK_E = 128;
constexpr int NBLK_X = 64;

#define LEAK  0.1f
#define BNEPS 1e-5f

typedef __attribute__((ext_vector_type(8))) short bfrag;
typedef __attribute__((ext_vector_type(4))) float f32x4;
typedef __attribute__((ext_vector_type(2))) float f32x2;
typedef __attribute__((ext_vector_type(4))) int   i32x4;

__device__ __forceinline__ float lky(float v){ return fmaxf(v, LEAK*v); }
__device__ __forceinline__ unsigned f2bf(float f){
  unsigned u = __float_as_uint(f);
  return ((u + 0x7FFFu + ((u >> 16) & 1u)) >> 16);   // RNE
}
__device__ __forceinline__ void split8(const float* v, i32x4& h4, i32x4& l4){
  unsigned hs[8], ls[8];
  #pragma unroll
  for(int j = 0; j < 8; j++){
    unsigned hh = f2bf(v[j]);
    float hf = __uint_as_float(hh << 16);
    hs[j] = hh; ls[j] = f2bf(v[j] - hf);
  }
  h4[0] = (int)(hs[0] | (hs[1]<<16)); h4[1] = (int)(hs[2] | (hs[3]<<16));
  h4[2] = (int)(hs[4] | (hs[5]<<16)); h4[3] = (int)(hs[6] | (hs[7]<<16));
  l4[0] = (int)(ls[0] | (ls[1]<<16)); l4[1] = (int)(ls[2] | (ls[3]<<16));
  l4[2] = (int)(ls[4] | (ls[5]<<16)); l4[3] = (int)(ls[6] | (ls[7]<<16));
}

// ---------------------------------------------------------------- zero
__global__ void zero_kernel(float* __restrict__ p, int n){
  int stride = gridDim.x * blockDim.x;
  for(int i = blockIdx.x*blockDim.x + threadIdx.x; i < n; i += stride) p[i] = 0.f;
}

// ---------------------------------------------------------------- stats (proven R5)
__global__ __launch_bounds__(256) void stats_all_kernel(const float* __restrict__ e,
                                                        const float* __restrict__ x,
                                                        float* __restrict__ partial_e,
                                                        float* __restrict__ partial_x){
  __shared__ float red[4][40];
  const int tid = threadIdx.x, lane = tid & 63, wid = tid >> 6;
  if(blockIdx.x < NBLK_E){
    float s[EIN], q[EIN];
    #pragma unroll
    for(int c = 0; c < EIN; c++){ s[c] = 0.f; q[c] = 0.f; }
    const int gstride = NBLK_E * 256;
    for(int g = blockIdx.x*256 + tid; g < NE/4; g += gstride){
      const f32x4* p = (const f32x4*)(e + (size_t)g * 76);
      #pragma unroll
      for(int m = 0; m < 19; m++){
        f32x4 v = p[m];
        #pragma unroll
        for(int j = 0; j < 4; j++){
          int c = (4*m + j) % 19;
          s[c] += v[j]; q[c] = fmaf(v[j], v[j], q[c]);
        }
      }
    }
    #pragma unroll
    for(int off = 32; off; off >>= 1){
      #pragma unroll
      for(int c = 0; c < EIN; c++){ s[c] += __shfl_xor(s[c], off); q[c] += __shfl_xor(q[c], off); }
    }
    if(lane == 0){
      #pragma unroll
      for(int c = 0; c < EIN; c++){ red[wid][c] = s[c]; red[wid][20 + c] = q[c]; }
    }
    __syncthreads();
    if(tid < 39 && tid != 19)
      partial_e[blockIdx.x*40 + tid] = red[0][tid] + red[1][tid] + red[2][tid] + red[3][tid];
  } else {
    float s[NIN], q[NIN];
    #pragma unroll
    for(int c = 0; c < NIN; c++){ s[c] = 0.f; q[c] = 0.f; }
    const int bid = blockIdx.x - NBLK_E;
    const int gstride = NBLK_X * 256;
    for(int r = bid*256 + tid; r < NN; r += gstride){
      const f32x4* p = (const f32x4*)(x + (size_t)r * NIN);
      #pragma unroll
      for(int m = 0; m < 4; m++){
        f32x4 v = p[m];
        #pragma unroll
        for(int j = 0; j < 4; j++){
          int c = 4*m + j;
          s[c] += v[j]; q[c] = fmaf(v[j], v[j], q[c]);
        }
      }
    }
    #pragma unroll
    for(int off = 32; off; off >>= 1){
      #pragma unroll
      for(int c = 0; c < NIN; c++){ s[c] += __shfl_xor(s[c], off); q[c] += __shfl_xor(q[c], off); }
    }
    if(lane == 0){
      #pragma unroll
      for(int c = 0; c < NIN; c++){ red[wid][c] = s[c]; red[wid][16 + c] = q[c]; }
    }
    __syncthreads();
    if(tid < 32)
      partial_x[bid*32 + tid] = red[0][tid] + red[1][tid] + red[2][tid] + red[3][tid];
  }
}

// ---------------------------------------------------------------- prep (proven R5)
__global__ __launch_bounds__(1024) void prep_kernel(const float* __restrict__ partial_e,
                                                    const float* __restrict__ partial_x,
                                                    const float* __restrict__ ge, const float* __restrict__ be,
                                                    const float* __restrict__ gx, const float* __restrict__ bx,
                                                    const float* __restrict__ l0W1, const float* __restrict__ l0b1,
                                                    const float* __restrict__ l1W1, const float* __restrict__ l1b1,
                                                    const float* __restrict__ l2W1, const float* __restrict__ l2b1,
                                                    const float* __restrict__ emW1, const float* __restrict__ emb1,
                                                    const float* __restrict__ emW2, const float* __restrict__ emb2,
                                                    const float* __restrict__ nm1W1, const float* __restrict__ nm1b1,
                                                    const float* __restrict__ nm1W2, const float* __restrict__ nm1b2,
                                                    float* __restrict__ ss_g, float* __restrict__ W1f,
                                                    float* __restrict__ b1f, float* __restrict__ biasP,
                                                    short* __restrict__ predpk){
  __shared__ float ss[70];
  __shared__ float emW1f[608];
  __shared__ float emb1f[32];
  __shared__ float predW[7168];
  const int t = threadIdx.x;

  if(t < EIN){
    float s = 0.f, q = 0.f;
    for(int b = 0; b < NBLK_E; b++){ s += partial_e[b*40 + t]; q += partial_e[b*40 + 20 + t]; }
    float m = s / (float)NE;
    float v = q / (float)NE - m*m;
    float sc = ge[t] * rsqrtf(v + BNEPS);
    ss[t] = sc; ss[EIN + t] = be[t] - m*sc;
  } else if(t >= 32 && t < 32 + NIN){
    int c = t - 32;
    float s = 0.f, q = 0.f;
    for(int b = 0; b < NBLK_X; b++){ s += partial_x[b*32 + c]; q += partial_x[b*32 + 16 + c]; }
    float m = s / (float)NN;
    float v = q / (float)NN - m*m;
    float sc = gx[c] * rsqrtf(v + BNEPS);
    ss[2*EIN + c] = sc; ss[2*EIN + NIN + c] = bx[c] - m*sc;
  }
  __syncthreads();
  if(t < 70) ss_g[t] = ss[t];

  if(t < 128){
    int seg = t >> 5, j = t & 31;
    if(seg == 0){
      if(j < NIN){
        float acc = l0b1[j];
        for(int k = 0; k < EIN; k++){
          W1f[0*640 + k*NIN + j] = ss[k] * l0W1[k*NIN + j];
          acc += ss[EIN+k] * l0W1[k*NIN + j];
        }
        b1f[0*32 + j] = acc;
      }
    } else if(seg == 1){
      float acc = l1b1[j];
      for(int k = 0; k < EIN; k++){
        W1f[1*640 + k*HD + j] = ss[k] * l1W1[k*HD + j];
        acc += ss[EIN+k] * l1W1[k*HD + j];
      }
      b1f[1*32 + j] = acc;
    } else if(seg == 2){
      float acc = l2b1[j];
      for(int k = 0; k < EIN; k++){
        W1f[2*640 + k*HD + j] = ss[k] * l2W1[k*HD + j];
        acc += ss[EIN+k] * l2W1[k*HD + j];
      }
      b1f[2*32 + j] = acc;
    } else {
      float acc = emb1[j];
      for(int k = 0; k < EIN; k++){
        emW1f[k*HD + j] = ss[k] * emW1[(2*HD+k)*HD + j];
        acc += ss[EIN+k] * emW1[(2*HD+k)*HD + j];
      }
      emb1f[j] = acc;
    }
  }
  __syncthreads();

  for(int i = t; i < 224*32; i += 1024){
    int k = i >> 5, n = i & 31;
    float v;
    if(k < 64)       v = emW1[k*32 + n];
    else if(k < 83)  v = emW1f[(k-64)*32 + n];
    else if(k < 96)  v = 0.f;
    else if(k < 128) v = emW2[(k-96)*32 + n];
    else if(k < 192) v = nm1W1[(k-128)*32 + n];
    else             v = nm1W2[(k-192)*32 + n];
    predW[i] = v;
  }
  if(t < 128){
    int s = t >> 5, n = t & 31;
    biasP[t] = (s==0) ? emb1f[n] : (s==1) ? emb2[n] : (s==2) ? nm1b1[n] : nm1b2[n];
  }
  __syncthreads();

  for(int idx = t; idx < 14*512; idx += 1024){
    int c = idx >> 9, l = (idx >> 3) & 63, j = idx & 7;
    int kbg = c >> 1, nc = c & 1;
    int k = kbg*32 + 8*(l>>4) + j;
    int n = nc*16 + (l & 15);
    predpk[idx] = (short)f2bf(predW[k*32 + n]);
  }
}

// ---------------------------------------------------------------- pack all three W2
__global__ __launch_bounds__(256) void w2pack_all_kernel(const float* __restrict__ W20,
                                                         const float* __restrict__ W21,
                                                         const float* __restrict__ W22,
                                                         short* __restrict__ w2pk){
  int idx = blockIdx.x*256 + threadIdx.x;
  if(idx >= 81920) return;
  const float* W2; int DIN, base, ci;
  if(idx < 16384){ W2 = W20; DIN = 16; base = 0;     ci = idx; }
  else if(idx < 49152){ W2 = W21; DIN = 32; base = 32768; ci = idx - 16384; }
  else { W2 = W22; DIN = 32; base = 65536; ci = idx - 49152; }
  int c = ci >> 9, l = (ci >> 3) & 63, j = ci & 7;
  int k = 8*(l>>4) + j;
  int n = c*16 + (l & 15);
  float v = (k < DIN) ? W2[(size_t)k*(DIN*HD) + n] : 0.f;
  w2pk[base + ci] = (short)f2bf(v);
}

// ---------------------------------------------------------------- normalize x
template<int C>
__global__ void normalize_kernel(const float* __restrict__ in, float* __restrict__ outp,
                                 const float* __restrict__ ss, int rows){
  int n = rows * C;
  int stride = gridDim.x * blockDim.x;
  for(int i = blockIdx.x*blockDim.x + threadIdx.x; i < n; i += stride){
    int c = i % C;
    outp[i] = in[i] * ss[c] + ss[C + c];
  }
}

// ---------------------------------------------------------------- T1 for ALL layers in one pass over e
__global__ __launch_bounds__(256) void t1all_kernel(const float* __restrict__ eraw,
                                                    const float* __restrict__ W1f,
                                                    const float* __restrict__ b1f,
                                                    short* __restrict__ T10,
                                                    short* __restrict__ T11,
                                                    short* __restrict__ T12){
  int e = blockIdx.x*256 + threadIdx.x;
  if(e >= NE) return;
  const float* ep = eraw + (size_t)e*EIN;
  float eb[EIN];
  #pragma unroll
  for(int k = 0; k < EIN; k++) eb[k] = ep[k];

  // ---- layer 0 (DIN=16)
  {
    float tv[16];
    #pragma unroll
    for(int j = 0; j < 16; j++) tv[j] = b1f[j];
    #pragma unroll
    for(int k = 0; k < EIN; k++){
      float v = eb[k];
      #pragma unroll
      for(int j = 0; j < 16; j++) tv[j] = fmaf(v, W1f[k*16 + j], tv[j]);
    }
    unsigned pk[8];
    #pragma unroll
    for(int p = 0; p < 8; p++){
      float a = tv[2*p], b = tv[2*p+1];
      pk[p] = f2bf(fmaxf(a, LEAK*a)) | (f2bf(fmaxf(b, LEAK*b)) << 16);
    }
    i32x4* outp = (i32x4*)(T10 + (size_t)e*32);
    i32x4 v0; v0[0]=(int)pk[0]; v0[1]=(int)pk[1]; v0[2]=(int)pk[2]; v0[3]=(int)pk[3];
    i32x4 v1; v1[0]=(int)pk[4]; v1[1]=(int)pk[5]; v1[2]=(int)pk[6]; v1[3]=(int)pk[7];
    i32x4 zz; zz[0]=0; zz[1]=0; zz[2]=0; zz[3]=0;
    outp[0] = v0; outp[1] = v1; outp[2] = zz; outp[3] = zz;
  }
  // ---- layers 1,2 (DIN=32)
  #pragma unroll
  for(int l = 1; l < 3; l++){
    const float* Wl = W1f + l*640;
    const float* bl = b1f + l*32;
    short* Tl = (l == 1) ? T11 : T12;
    float tv[32];
    #pragma unroll
    for(int j = 0; j < 32; j++) tv[j] = bl[j];
    #pragma unroll
    for(int k = 0; k < EIN; k++){
      float v = eb[k];
      #pragma unroll
      for(int j = 0; j < 32; j++) tv[j] = fmaf(v, Wl[k*32 + j], tv[j]);
    }
    unsigned pk[16];
    #pragma unroll
    for(int p = 0; p < 16; p++){
      float a = tv[2*p], b = tv[2*p+1];
      pk[p] = f2bf(fmaxf(a, LEAK*a)) | (f2bf(fmaxf(b, LEAK*b)) << 16);
    }
    i32x4* outp = (i32x4*)(Tl + (size_t)e*32);
    #pragma unroll
    for(int g = 0; g < 4; g++){
      i32x4 v; v[0]=(int)pk[g*4]; v[1]=(int)pk[g*4+1]; v[2]=(int)pk[g*4+2]; v[3]=(int)pk[g*4+3];
      outp[g] = v;
    }
  }
}

// ---------------------------------------------------------------- root (proven R5)
template<int DIN>
__global__ __launch_bounds__(256) void rootv2_kernel(const float* __restrict__ xin,
                                                     const float* __restrict__ root,
                                                     const float* __restrict__ bias,
                                                     float* __restrict__ xout){
  int n = blockIdx.x*256 + threadIdx.x;
  if(n >= NN) return;
  float xr[DIN];
  const f32x4* xp = (const f32x4*)(xin + (size_t)n*DIN);
  #pragma unroll
  for(int g = 0; g < DIN/4; g++){ f32x4 v = xp[g];
    #pragma unroll
    for(int j = 0; j < 4; j++) xr[g*4+j] = v[j]; }
  float acc[HD];
  #pragma unroll
  for(int o = 0; o < HD; o++) acc[o] = bias[o];
  #pragma unroll
  for(int k = 0; k < DIN; k++){
    float v = xr[k];
    #pragma unroll
    for(int o = 0; o < HD; o++) acc[o] = fmaf(v, root[k*HD + o], acc[o]);
  }
  f32x4* outp = (f32x4*)(xout + (size_t)n*HD);
  #pragma unroll
  for(int g = 0; g < 8; g++){ f32x4 v; v[0]=acc[g*4]; v[1]=acc[g*4+1]; v[2]=acc[g*4+2]; v[3]=acc[g*4+3]; outp[g] = v; }
}

// ---------------------------------------------------------------- msg v6: transposed xgs -> 1 ds_read_b128 per MFMA pair
template<int DIN, int NCH, int HALVES>
__global__ __launch_bounds__(512) void msg6_kernel(const short* __restrict__ T1,
                                                   const int* __restrict__ rowp,
                                                   const int* __restrict__ colp,
                                                   const float* __restrict__ xin,
                                                   const short* __restrict__ w2p,
                                                   const float* __restrict__ b2,
                                                   float* __restrict__ xout){
  constexpr int CH = NCH / HALVES;
  __shared__ short w2s[CH*512];
  __shared__ float b2s[NCH*16];
  __shared__ float xgs[8][DIN][16];     // transposed: [i][edge]

  const int tid = threadIdx.x;
  const int l   = tid & 63;
  const int wid = tid >> 6;             // 0..7
  const int grp = l >> 4, lo16 = l & 15;
  const int tile = blockIdx.x*8 + wid;
  const bool active = tile < NTILES;
  const int e0 = tile * 16;

  // stage x rows transposed (per-wave region; in-wave DS ordering handles hazards)
  if(active){
    int r = rowp[e0 + lo16];
    if(DIN == 32){
      const f32x4* xp = (const f32x4*)(xin + (size_t)r*32 + grp*8);
      f32x4 a = xp[0], b = xp[1];
      #pragma unroll
      for(int j = 0; j < 4; j++) xgs[wid][grp*8 + j][lo16]     = a[j];
      #pragma unroll
      for(int j = 0; j < 4; j++) xgs[wid][grp*8 + 4 + j][lo16] = b[j];
    } else {
      const f32x4* xp = (const f32x4*)(xin + (size_t)r*16 + grp*4);
      f32x4 a = xp[0];
      #pragma unroll
      for(int j = 0; j < 4; j++) xgs[wid][grp*4 + j][lo16] = a[j];
    }
  }

  bfrag af = {0,0,0,0,0,0,0,0};
  if(active) af = *(const bfrag*)(T1 + (size_t)(e0 + lo16)*32 + grp*8);

  f32x2 m0a = {0.f,0.f}, m0b = {0.f,0.f}, m1a = {0.f,0.f}, m1b = {0.f,0.f};

  for(int h = 0; h < HALVES; h++){
    if(h) __syncthreads();
    for(int t = tid; t < CH*64; t += 512)
      ((i32x4*)w2s)[t] = ((const i32x4*)w2p)[h*CH*64 + t];
    if(h == 0)
      for(int t = tid; t < NCH*16; t += 512) b2s[t] = b2[t];
    __syncthreads();

    if(active){
      #pragma unroll 4
      for(int i = 0; i < CH/2; i++){
        const int cg = h*CH + 2*i;
        const int ig = cg >> 1;
        float bv0 = b2s[cg*16 + lo16];
        float bv1 = b2s[(cg+1)*16 + lo16];
        f32x4 c0 = {bv0,bv0,bv0,bv0};
        f32x4 c1 = {bv1,bv1,bv1,bv1};
        bfrag b0 = *(const bfrag*)&w2s[((2*i  )*64 + l)*8];
        bfrag b1 = *(const bfrag*)&w2s[((2*i+1)*64 + l)*8];
        f32x4 u0 = __builtin_amdgcn_mfma_f32_16x16x32_bf16(af, b0, c0, 0, 0, 0);
        f32x4 u1 = __builtin_amdgcn_mfma_f32_16x16x32_bf16(af, b1, c1, 0, 0, 0);

        f32x4 xv = *(const f32x4*)&xgs[wid][ig][grp*4];   // one b128: xv for all 4 C-rows
        f32x2 xva = {xv[0], xv[1]}, xvb = {xv[2], xv[3]};
        f32x2 u0a = {u0[0],u0[1]}, u0b = {u0[2],u0[3]};
        f32x2 u1a = {u1[0],u1[1]}, u1b = {u1[2],u1[3]};
        f32x2 a0a = __builtin_elementwise_max(u0a, u0a*LEAK);
        f32x2 a0b = __builtin_elementwise_max(u0b, u0b*LEAK);
        f32x2 a1a = __builtin_elementwise_max(u1a, u1a*LEAK);
        f32x2 a1b = __builtin_elementwise_max(u1b, u1b*LEAK);
        m0a = __builtin_elementwise_fma(xva, a0a, m0a);
        m0b = __builtin_elementwise_fma(xvb, a0b, m0b);
        m1a = __builtin_elementwise_fma(xva, a1a, m1a);
        m1b = __builtin_elementwise_fma(xvb, a1b, m1b);
      }
    }
  }

  if(active){
    float m0[4] = {m0a[0], m0a[1], m0b[0], m0b[1]};
    float m1[4] = {m1a[0], m1a[1], m1b[0], m1b[1]};
    #pragma unroll
    for(int reg = 0; reg < 4; reg++){
      int ce = colp[e0 + grp*4 + reg];
      atomicAdd(&xout[(size_t)ce*HD + lo16],      m0[reg]);
      atomicAdd(&xout[(size_t)ce*HD + 16 + lo16], m1[reg]);
    }
  }
}

// ---------------------------------------------------------------- predictor v5: weights in VGPRs, 4 tiles/wave, no barriers
__global__ __launch_bounds__(256, 4) void pred5_kernel(const float* __restrict__ x,
                                                       const float* __restrict__ eraw,
                                                       const int* __restrict__ rowp,
                                                       const int* __restrict__ colp,
                                                       const short* __restrict__ predpk,
                                                       const float* __restrict__ biasP,
                                                       float* __restrict__ agg,
                                                       float* __restrict__ cnt){
  __shared__ short fAhi[4][16][104];
  __shared__ short fAlo[4][16][104];
  __shared__ short uAhi[4][16][40];
  __shared__ short uAlo[4][16][40];

  const int tid = threadIdx.x;
  const int l = tid & 63, wid = tid >> 6;
  const int grp = l >> 4, lo16 = l & 15;

  // weight B-frags resident in VGPRs (reused across 4 tiles)
  bfrag wb[14];
  #pragma unroll
  for(int c = 0; c < 14; c++) wb[c] = *(const bfrag*)(predpk + ((size_t)c*64 + l)*8);
  // per-lane biases: bP[stage][nc]
  float bP[8];
  #pragma unroll
  for(int s = 0; s < 4; s++){
    bP[s*2]   = biasP[s*32 + lo16];
    bP[s*2+1] = biasP[s*32 + 16 + lo16];
  }

  f32x4 z; z[0]=0.f; z[1]=0.f; z[2]=0.f; z[3]=0.f;
  const int tbase = (blockIdx.x*4 + wid) * 4;

  for(int tt = 0; tt < 4; tt++){
    const int tile = tbase + tt;
    if(tile >= NTILES) break;
    const int e0 = tile * 16;

    // ---- build feature tile (hi/lo)
    {
      float v[8];
      i32x4 h4, l4;
      int r = rowp[e0 + lo16];
      const float* xp = x + (size_t)r*32 + grp*8;
      #pragma unroll
      for(int j = 0; j < 8; j++) v[j] = xp[j];
      split8(v, h4, l4);
      *(i32x4*)&fAhi[wid][lo16][grp*8] = h4;
      *(i32x4*)&fAlo[wid][lo16][grp*8] = l4;

      int c = colp[e0 + lo16];
      const float* xq = x + (size_t)c*32 + grp*8;
      #pragma unroll
      for(int j = 0; j < 8; j++) v[j] = xq[j];
      split8(v, h4, l4);
      *(i32x4*)&fAhi[wid][lo16][32 + grp*8] = h4;
      *(i32x4*)&fAlo[wid][lo16][32 + grp*8] = l4;

      const float* ep = eraw + (size_t)(e0 + lo16)*EIN;
      #pragma unroll
      for(int j = 0; j < 8; j++){ int f = grp*8 + j; v[j] = (f < EIN) ? ep[f] : 0.f; }
      split8(v, h4, l4);
      *(i32x4*)&fAhi[wid][lo16][64 + grp*8] = h4;
      *(i32x4*)&fAlo[wid][lo16][64 + grp*8] = l4;
    }

    // ---- stage u: K=96 (chunks 0..5), leaky -> uA
    #pragma unroll
    for(int nc = 0; nc < 2; nc++){
      f32x4 acc = z;
      #pragma unroll
      for(int kb = 0; kb < 3; kb++){
        bfrag ah = *(const bfrag*)&fAhi[wid][lo16][kb*32 + grp*8];
        bfrag al = *(const bfrag*)&fAlo[wid][lo16][kb*32 + grp*8];
        acc = __builtin_amdgcn_mfma_f32_16x16x32_bf16(ah, wb[kb*2 + nc], acc, 0, 0, 0);
        acc = __builtin_amdgcn_mfma_f32_16x16x32_bf16(al, wb[kb*2 + nc], acc, 0, 0, 0);
      }
      int n = nc*16 + lo16;
      float bv = bP[nc];
      #pragma unroll
      for(int reg = 0; reg < 4; reg++){
        float uv = acc[reg] + bv; uv = fmaxf(uv, LEAK*uv);
        unsigned hh = f2bf(uv);
        float hf = __uint_as_float(hh << 16);
        uAhi[wid][grp*4 + reg][n] = (short)hh;
        uAlo[wid][grp*4 + reg][n] = (short)f2bf(uv - hf);
      }
    }

    // ---- stage e2: K=32 (chunks 6..7), linear -> fA cols 32..63
    #pragma unroll
    for(int nc = 0; nc < 2; nc++){
      f32x4 acc = z;
      bfrag ah = *(const bfrag*)&uAhi[wid][lo16][grp*8];
      bfrag al = *(const bfrag*)&uAlo[wid][lo16][grp*8];
      acc = __builtin_amdgcn_mfma_f32_16x16x32_bf16(ah, wb[6 + nc], acc, 0, 0, 0);
      acc = __builtin_amdgcn_mfma_f32_16x16x32_bf16(al, wb[6 + nc], acc, 0, 0, 0);
      int n = nc*16 + lo16;
      float bv = bP[2 + nc];
      #pragma unroll
      for(int reg = 0; reg < 4; reg++){
        float ev = acc[reg] + bv;
        unsigned hh = f2bf(ev);
        float hf = __uint_as_float(hh << 16);
        fAhi[wid][grp*4 + reg][32 + n] = (short)hh;
        fAlo[wid][grp*4 + reg][32 + n] = (short)f2bf(ev - hf);
      }
    }

    // ---- stage vv: K=64 (chunks 8..11: [xr|e2]), leaky -> uA
    #pragma unroll
    for(int nc = 0; nc < 2; nc++){
      f32x4 acc = z;
      #pragma unroll
      for(int kb = 0; kb < 2; kb++){
        bfrag ah = *(const bfrag*)&fAhi[wid][lo16][kb*32 + grp*8];
        bfrag al = *(const bfrag*)&fAlo[wid][lo16][kb*32 + grp*8];
        acc = __builtin_amdgcn_mfma_f32_16x16x32_bf16(ah, wb[8 + kb*2 + nc], acc, 0, 0, 0);
        acc = __builtin_amdgcn_mfma_f32_16x16x32_bf16(al, wb[8 + kb*2 + nc], acc, 0, 0, 0);
      }
      int n = nc*16 + lo16;
      float bv = bP[4 + nc];
      #pragma unroll
      for(int reg = 0; reg < 4; reg++){
        float vv = acc[reg] + bv; vv = fmaxf(vv, LEAK*vv);
        unsigned hh = f2bf(vv);
        float hf = __uint_as_float(hh << 16);
        uAhi[wid][grp*4 + reg][n] = (short)hh;
        uAlo[wid][grp*4 + reg][n] = (short)f2bf(vv - hf);
      }
    }

    // ---- stage h: K=32 (chunks 12..13), linear -> atomic scatter
    int ce[4];
    #pragma unroll
    for(int reg = 0; reg < 4; reg++) ce[reg] = colp[e0 + grp*4 + reg];

    #pragma unroll
    for(int nc = 0; nc < 2; nc++){
      f32x4 acc = z;
      bfrag ah = *(const bfrag*)&uAhi[wid][lo16][grp*8];
      bfrag al = *(const bfrag*)&uAlo[wid][lo16][grp*8];
      acc = __builtin_amdgcn_mfma_f32_16x16x32_bf16(ah, wb[12 + nc], acc, 0, 0, 0);
      acc = __builtin_amdgcn_mfma_f32_16x16x32_bf16(al, wb[12 + nc], acc, 0, 0, 0);
      int n = nc*16 + lo16;
      float bv = bP[6 + nc];
      #pragma unroll
      for(int reg = 0; reg < 4; reg++)
        atomicAdd(&agg[(size_t)ce[reg]*HD + n], acc[reg] + bv);
    }

    if(l < 16) atomicAdd(&cnt[colp[e0 + l]], 1.f);
  }
}

// ---------------------------------------------------------------- final node model + log_softmax
__global__ __launch_bounds__(256) void final_kernel(const float* __restrict__ x,
                                                    const float* __restrict__ agg,
                                                    const float* __restrict__ cnt,
                                                    const float* __restrict__ W1,
                                                    const float* __restrict__ b1,
                                                    const float* __restrict__ W2,
                                                    const float* __restrict__ b2,
                                                    float* __restrict__ out){
  int n = blockIdx.x*blockDim.x + threadIdx.x;
  if(n >= NN) return;
  float inv = 1.f / fmaxf(cnt[n], 1.f);
  const float* xp = x + (size_t)n * HD;
  const float* ap = agg + (size_t)n * HD;

  float t[HD];
  #pragma unroll
  for(int o = 0; o < HD; o++) t[o] = b1[o];
  #pragma unroll
  for(int k = 0; k < HD; k++){ float v = xp[k]; const float* wp = W1 + k*HD;
    #pragma unroll
    for(int o = 0; o < HD; o++) t[o] += v * wp[o]; }
  #pragma unroll
  for(int k = 0; k < HD; k++){ float v = ap[k] * inv; const float* wp = W1 + (HD+k)*HD;
    #pragma unroll
    for(int o = 0; o < HD; o++) t[o] += v * wp[o]; }

  float a0 = b2[0], a1 = b2[1];
  #pragma unroll
  for(int k = 0; k < HD; k++){ float v = lky(t[k]); a0 += v * W2[k*2]; a1 += v * W2[k*2+1]; }

  float m  = fmaxf(a0, a1);
  float ls = m + logf(expf(a0 - m) + expf(a1 - m));
  out[(size_t)n*2]   = a0 - ls;
  out[(size_t)n*2+1] = a1 - ls;
}

// ---------------------------------------------------------------- launch
extern "C" void kernel_launch(void* const* d_in, const int* in_sizes, int n_in,
                              void* d_out, int out_size, void* d_ws, size_t ws_size,
                              hipStream_t stream){
  const float* x  = (const float*)d_in[0];
  const int*   ei = (const int*)  d_in[1];
  const float* e  = (const float*)d_in[2];
  const float* bn_node_g = (const float*)d_in[4];
  const float* bn_node_b = (const float*)d_in[5];
  const float* bn_edge_g = (const float*)d_in[6];
  const float* bn_edge_b = (const float*)d_in[7];
  const float* lW1[3], *lb1[3], *lW2[3], *lb2[3], *lroot[3], *lbias[3];
  for(int l = 0; l < 3; l++){
    lW1[l]   = (const float*)d_in[8 + 6*l + 0];
    lb1[l]   = (const float*)d_in[8 + 6*l + 1];
    lW2[l]   = (const float*)d_in[8 + 6*l + 2];
    lb2[l]   = (const float*)d_in[8 + 6*l + 3];
    lroot[l] = (const float*)d_in[8 + 6*l + 4];
    lbias[l] = (const float*)d_in[8 + 6*l + 5];
  }
  const float* emW1  = (const float*)d_in[26];
  const float* emb1  = (const float*)d_in[27];
  const float* emW2  = (const float*)d_in[28];
  const float* emb2  = (const float*)d_in[29];
  const float* nm1W1 = (const float*)d_in[30];
  const float* nm1b1 = (const float*)d_in[31];
  const float* nm1W2 = (const float*)d_in[32];
  const float* nm1b2 = (const float*)d_in[33];
  const float* nm2W1 = (const float*)d_in[34];
  const float* nm2b1 = (const float*)d_in[35];
  const float* nm2W2 = (const float*)d_in[36];
  const float* nm2b2 = (const float*)d_in[37];

  const int* rowp = ei;
  const int* colp = ei + NE;

  // workspace layout (float units) — ws is 256 MB, plenty
  float* ws   = (float*)d_ws;
  float* x_bn = ws;                                 // NN*16
  float* x_a  = x_bn + (size_t)NN*NIN;              // NN*32
  float* x_b  = x_a  + (size_t)NN*HD;               // NN*32
  float* scr  = x_b  + (size_t)NN*HD;               // 16384 floats
  float* partial_e = scr;            // 5120
  float* partial_x = scr + 5120;     // 2048
  float* ss_g      = scr + 7168;     // 70
  float* W1f       = scr + 7424;     // 1920
  float* b1f       = scr + 9344;     // 96
  float* biasP     = scr + 9440;     // 128
  short* w2pk   = (short*)(scr + 16384);            // 3*32768 shorts
  short* predpk = w2pk + 3*32768;                   // 8192 shorts
  short* T10    = predpk + 8192;                    // NE*32 bf16
  short* T11    = T10 + (size_t)NE*32;
  short* T12    = T11 + (size_t)NE*32;
  float* agg    = (float*)T10;                      // alias (T10 dead after layer-0 msg)
  float* cnt    = agg + (size_t)NN*HD;

  stats_all_kernel<<<NBLK_E + NBLK_X, 256, 0, stream>>>(e, x, partial_e, partial_x);
  prep_kernel<<<1, 1024, 0, stream>>>(partial_e, partial_x,
                                      bn_edge_g, bn_edge_b, bn_node_g, bn_node_b,
                                      lW1[0], lb1[0], lW1[1], lb1[1], lW1[2], lb1[2],
                                      emW1, emb1, emW2, emb2,
                                      nm1W1, nm1b1, nm1W2, nm1b2,
                                      ss_g, W1f, b1f, biasP, predpk);
  w2pack_all_kernel<<<320, 256, 0, stream>>>(lW2[0], lW2[1], lW2[2], w2pk);
  normalize_kernel<NIN><<<1024, 256, 0, stream>>>(x, x_bn, ss_g + 2*EIN, NN);
  t1all_kernel<<<(NE + 255)/256, 256, 0, stream>>>(e, W1f, b1f, T10, T11, T12);

  const int nblocks  = (NN + 255)/256;     // 196
  const int m6blocks = (NTILES + 7)/8;     // 1172

  // layer 0 (din=16): x_bn -> x_a
  rootv2_kernel<NIN><<<nblocks, 256, 0, stream>>>(x_bn, lroot[0], lbias[0], x_a);
  msg6_kernel<NIN, 32, 2><<<m6blocks, 512, 0, stream>>>(T10, rowp, colp, x_bn,
                                                        w2pk + 0*32768, lb2[0], x_a);
  // layer 1 (din=32): x_a -> x_b
  rootv2_kernel<HD><<<nblocks, 256, 0, stream>>>(x_a, lroot[1], lbias[1], x_b);
  msg6_kernel<HD, 64, 2><<<m6blocks, 512, 0, stream>>>(T11, rowp, colp, x_a,
                                                       w2pk + 1*32768, lb2[1], x_b);
  // layer 2 (din=32): x_b -> x_a
  rootv2_kernel<HD><<<nblocks, 256, 0, stream>>>(x_b, lroot[2], lbias[2], x_a);
  msg6_kernel<HD, 64, 2><<<m6blocks, 512, 0, stream>>>(T12, rowp, colp, x_b,
                                                       w2pk + 2*32768, lb2[2], x_a);

  // predictor (agg/cnt alias T10 — zero first; T10 dead since layer-0 msg done)
  zero_kernel<<<2048, 256, 0, stream>>>(agg, NN*HD + NN);
  pred5_kernel<<<(NTILES + 15)/16, 256, 0, stream>>>(x_a, e, rowp, colp, predpk, biasP, agg, cnt);
  final_kernel<<<(NN + 255)/256, 256, 0, stream>>>(x_a, agg, cnt,
                                                   nm2W1, nm2b1, nm2W2, nm2b2,
                                                   (float*)d_out);
}

// Round 9
// 219.865 us; speedup vs baseline: 3.5831x; 1.1200x over previous
//
#include <hip/hip_runtime.h>
#include <math.h>

constexpr int NN  = 50000;   // nodes
constexpr int NE  = 150000;  // edges
constexpr int NIN = 16;      // node features in
constexpr int EIN = 19;      // edge features in
constexpr int HD  = 32;      // hidden H
constexpr int NTILES = NE / 16;  // 9375
constexpr int NBLK_E = 128;
constexpr int NBLK_X = 64;

#define LEAK  0.1f
#define BNEPS 1e-5f

typedef __attribute__((ext_vector_type(8))) short bfrag;
typedef __attribute__((ext_vector_type(4))) float f32x4;
typedef __attribute__((ext_vector_type(2))) float f32x2;
typedef __attribute__((ext_vector_type(4))) int   i32x4;

__device__ __forceinline__ float lky(float v){ return fmaxf(v, LEAK*v); }
__device__ __forceinline__ unsigned f2bf(float f){
  unsigned u = __float_as_uint(f);
  return ((u + 0x7FFFu + ((u >> 16) & 1u)) >> 16);   // RNE
}
__device__ __forceinline__ void split8(const float* v, i32x4& h4, i32x4& l4){
  unsigned hs[8], ls[8];
  #pragma unroll
  for(int j = 0; j < 8; j++){
    unsigned hh = f2bf(v[j]);
    float hf = __uint_as_float(hh << 16);
    hs[j] = hh; ls[j] = f2bf(v[j] - hf);
  }
  h4[0] = (int)(hs[0] | (hs[1]<<16)); h4[1] = (int)(hs[2] | (hs[3]<<16));
  h4[2] = (int)(hs[4] | (hs[5]<<16)); h4[3] = (int)(hs[6] | (hs[7]<<16));
  l4[0] = (int)(ls[0] | (ls[1]<<16)); l4[1] = (int)(ls[2] | (ls[3]<<16));
  l4[2] = (int)(ls[4] | (ls[5]<<16)); l4[3] = (int)(ls[6] | (ls[7]<<16));
}

// ---------------------------------------------------------------- zero
__global__ void zero_kernel(float* __restrict__ p, int n){
  int stride = gridDim.x * blockDim.x;
  for(int i = blockIdx.x*blockDim.x + threadIdx.x; i < n; i += stride) p[i] = 0.f;
}

// ---------------------------------------------------------------- stats (proven R5)
__global__ __launch_bounds__(256) void stats_all_kernel(const float* __restrict__ e,
                                                        const float* __restrict__ x,
                                                        float* __restrict__ partial_e,
                                                        float* __restrict__ partial_x){
  __shared__ float red[4][40];
  const int tid = threadIdx.x, lane = tid & 63, wid = tid >> 6;
  if(blockIdx.x < NBLK_E){
    float s[EIN], q[EIN];
    #pragma unroll
    for(int c = 0; c < EIN; c++){ s[c] = 0.f; q[c] = 0.f; }
    const int gstride = NBLK_E * 256;
    for(int g = blockIdx.x*256 + tid; g < NE/4; g += gstride){
      const f32x4* p = (const f32x4*)(e + (size_t)g * 76);
      #pragma unroll
      for(int m = 0; m < 19; m++){
        f32x4 v = p[m];
        #pragma unroll
        for(int j = 0; j < 4; j++){
          int c = (4*m + j) % 19;
          s[c] += v[j]; q[c] = fmaf(v[j], v[j], q[c]);
        }
      }
    }
    #pragma unroll
    for(int off = 32; off; off >>= 1){
      #pragma unroll
      for(int c = 0; c < EIN; c++){ s[c] += __shfl_xor(s[c], off); q[c] += __shfl_xor(q[c], off); }
    }
    if(lane == 0){
      #pragma unroll
      for(int c = 0; c < EIN; c++){ red[wid][c] = s[c]; red[wid][20 + c] = q[c]; }
    }
    __syncthreads();
    if(tid < 39 && tid != 19)
      partial_e[blockIdx.x*40 + tid] = red[0][tid] + red[1][tid] + red[2][tid] + red[3][tid];
  } else {
    float s[NIN], q[NIN];
    #pragma unroll
    for(int c = 0; c < NIN; c++){ s[c] = 0.f; q[c] = 0.f; }
    const int bid = blockIdx.x - NBLK_E;
    const int gstride = NBLK_X * 256;
    for(int r = bid*256 + tid; r < NN; r += gstride){
      const f32x4* p = (const f32x4*)(x + (size_t)r * NIN);
      #pragma unroll
      for(int m = 0; m < 4; m++){
        f32x4 v = p[m];
        #pragma unroll
        for(int j = 0; j < 4; j++){
          int c = 4*m + j;
          s[c] += v[j]; q[c] = fmaf(v[j], v[j], q[c]);
        }
      }
    }
    #pragma unroll
    for(int off = 32; off; off >>= 1){
      #pragma unroll
      for(int c = 0; c < NIN; c++){ s[c] += __shfl_xor(s[c], off); q[c] += __shfl_xor(q[c], off); }
    }
    if(lane == 0){
      #pragma unroll
      for(int c = 0; c < NIN; c++){ red[wid][c] = s[c]; red[wid][16 + c] = q[c]; }
    }
    __syncthreads();
    if(tid < 32)
      partial_x[bid*32 + tid] = red[0][tid] + red[1][tid] + red[2][tid] + red[3][tid];
  }
}

// ---------------------------------------------------------------- prep (proven R5)
__global__ __launch_bounds__(1024) void prep_kernel(const float* __restrict__ partial_e,
                                                    const float* __restrict__ partial_x,
                                                    const float* __restrict__ ge, const float* __restrict__ be,
                                                    const float* __restrict__ gx, const float* __restrict__ bx,
                                                    const float* __restrict__ l0W1, const float* __restrict__ l0b1,
                                                    const float* __restrict__ l1W1, const float* __restrict__ l1b1,
                                                    const float* __restrict__ l2W1, const float* __restrict__ l2b1,
                                                    const float* __restrict__ emW1, const float* __restrict__ emb1,
                                                    const float* __restrict__ emW2, const float* __restrict__ emb2,
                                                    const float* __restrict__ nm1W1, const float* __restrict__ nm1b1,
                                                    const float* __restrict__ nm1W2, const float* __restrict__ nm1b2,
                                                    float* __restrict__ ss_g, float* __restrict__ W1f,
                                                    float* __restrict__ b1f, float* __restrict__ biasP,
                                                    short* __restrict__ predpk){
  __shared__ float ss[70];
  __shared__ float emW1f[608];
  __shared__ float emb1f[32];
  __shared__ float predW[7168];
  const int t = threadIdx.x;

  if(t < EIN){
    float s = 0.f, q = 0.f;
    for(int b = 0; b < NBLK_E; b++){ s += partial_e[b*40 + t]; q += partial_e[b*40 + 20 + t]; }
    float m = s / (float)NE;
    float v = q / (float)NE - m*m;
    float sc = ge[t] * rsqrtf(v + BNEPS);
    ss[t] = sc; ss[EIN + t] = be[t] - m*sc;
  } else if(t >= 32 && t < 32 + NIN){
    int c = t - 32;
    float s = 0.f, q = 0.f;
    for(int b = 0; b < NBLK_X; b++){ s += partial_x[b*32 + c]; q += partial_x[b*32 + 16 + c]; }
    float m = s / (float)NN;
    float v = q / (float)NN - m*m;
    float sc = gx[c] * rsqrtf(v + BNEPS);
    ss[2*EIN + c] = sc; ss[2*EIN + NIN + c] = bx[c] - m*sc;
  }
  __syncthreads();
  if(t < 70) ss_g[t] = ss[t];

  if(t < 128){
    int seg = t >> 5, j = t & 31;
    if(seg == 0){
      if(j < NIN){
        float acc = l0b1[j];
        for(int k = 0; k < EIN; k++){
          W1f[0*640 + k*NIN + j] = ss[k] * l0W1[k*NIN + j];
          acc += ss[EIN+k] * l0W1[k*NIN + j];
        }
        b1f[0*32 + j] = acc;
      }
    } else if(seg == 1){
      float acc = l1b1[j];
      for(int k = 0; k < EIN; k++){
        W1f[1*640 + k*HD + j] = ss[k] * l1W1[k*HD + j];
        acc += ss[EIN+k] * l1W1[k*HD + j];
      }
      b1f[1*32 + j] = acc;
    } else if(seg == 2){
      float acc = l2b1[j];
      for(int k = 0; k < EIN; k++){
        W1f[2*640 + k*HD + j] = ss[k] * l2W1[k*HD + j];
        acc += ss[EIN+k] * l2W1[k*HD + j];
      }
      b1f[2*32 + j] = acc;
    } else {
      float acc = emb1[j];
      for(int k = 0; k < EIN; k++){
        emW1f[k*HD + j] = ss[k] * emW1[(2*HD+k)*HD + j];
        acc += ss[EIN+k] * emW1[(2*HD+k)*HD + j];
      }
      emb1f[j] = acc;
    }
  }
  __syncthreads();

  for(int i = t; i < 224*32; i += 1024){
    int k = i >> 5, n = i & 31;
    float v;
    if(k < 64)       v = emW1[k*32 + n];
    else if(k < 83)  v = emW1f[(k-64)*32 + n];
    else if(k < 96)  v = 0.f;
    else if(k < 128) v = emW2[(k-96)*32 + n];
    else if(k < 192) v = nm1W1[(k-128)*32 + n];
    else             v = nm1W2[(k-192)*32 + n];
    predW[i] = v;
  }
  if(t < 128){
    int s = t >> 5, n = t & 31;
    biasP[t] = (s==0) ? emb1f[n] : (s==1) ? emb2[n] : (s==2) ? nm1b1[n] : nm1b2[n];
  }
  __syncthreads();

  for(int idx = t; idx < 14*512; idx += 1024){
    int c = idx >> 9, l = (idx >> 3) & 63, j = idx & 7;
    int kbg = c >> 1, nc = c & 1;
    int k = kbg*32 + 8*(l>>4) + j;
    int n = nc*16 + (l & 15);
    predpk[idx] = (short)f2bf(predW[k*32 + n]);
  }
}

// ---------------------------------------------------------------- pack all three W2
__global__ __launch_bounds__(256) void w2pack_all_kernel(const float* __restrict__ W20,
                                                         const float* __restrict__ W21,
                                                         const float* __restrict__ W22,
                                                         short* __restrict__ w2pk){
  int idx = blockIdx.x*256 + threadIdx.x;
  if(idx >= 81920) return;
  const float* W2; int DIN, base, ci;
  if(idx < 16384){ W2 = W20; DIN = 16; base = 0;     ci = idx; }
  else if(idx < 49152){ W2 = W21; DIN = 32; base = 32768; ci = idx - 16384; }
  else { W2 = W22; DIN = 32; base = 65536; ci = idx - 49152; }
  int c = ci >> 9, l = (ci >> 3) & 63, j = ci & 7;
  int k = 8*(l>>4) + j;
  int n = c*16 + (l & 15);
  float v = (k < DIN) ? W2[(size_t)k*(DIN*HD) + n] : 0.f;
  w2pk[base + ci] = (short)f2bf(v);
}

// ---------------------------------------------------------------- fused: BN-normalize(x) + layer0 root GEMV
__global__ __launch_bounds__(256) void norm_root_kernel(const float* __restrict__ x,
                                                        const float* __restrict__ ssx,   // scale[16], shift[16]
                                                        const float* __restrict__ root,  // [16][32]
                                                        const float* __restrict__ bias,  // [32]
                                                        float* __restrict__ x_bn,
                                                        float* __restrict__ x_a){
  __shared__ float rs[NIN*HD];
  __shared__ float scs[NIN], shs[NIN], bs[HD];
  const int tid = threadIdx.x;
  for(int i = tid; i < NIN*HD; i += 256) rs[i] = root[i];
  if(tid < NIN){ scs[tid] = ssx[tid]; shs[tid] = ssx[NIN + tid]; }
  else if(tid < NIN + HD) bs[tid - NIN] = bias[tid - NIN];
  __syncthreads();

  int n = blockIdx.x*256 + tid;
  if(n >= NN) return;
  float xb[NIN];
  const f32x4* xp = (const f32x4*)(x + (size_t)n*NIN);
  #pragma unroll
  for(int g = 0; g < 4; g++){
    f32x4 v = xp[g];
    #pragma unroll
    for(int j = 0; j < 4; j++) xb[g*4+j] = fmaf(v[j], scs[g*4+j], shs[g*4+j]);
  }
  f32x4* obn = (f32x4*)(x_bn + (size_t)n*NIN);
  #pragma unroll
  for(int g = 0; g < 4; g++){
    f32x4 v; v[0]=xb[g*4]; v[1]=xb[g*4+1]; v[2]=xb[g*4+2]; v[3]=xb[g*4+3];
    obn[g] = v;
  }
  f32x4 a0 = *(const f32x4*)&bs[0],  a1 = *(const f32x4*)&bs[4];
  f32x4 a2 = *(const f32x4*)&bs[8],  a3 = *(const f32x4*)&bs[12];
  f32x4 a4 = *(const f32x4*)&bs[16], a5 = *(const f32x4*)&bs[20];
  f32x4 a6 = *(const f32x4*)&bs[24], a7 = *(const f32x4*)&bs[28];
  #pragma unroll
  for(int k = 0; k < NIN; k++){
    float v = xb[k];
    const f32x4* wp = (const f32x4*)&rs[k*HD];
    a0 = __builtin_elementwise_fma((f32x4){v,v,v,v}, wp[0], a0);
    a1 = __builtin_elementwise_fma((f32x4){v,v,v,v}, wp[1], a1);
    a2 = __builtin_elementwise_fma((f32x4){v,v,v,v}, wp[2], a2);
    a3 = __builtin_elementwise_fma((f32x4){v,v,v,v}, wp[3], a3);
    a4 = __builtin_elementwise_fma((f32x4){v,v,v,v}, wp[4], a4);
    a5 = __builtin_elementwise_fma((f32x4){v,v,v,v}, wp[5], a5);
    a6 = __builtin_elementwise_fma((f32x4){v,v,v,v}, wp[6], a6);
    a7 = __builtin_elementwise_fma((f32x4){v,v,v,v}, wp[7], a7);
  }
  f32x4* outp = (f32x4*)(x_a + (size_t)n*HD);
  outp[0]=a0; outp[1]=a1; outp[2]=a2; outp[3]=a3;
  outp[4]=a4; outp[5]=a5; outp[6]=a6; outp[7]=a7;
}

// ---------------------------------------------------------------- T1 for ALL layers in one pass over e
__global__ __launch_bounds__(256) void t1all_kernel(const float* __restrict__ eraw,
                                                    const float* __restrict__ W1f,
                                                    const float* __restrict__ b1f,
                                                    short* __restrict__ T10,
                                                    short* __restrict__ T11,
                                                    short* __restrict__ T12){
  int e = blockIdx.x*256 + threadIdx.x;
  if(e >= NE) return;
  const float* ep = eraw + (size_t)e*EIN;
  float eb[EIN];
  #pragma unroll
  for(int k = 0; k < EIN; k++) eb[k] = ep[k];

  {
    float tv[16];
    #pragma unroll
    for(int j = 0; j < 16; j++) tv[j] = b1f[j];
    #pragma unroll
    for(int k = 0; k < EIN; k++){
      float v = eb[k];
      #pragma unroll
      for(int j = 0; j < 16; j++) tv[j] = fmaf(v, W1f[k*16 + j], tv[j]);
    }
    unsigned pk[8];
    #pragma unroll
    for(int p = 0; p < 8; p++){
      float a = tv[2*p], b = tv[2*p+1];
      pk[p] = f2bf(fmaxf(a, LEAK*a)) | (f2bf(fmaxf(b, LEAK*b)) << 16);
    }
    i32x4* outp = (i32x4*)(T10 + (size_t)e*32);
    i32x4 v0; v0[0]=(int)pk[0]; v0[1]=(int)pk[1]; v0[2]=(int)pk[2]; v0[3]=(int)pk[3];
    i32x4 v1; v1[0]=(int)pk[4]; v1[1]=(int)pk[5]; v1[2]=(int)pk[6]; v1[3]=(int)pk[7];
    i32x4 zz; zz[0]=0; zz[1]=0; zz[2]=0; zz[3]=0;
    outp[0] = v0; outp[1] = v1; outp[2] = zz; outp[3] = zz;
  }
  #pragma unroll
  for(int l = 1; l < 3; l++){
    const float* Wl = W1f + l*640;
    const float* bl = b1f + l*32;
    short* Tl = (l == 1) ? T11 : T12;
    float tv[32];
    #pragma unroll
    for(int j = 0; j < 32; j++) tv[j] = bl[j];
    #pragma unroll
    for(int k = 0; k < EIN; k++){
      float v = eb[k];
      #pragma unroll
      for(int j = 0; j < 32; j++) tv[j] = fmaf(v, Wl[k*32 + j], tv[j]);
    }
    unsigned pk[16];
    #pragma unroll
    for(int p = 0; p < 16; p++){
      float a = tv[2*p], b = tv[2*p+1];
      pk[p] = f2bf(fmaxf(a, LEAK*a)) | (f2bf(fmaxf(b, LEAK*b)) << 16);
    }
    i32x4* outp = (i32x4*)(Tl + (size_t)e*32);
    #pragma unroll
    for(int g = 0; g < 4; g++){
      i32x4 v; v[0]=(int)pk[g*4]; v[1]=(int)pk[g*4+1]; v[2]=(int)pk[g*4+2]; v[3]=(int)pk[g*4+3];
      outp[g] = v;
    }
  }
}

// ---------------------------------------------------------------- root (layers 1,2)
template<int DIN>
__global__ __launch_bounds__(256) void rootv2_kernel(const float* __restrict__ xin,
                                                     const float* __restrict__ root,
                                                     const float* __restrict__ bias,
                                                     float* __restrict__ xout){
  int n = blockIdx.x*256 + threadIdx.x;
  if(n >= NN) return;
  float xr[DIN];
  const f32x4* xp = (const f32x4*)(xin + (size_t)n*DIN);
  #pragma unroll
  for(int g = 0; g < DIN/4; g++){ f32x4 v = xp[g];
    #pragma unroll
    for(int j = 0; j < 4; j++) xr[g*4+j] = v[j]; }
  float acc[HD];
  #pragma unroll
  for(int o = 0; o < HD; o++) acc[o] = bias[o];
  #pragma unroll
  for(int k = 0; k < DIN; k++){
    float v = xr[k];
    #pragma unroll
    for(int o = 0; o < HD; o++) acc[o] = fmaf(v, root[k*HD + o], acc[o]);
  }
  f32x4* outp = (f32x4*)(xout + (size_t)n*HD);
  #pragma unroll
  for(int g = 0; g < 8; g++){ f32x4 v; v[0]=acc[g*4]; v[1]=acc[g*4+1]; v[2]=acc[g*4+2]; v[3]=acc[g*4+3]; outp[g] = v; }
}

// ---------------------------------------------------------------- msg v6 (proven R7)
template<int DIN, int NCH, int HALVES>
__global__ __launch_bounds__(512) void msg6_kernel(const short* __restrict__ T1,
                                                   const int* __restrict__ rowp,
                                                   const int* __restrict__ colp,
                                                   const float* __restrict__ xin,
                                                   const short* __restrict__ w2p,
                                                   const float* __restrict__ b2,
                                                   float* __restrict__ xout){
  constexpr int CH = NCH / HALVES;
  __shared__ short w2s[CH*512];
  __shared__ float b2s[NCH*16];
  __shared__ float xgs[8][DIN][16];     // transposed: [i][edge]

  const int tid = threadIdx.x;
  const int l   = tid & 63;
  const int wid = tid >> 6;
  const int grp = l >> 4, lo16 = l & 15;
  const int tile = blockIdx.x*8 + wid;
  const bool active = tile < NTILES;
  const int e0 = tile * 16;

  if(active){
    int r = rowp[e0 + lo16];
    if(DIN == 32){
      const f32x4* xp = (const f32x4*)(xin + (size_t)r*32 + grp*8);
      f32x4 a = xp[0], b = xp[1];
      #pragma unroll
      for(int j = 0; j < 4; j++) xgs[wid][grp*8 + j][lo16]     = a[j];
      #pragma unroll
      for(int j = 0; j < 4; j++) xgs[wid][grp*8 + 4 + j][lo16] = b[j];
    } else {
      const f32x4* xp = (const f32x4*)(xin + (size_t)r*16 + grp*4);
      f32x4 a = xp[0];
      #pragma unroll
      for(int j = 0; j < 4; j++) xgs[wid][grp*4 + j][lo16] = a[j];
    }
  }

  bfrag af = {0,0,0,0,0,0,0,0};
  if(active) af = *(const bfrag*)(T1 + (size_t)(e0 + lo16)*32 + grp*8);

  f32x2 m0a = {0.f,0.f}, m0b = {0.f,0.f}, m1a = {0.f,0.f}, m1b = {0.f,0.f};

  for(int h = 0; h < HALVES; h++){
    if(h) __syncthreads();
    for(int t = tid; t < CH*64; t += 512)
      ((i32x4*)w2s)[t] = ((const i32x4*)w2p)[h*CH*64 + t];
    if(h == 0)
      for(int t = tid; t < NCH*16; t += 512) b2s[t] = b2[t];
    __syncthreads();

    if(active){
      #pragma unroll 4
      for(int i = 0; i < CH/2; i++){
        const int cg = h*CH + 2*i;
        const int ig = cg >> 1;
        float bv0 = b2s[cg*16 + lo16];
        float bv1 = b2s[(cg+1)*16 + lo16];
        f32x4 c0 = {bv0,bv0,bv0,bv0};
        f32x4 c1 = {bv1,bv1,bv1,bv1};
        bfrag b0 = *(const bfrag*)&w2s[((2*i  )*64 + l)*8];
        bfrag b1 = *(const bfrag*)&w2s[((2*i+1)*64 + l)*8];
        f32x4 u0 = __builtin_amdgcn_mfma_f32_16x16x32_bf16(af, b0, c0, 0, 0, 0);
        f32x4 u1 = __builtin_amdgcn_mfma_f32_16x16x32_bf16(af, b1, c1, 0, 0, 0);

        f32x4 xv = *(const f32x4*)&xgs[wid][ig][grp*4];
        f32x2 xva = {xv[0], xv[1]}, xvb = {xv[2], xv[3]};
        f32x2 u0a = {u0[0],u0[1]}, u0b = {u0[2],u0[3]};
        f32x2 u1a = {u1[0],u1[1]}, u1b = {u1[2],u1[3]};
        f32x2 a0a = __builtin_elementwise_max(u0a, u0a*LEAK);
        f32x2 a0b = __builtin_elementwise_max(u0b, u0b*LEAK);
        f32x2 a1a = __builtin_elementwise_max(u1a, u1a*LEAK);
        f32x2 a1b = __builtin_elementwise_max(u1b, u1b*LEAK);
        m0a = __builtin_elementwise_fma(xva, a0a, m0a);
        m0b = __builtin_elementwise_fma(xvb, a0b, m0b);
        m1a = __builtin_elementwise_fma(xva, a1a, m1a);
        m1b = __builtin_elementwise_fma(xvb, a1b, m1b);
      }
    }
  }

  if(active){
    float m0[4] = {m0a[0], m0a[1], m0b[0], m0b[1]};
    float m1[4] = {m1a[0], m1a[1], m1b[0], m1b[1]};
    #pragma unroll
    for(int reg = 0; reg < 4; reg++){
      int ce = colp[e0 + grp*4 + reg];
      atomicAdd(&xout[(size_t)ce*HD + lo16],      m0[reg]);
      atomicAdd(&xout[(size_t)ce*HD + 16 + lo16], m1[reg]);
    }
  }
}

// ---------------------------------------------------------------- predictor v5 (proven R7)
__global__ __launch_bounds__(256, 4) void pred5_kernel(const float* __restrict__ x,
                                                       const float* __restrict__ eraw,
                                                       const int* __restrict__ rowp,
                                                       const int* __restrict__ colp,
                                                       const short* __restrict__ predpk,
                                                       const float* __restrict__ biasP,
                                                       float* __restrict__ agg,
                                                       float* __restrict__ cnt){
  __shared__ short fAhi[4][16][104];
  __shared__ short fAlo[4][16][104];
  __shared__ short uAhi[4][16][40];
  __shared__ short uAlo[4][16][40];

  const int tid = threadIdx.x;
  const int l = tid & 63, wid = tid >> 6;
  const int grp = l >> 4, lo16 = l & 15;

  bfrag wb[14];
  #pragma unroll
  for(int c = 0; c < 14; c++) wb[c] = *(const bfrag*)(predpk + ((size_t)c*64 + l)*8);
  float bP[8];
  #pragma unroll
  for(int s = 0; s < 4; s++){
    bP[s*2]   = biasP[s*32 + lo16];
    bP[s*2+1] = biasP[s*32 + 16 + lo16];
  }

  f32x4 z; z[0]=0.f; z[1]=0.f; z[2]=0.f; z[3]=0.f;
  const int tbase = (blockIdx.x*4 + wid) * 4;

  for(int tt = 0; tt < 4; tt++){
    const int tile = tbase + tt;
    if(tile >= NTILES) break;
    const int e0 = tile * 16;

    {
      float v[8];
      i32x4 h4, l4;
      int r = rowp[e0 + lo16];
      const float* xp = x + (size_t)r*32 + grp*8;
      #pragma unroll
      for(int j = 0; j < 8; j++) v[j] = xp[j];
      split8(v, h4, l4);
      *(i32x4*)&fAhi[wid][lo16][grp*8] = h4;
      *(i32x4*)&fAlo[wid][lo16][grp*8] = l4;

      int c = colp[e0 + lo16];
      const float* xq = x + (size_t)c*32 + grp*8;
      #pragma unroll
      for(int j = 0; j < 8; j++) v[j] = xq[j];
      split8(v, h4, l4);
      *(i32x4*)&fAhi[wid][lo16][32 + grp*8] = h4;
      *(i32x4*)&fAlo[wid][lo16][32 + grp*8] = l4;

      const float* ep = eraw + (size_t)(e0 + lo16)*EIN;
      #pragma unroll
      for(int j = 0; j < 8; j++){ int f = grp*8 + j; v[j] = (f < EIN) ? ep[f] : 0.f; }
      split8(v, h4, l4);
      *(i32x4*)&fAhi[wid][lo16][64 + grp*8] = h4;
      *(i32x4*)&fAlo[wid][lo16][64 + grp*8] = l4;
    }

    #pragma unroll
    for(int nc = 0; nc < 2; nc++){
      f32x4 acc = z;
      #pragma unroll
      for(int kb = 0; kb < 3; kb++){
        bfrag ah = *(const bfrag*)&fAhi[wid][lo16][kb*32 + grp*8];
        bfrag al = *(const bfrag*)&fAlo[wid][lo16][kb*32 + grp*8];
        acc = __builtin_amdgcn_mfma_f32_16x16x32_bf16(ah, wb[kb*2 + nc], acc, 0, 0, 0);
        acc = __builtin_amdgcn_mfma_f32_16x16x32_bf16(al, wb[kb*2 + nc], acc, 0, 0, 0);
      }
      int n = nc*16 + lo16;
      float bv = bP[nc];
      #pragma unroll
      for(int reg = 0; reg < 4; reg++){
        float uv = acc[reg] + bv; uv = fmaxf(uv, LEAK*uv);
        unsigned hh = f2bf(uv);
        float hf = __uint_as_float(hh << 16);
        uAhi[wid][grp*4 + reg][n] = (short)hh;
        uAlo[wid][grp*4 + reg][n] = (short)f2bf(uv - hf);
      }
    }

    #pragma unroll
    for(int nc = 0; nc < 2; nc++){
      f32x4 acc = z;
      bfrag ah = *(const bfrag*)&uAhi[wid][lo16][grp*8];
      bfrag al = *(const bfrag*)&uAlo[wid][lo16][grp*8];
      acc = __builtin_amdgcn_mfma_f32_16x16x32_bf16(ah, wb[6 + nc], acc, 0, 0, 0);
      acc = __builtin_amdgcn_mfma_f32_16x16x32_bf16(al, wb[6 + nc], acc, 0, 0, 0);
      int n = nc*16 + lo16;
      float bv = bP[2 + nc];
      #pragma unroll
      for(int reg = 0; reg < 4; reg++){
        float ev = acc[reg] + bv;
        unsigned hh = f2bf(ev);
        float hf = __uint_as_float(hh << 16);
        fAhi[wid][grp*4 + reg][32 + n] = (short)hh;
        fAlo[wid][grp*4 + reg][32 + n] = (short)f2bf(ev - hf);
      }
    }

    #pragma unroll
    for(int nc = 0; nc < 2; nc++){
      f32x4 acc = z;
      #pragma unroll
      for(int kb = 0; kb < 2; kb++){
        bfrag ah = *(const bfrag*)&fAhi[wid][lo16][kb*32 + grp*8];
        bfrag al = *(const bfrag*)&fAlo[wid][lo16][kb*32 + grp*8];
        acc = __builtin_amdgcn_mfma_f32_16x16x32_bf16(ah, wb[8 + kb*2 + nc], acc, 0, 0, 0);
        acc = __builtin_amdgcn_mfma_f32_16x16x32_bf16(al, wb[8 + kb*2 + nc], acc, 0, 0, 0);
      }
      int n = nc*16 + lo16;
      float bv = bP[4 + nc];
      #pragma unroll
      for(int reg = 0; reg < 4; reg++){
        float vv = acc[reg] + bv; vv = fmaxf(vv, LEAK*vv);
        unsigned hh = f2bf(vv);
        float hf = __uint_as_float(hh << 16);
        uAhi[wid][grp*4 + reg][n] = (short)hh;
        uAlo[wid][grp*4 + reg][n] = (short)f2bf(vv - hf);
      }
    }

    int ce[4];
    #pragma unroll
    for(int reg = 0; reg < 4; reg++) ce[reg] = colp[e0 + grp*4 + reg];

    #pragma unroll
    for(int nc = 0; nc < 2; nc++){
      f32x4 acc = z;
      bfrag ah = *(const bfrag*)&uAhi[wid][lo16][grp*8];
      bfrag al = *(const bfrag*)&uAlo[wid][lo16][grp*8];
      acc = __builtin_amdgcn_mfma_f32_16x16x32_bf16(ah, wb[12 + nc], acc, 0, 0, 0);
      acc = __builtin_amdgcn_mfma_f32_16x16x32_bf16(al, wb[12 + nc], acc, 0, 0, 0);
      int n = nc*16 + lo16;
      float bv = bP[6 + nc];
      #pragma unroll
      for(int reg = 0; reg < 4; reg++)
        atomicAdd(&agg[(size_t)ce[reg]*HD + n], acc[reg] + bv);
    }

    if(l < 16) atomicAdd(&cnt[colp[e0 + l]], 1.f);
  }
}

// ---------------------------------------------------------------- final v2: LDS weights, f32x4 register accumulators
__global__ __launch_bounds__(256) void final2_kernel(const float* __restrict__ x,
                                                     const float* __restrict__ agg,
                                                     const float* __restrict__ cnt,
                                                     const float* __restrict__ W1,
                                                     const float* __restrict__ b1,
                                                     const float* __restrict__ W2,
                                                     const float* __restrict__ b2,
                                                     float* __restrict__ out){
  __shared__ float w1s[2*HD*HD];   // 2048
  __shared__ float w2s[HD*2];      // 64
  __shared__ float b1s[HD];
  __shared__ float b2s[2];
  const int tid = threadIdx.x;
  for(int i = tid; i < 2*HD*HD; i += 256) w1s[i] = W1[i];
  if(tid < 64) w2s[tid] = W2[tid];
  if(tid < HD) b1s[tid] = b1[tid];
  if(tid < 2)  b2s[tid] = b2[tid];
  __syncthreads();

  int n = blockIdx.x*256 + tid;
  if(n >= NN) return;
  float inv = 1.f / fmaxf(cnt[n], 1.f);

  float xin[HD], ain[HD];
  const f32x4* xp = (const f32x4*)(x + (size_t)n*HD);
  const f32x4* ap = (const f32x4*)(agg + (size_t)n*HD);
  #pragma unroll
  for(int g = 0; g < 8; g++){
    f32x4 v = xp[g];
    #pragma unroll
    for(int j = 0; j < 4; j++) xin[g*4+j] = v[j];
  }
  #pragma unroll
  for(int g = 0; g < 8; g++){
    f32x4 v = ap[g];
    #pragma unroll
    for(int j = 0; j < 4; j++) ain[g*4+j] = v[j] * inv;
  }

  f32x4 a0 = *(const f32x4*)&b1s[0],  a1 = *(const f32x4*)&b1s[4];
  f32x4 a2 = *(const f32x4*)&b1s[8],  a3 = *(const f32x4*)&b1s[12];
  f32x4 a4 = *(const f32x4*)&b1s[16], a5 = *(const f32x4*)&b1s[20];
  f32x4 a6 = *(const f32x4*)&b1s[24], a7 = *(const f32x4*)&b1s[28];
  #pragma unroll
  for(int k = 0; k < HD; k++){
    float v = xin[k];
    const f32x4* wp = (const f32x4*)&w1s[k*HD];
    f32x4 vv = {v,v,v,v};
    a0 = __builtin_elementwise_fma(vv, wp[0], a0);
    a1 = __builtin_elementwise_fma(vv, wp[1], a1);
    a2 = __builtin_elementwise_fma(vv, wp[2], a2);
    a3 = __builtin_elementwise_fma(vv, wp[3], a3);
    a4 = __builtin_elementwise_fma(vv, wp[4], a4);
    a5 = __builtin_elementwise_fma(vv, wp[5], a5);
    a6 = __builtin_elementwise_fma(vv, wp[6], a6);
    a7 = __builtin_elementwise_fma(vv, wp[7], a7);
  }
  #pragma unroll
  for(int k = 0; k < HD; k++){
    float v = ain[k];
    const f32x4* wp = (const f32x4*)&w1s[(HD+k)*HD];
    f32x4 vv = {v,v,v,v};
    a0 = __builtin_elementwise_fma(vv, wp[0], a0);
    a1 = __builtin_elementwise_fma(vv, wp[1], a1);
    a2 = __builtin_elementwise_fma(vv, wp[2], a2);
    a3 = __builtin_elementwise_fma(vv, wp[3], a3);
    a4 = __builtin_elementwise_fma(vv, wp[4], a4);
    a5 = __builtin_elementwise_fma(vv, wp[5], a5);
    a6 = __builtin_elementwise_fma(vv, wp[6], a6);
    a7 = __builtin_elementwise_fma(vv, wp[7], a7);
  }

  float t[HD];
  *(f32x4*)&t[0]  = a0; *(f32x4*)&t[4]  = a1; *(f32x4*)&t[8]  = a2; *(f32x4*)&t[12] = a3;
  *(f32x4*)&t[16] = a4; *(f32x4*)&t[20] = a5; *(f32x4*)&t[24] = a6; *(f32x4*)&t[28] = a7;

  float o0 = b2s[0], o1 = b2s[1];
  #pragma unroll
  for(int k = 0; k < HD; k++){
    float v = lky(t[k]);
    o0 = fmaf(v, w2s[k*2],   o0);
    o1 = fmaf(v, w2s[k*2+1], o1);
  }

  float m  = fmaxf(o0, o1);
  float ls = m + logf(expf(o0 - m) + expf(o1 - m));
  out[(size_t)n*2]   = o0 - ls;
  out[(size_t)n*2+1] = o1 - ls;
}

// ---------------------------------------------------------------- launch
extern "C" void kernel_launch(void* const* d_in, const int* in_sizes, int n_in,
                              void* d_out, int out_size, void* d_ws, size_t ws_size,
                              hipStream_t stream){
  const float* x  = (const float*)d_in[0];
  const int*   ei = (const int*)  d_in[1];
  const float* e  = (const float*)d_in[2];
  const float* bn_node_g = (const float*)d_in[4];
  const float* bn_node_b = (const float*)d_in[5];
  const float* bn_edge_g = (const float*)d_in[6];
  const float* bn_edge_b = (const float*)d_in[7];
  const float* lW1[3], *lb1[3], *lW2[3], *lb2[3], *lroot[3], *lbias[3];
  for(int l = 0; l < 3; l++){
    lW1[l]   = (const float*)d_in[8 + 6*l + 0];
    lb1[l]   = (const float*)d_in[8 + 6*l + 1];
    lW2[l]   = (const float*)d_in[8 + 6*l + 2];
    lb2[l]   = (const float*)d_in[8 + 6*l + 3];
    lroot[l] = (const float*)d_in[8 + 6*l + 4];
    lbias[l] = (const float*)d_in[8 + 6*l + 5];
  }
  const float* emW1  = (const float*)d_in[26];
  const float* emb1  = (const float*)d_in[27];
  const float* emW2  = (const float*)d_in[28];
  const float* emb2  = (const float*)d_in[29];
  const float* nm1W1 = (const float*)d_in[30];
  const float* nm1b1 = (const float*)d_in[31];
  const float* nm1W2 = (const float*)d_in[32];
  const float* nm1b2 = (const float*)d_in[33];
  const float* nm2W1 = (const float*)d_in[34];
  const float* nm2b1 = (const float*)d_in[35];
  const float* nm2W2 = (const float*)d_in[36];
  const float* nm2b2 = (const float*)d_in[37];

  const int* rowp = ei;
  const int* colp = ei + NE;

  // workspace layout (float units)
  float* ws   = (float*)d_ws;
  float* x_bn = ws;                                 // NN*16
  float* x_a  = x_bn + (size_t)NN*NIN;              // NN*32
  float* x_b  = x_a  + (size_t)NN*HD;               // NN*32
  float* scr  = x_b  + (size_t)NN*HD;               // 16384 floats
  float* partial_e = scr;            // 5120
  float* partial_x = scr + 5120;     // 2048
  float* ss_g      = scr + 7168;     // 70
  float* W1f       = scr + 7424;     // 1920
  float* b1f       = scr + 9344;     // 96
  float* biasP     = scr + 9440;     // 128
  short* w2pk   = (short*)(scr + 16384);            // 3*32768 shorts
  short* predpk = w2pk + 3*32768;                   // 8192 shorts
  short* T10    = predpk + 8192;                    // NE*32 bf16
  short* T11    = T10 + (size_t)NE*32;
  short* T12    = T11 + (size_t)NE*32;
  float* agg    = (float*)T10;                      // alias (T10 dead after layer-0 msg)
  float* cnt    = agg + (size_t)NN*HD;

  stats_all_kernel<<<NBLK_E + NBLK_X, 256, 0, stream>>>(e, x, partial_e, partial_x);
  prep_kernel<<<1, 1024, 0, stream>>>(partial_e, partial_x,
                                      bn_edge_g, bn_edge_b, bn_node_g, bn_node_b,
                                      lW1[0], lb1[0], lW1[1], lb1[1], lW1[2], lb1[2],
                                      emW1, emb1, emW2, emb2,
                                      nm1W1, nm1b1, nm1W2, nm1b2,
                                      ss_g, W1f, b1f, biasP, predpk);
  w2pack_all_kernel<<<320, 256, 0, stream>>>(lW2[0], lW2[1], lW2[2], w2pk);
  t1all_kernel<<<(NE + 255)/256, 256, 0, stream>>>(e, W1f, b1f, T10, T11, T12);

  const int nblocks  = (NN + 255)/256;     // 196
  const int m6blocks = (NTILES + 7)/8;     // 1172

  // layer 0 (din=16): fused normalize+root -> x_bn, x_a
  norm_root_kernel<<<nblocks, 256, 0, stream>>>(x, ss_g + 2*EIN, lroot[0], lbias[0], x_bn, x_a);
  msg6_kernel<NIN, 32, 2><<<m6blocks, 512, 0, stream>>>(T10, rowp, colp, x_bn,
                                                        w2pk + 0*32768, lb2[0], x_a);
  // layer 1 (din=32): x_a -> x_b
  rootv2_kernel<HD><<<nblocks, 256, 0, stream>>>(x_a, lroot[1], lbias[1], x_b);
  msg6_kernel<HD, 64, 2><<<m6blocks, 512, 0, stream>>>(T11, rowp, colp, x_a,
                                                       w2pk + 1*32768, lb2[1], x_b);
  // layer 2 (din=32): x_b -> x_a
  rootv2_kernel<HD><<<nblocks, 256, 0, stream>>>(x_b, lroot[2], lbias[2], x_a);
  msg6_kernel<HD, 64, 2><<<m6blocks, 512, 0, stream>>>(T12, rowp, colp, x_b,
                                                       w2pk + 2*32768, lb2[2], x_a);

  // predictor (agg/cnt alias T10 — zero first)
  zero_kernel<<<2048, 256, 0, stream>>>(agg, NN*HD + NN);
  pred5_kernel<<<(NTILES + 15)/16, 256, 0, stream>>>(x_a, e, rowp, colp, predpk, biasP, agg, cnt);
  final2_kernel<<<(NN + 255)/256, 256, 0, stream>>>(x_a, agg, cnt,
                                                    nm2W1, nm2b1, nm2W2, nm2b2,
                                                    (float*)d_out);
}